// Round 1
// 312.071 us; speedup vs baseline: 1.0380x; 1.0380x over previous
//
#include <hip/hip_runtime.h>
#include <math.h>

typedef __bf16 bf16;
typedef __bf16 bf16x2 __attribute__((ext_vector_type(2)));
typedef __bf16 bf16x4 __attribute__((ext_vector_type(4)));
typedef __bf16 bf16x8 __attribute__((ext_vector_type(8)));
typedef float f32x4 __attribute__((ext_vector_type(4)));

#define SEQ 2048
#define DH 64
#define DX 1024
#define NH 16
#define LP 72   // padded LDS row stride (64+8)

static __device__ __forceinline__ f32x4 mfma16(bf16x8 a, bf16x8 b, f32x4 c) {
    return __builtin_amdgcn_mfma_f32_16x16x32_bf16(a, b, c, 0, 0, 0);
}
static __device__ __forceinline__ bf16x8 cvt8(const float* __restrict__ p) {
    f32x4 a = *(const f32x4*)p;
    f32x4 b = *(const f32x4*)(p + 4);
    bf16x8 r;
    #pragma unroll
    for (int j = 0; j < 4; ++j) { r[j] = (bf16)a[j]; r[4 + j] = (bf16)b[j]; }
    return r;
}

// async global->LDS, 16 B per lane (lands at ldsbase + lane*16)
#define GL16(gp, lp) __builtin_amdgcn_global_load_lds( \
    (const __attribute__((address_space(1))) void*)(gp), \
    (__attribute__((address_space(3))) void*)(lp), 16, 0, 0)

// ============================ PLAN A kernels ================================

// f32 -> bf16 bulk convert: 3 inputs (4M el each) + 6 weights (1M el each)
// into ws at fixed offsets. 18M elements, 8 per thread.
__global__ __launch_bounds__(256) void cvt_all(
    const float* __restrict__ q, const float* __restrict__ k,
    const float* __restrict__ v,
    const float* __restrict__ w0, const float* __restrict__ w1,
    const float* __restrict__ w2, const float* __restrict__ w3,
    const float* __restrict__ w4, const float* __restrict__ w5,
    bf16* __restrict__ out)
{
    const size_t i = (size_t)blockIdx.x * 2048 + threadIdx.x * 8;
    const int seg = (int)(i >> 20);
    const float* s;
    size_t off;
    if (seg < 4)       { s = q; off = i; }
    else if (seg < 8)  { s = k; off = i - (4ull << 20); }
    else if (seg < 12) { s = v; off = i - (8ull << 20); }
    else {
        const float* ww[6] = {w0, w1, w2, w3, w4, w5};
        s = ww[seg - 12]; off = i - ((size_t)seg << 20);
    }
    *(bf16x8*)(out + i) = cvt8(s + off);
}

// fused multi-GEMM: Y_z = X_z @ W_z^T + bias_z, M=4096, N=K=1024, all bf16 in.
// xmode: 0 = X row-major [4096][1024]; 1 = X bhsd [2][16][2048][64]
// ymode: 0 = Y bf16 bhsd;              1 = Y f32 row-major
struct G4 {
    const bf16* X[4]; const bf16* W[4]; const float* B[4];
    bf16* Yb[4]; float* Yf[4]; int xmode[4]; int ymode[4];
};
__global__ __launch_bounds__(256) void gemm_fused(G4 a)
{
    __shared__ __align__(16) bf16 As[128 * 64];
    __shared__ __align__(16) bf16 Bs[128 * 64];

    const int z = blockIdx.z;
    const bf16* __restrict__ X = a.X[z];
    const bf16* __restrict__ W = a.W[z];
    const int xmode = a.xmode[z], ymode = a.ymode[z];

    const int tid  = threadIdx.x;
    const int wave = tid >> 6;
    const int lane = tid & 63;
    const int l16  = lane & 15;
    const int quad = lane >> 4;
    const int m0 = blockIdx.y * 128;
    const int n0 = blockIdx.x * 128;
    const int mw = (wave >> 1) * 64;
    const int nw = (wave & 1) * 64;

    const int srow = wave * 32 + (lane >> 3);  // base stage row (+ j*8)
    const int scol = (lane & 7) * 8;           // 8 bf16 = 16 B

    f32x4 acc[4][4];
    #pragma unroll
    for (int i = 0; i < 4; ++i)
        #pragma unroll
        for (int j = 0; j < 4; ++j) acc[i][j] = (f32x4){0.f,0.f,0.f,0.f};

    for (int kb = 0; kb < DX / 64; ++kb) {
        __syncthreads();
        // stage A (X): wave covers rows wave*32 .. +31, 4 insts
        if (xmode == 0) {
            const bf16* ga = X + (size_t)(m0 + srow) * DX + kb * 64 + scol;
            #pragma unroll
            for (int j = 0; j < 4; ++j)
                GL16(ga + (size_t)j * 8 * DX, &As[(wave * 32 + j * 8) * 64]);
        } else {
            #pragma unroll
            for (int j = 0; j < 4; ++j) {
                const int m = m0 + srow + j * 8;
                const int b = m >> 11, s = m & 2047;
                GL16(X + ((size_t)(b * NH + kb) * SEQ + s) * DH + scol,
                     &As[(wave * 32 + j * 8) * 64]);
            }
        }
        // stage B (W row-major)
        {
            const bf16* gb = W + (size_t)(n0 + srow) * DX + kb * 64 + scol;
            #pragma unroll
            for (int j = 0; j < 4; ++j)
                GL16(gb + (size_t)j * 8 * DX, &Bs[(wave * 32 + j * 8) * 64]);
        }
        __syncthreads();   // drains vmcnt -> LDS visible

        #pragma unroll
        for (int ks = 0; ks < 2; ++ks) {
            bf16x8 af[4], bfr[4];
            #pragma unroll
            for (int mf = 0; mf < 4; ++mf)
                af[mf] = *(const bf16x8*)&As[(mw + mf * 16 + l16) * 64 + ks * 32 + quad * 8];
            #pragma unroll
            for (int nf = 0; nf < 4; ++nf)
                bfr[nf] = *(const bf16x8*)&Bs[(nw + nf * 16 + l16) * 64 + ks * 32 + quad * 8];
            #pragma unroll
            for (int mf = 0; mf < 4; ++mf)
                #pragma unroll
                for (int nf = 0; nf < 4; ++nf)
                    acc[mf][nf] = mfma16(af[mf], bfr[nf], acc[mf][nf]);
        }
    }

    #pragma unroll
    for (int nf = 0; nf < 4; ++nf) {
        const int col = n0 + nw + nf * 16 + l16;
        const float bvv = a.B[z][col];
        #pragma unroll
        for (int mf = 0; mf < 4; ++mf) {
            #pragma unroll
            for (int r = 0; r < 4; ++r) {
                const int row = m0 + mw + mf * 16 + quad * 4 + r;
                const float vv = acc[mf][nf][r] + bvv;
                if (ymode == 0) {
                    const int b = row >> 11, s = row & 2047;
                    const int h = col >> 6, d = col & 63;
                    a.Yb[z][((size_t)(b * NH + h) * SEQ + s) * DH + d] = (bf16)vv;
                } else {
                    a.Yf[z][(size_t)row * DX + col] = vv;
                }
            }
        }
    }
}

// dual flash attention, both batches: grid (qt 16, h 16, b 2), block 256.
// R1: software-pipelined staging.
//  - K double-buffered in LDS via global_load_lds with both-sides XOR swizzle
//    (linear dest, inverse-swizzled global source, swizzled read — rule #21).
//  - V/xV prefetched into regs during compute of tile t, committed to the
//    transposed LDS tiles at the top of tile t+1 (T14 async-STAGE split).
//  - raw s_barrier + counted vmcnt(6): the 6 prefetch ops (2 GL16 + 4 reg
//    loads) stay in flight across the barrier (T4). Invariant: vmcnt(6)
//    leaves at most THIS iter's prefetch outstanding; all older ops (incl.
//    the GL16s feeding the current K buffer) are drained.
//  - s_setprio(1) around both MFMA clusters (T5).
__global__ __launch_bounds__(256) void attn_fast(
    bf16* __restrict__ Q, const bf16* __restrict__ K,
    const bf16* __restrict__ V, const bf16* __restrict__ xV,
    bf16* __restrict__ VB)
{
    __shared__ __align__(16) bf16 Ks[2][64 * 64];   // unpadded, XOR-swizzled
    __shared__ __align__(16) bf16 Vt [64 * LP];
    __shared__ __align__(16) bf16 xVt[64 * LP];
    __shared__ __align__(16) bf16 Pl[4][32 * LP];
    __shared__ float Lw[4][32];

    const int tid  = threadIdx.x;
    const int wave = tid >> 6;
    const int lane = tid & 63;
    const int l16  = lane & 15;
    const int quad = lane >> 4;
    const size_t hb = ((size_t)blockIdx.z * NH + blockIdx.y) * SEQ * DH;
    const int q0 = blockIdx.x * 128 + wave * 32;

    bf16x8 qf[2][2];
    #pragma unroll
    for (int mf = 0; mf < 2; ++mf)
        #pragma unroll
        for (int ks = 0; ks < 2; ++ks)
            qf[mf][ks] = *(const bf16x8*)(Q + hb + (size_t)(q0 + mf*16 + l16) * DH + ks*32 + quad*8);

    f32x4 ov[2][4], oxv[2][4];
    float rs[2] = {0.f, 0.f};
    #pragma unroll
    for (int mf = 0; mf < 2; ++mf)
        #pragma unroll
        for (int c = 0; c < 4; ++c) {
            ov[mf][c]  = (f32x4){0.f,0.f,0.f,0.f};
            oxv[mf][c] = (f32x4){0.f,0.f,0.f,0.f};
        }

    // K staging via GL16: wave covers 16 rows (2 calls x 8 rows).
    // lane l writes LDS slot (row = l>>3, chunk = l&7); source chunk is
    // (l&7)^(l>>3) so that read-side XOR recovers linear data.
    const int krow = lane >> 3;             // 0..7
    const int kch  = (lane & 7) ^ krow;     // pre-swizzled source chunk
    // V/xV transpose staging geometry (unchanged)
    const int vkp = (tid & 31) * 2;
    const int vd0 = (tid >> 5) * 8;
    const float SCL = 0.125f * 1.4426950408889634f;

    // ---- prologue: prefetch tile 0 (GL16 K first, then reg loads) ----
    bf16x8 pv0, pv1, px0, px1;
    {
        const bf16* kg = K + hb + (size_t)(wave*16 + krow) * DH + kch*8;
        GL16(kg,            &Ks[0][(wave*16 + 0) * 64]);
        GL16(kg + 8 * DH,   &Ks[0][(wave*16 + 8) * 64]);
        const size_t g0 = hb + (size_t)vkp * DH + vd0;
        pv0 = *(const bf16x8*)(V  + g0);
        pv1 = *(const bf16x8*)(V  + g0 + DH);
        px0 = *(const bf16x8*)(xV + g0);
        px1 = *(const bf16x8*)(xV + g0 + DH);
    }

    int c = 0;
    for (int kt = 0; kt < SEQ; kt += 64) {
        // A: commit prefetched V/xV into transposed LDS tiles
        //    (compiler inserts the vmcnt wait for pv*/px* here)
        #pragma unroll
        for (int j = 0; j < 8; ++j) {
            *(bf16x2*)&Vt [(vd0 + j) * LP + vkp] = (bf16x2){pv0[j], pv1[j]};
            *(bf16x2*)&xVt[(vd0 + j) * LP + vkp] = (bf16x2){px0[j], px1[j]};
        }
        // B: issue prefetch for tile t+1 (6 vmem ops; consumed next iter)
        if (kt + 64 < SEQ) {
            const bf16* kg = K + hb + (size_t)(kt + 64 + wave*16 + krow) * DH + kch*8;
            GL16(kg,          &Ks[c ^ 1][(wave*16 + 0) * 64]);
            GL16(kg + 8 * DH, &Ks[c ^ 1][(wave*16 + 8) * 64]);
            const size_t g0 = hb + (size_t)(kt + 64 + vkp) * DH + vd0;
            pv0 = *(const bf16x8*)(V  + g0);
            pv1 = *(const bf16x8*)(V  + g0 + DH);
            px0 = *(const bf16x8*)(xV + g0);
            px1 = *(const bf16x8*)(xV + g0 + DH);
        }
        // C: make staging visible to all waves; keep prefetch in flight
        __asm__ volatile("s_waitcnt lgkmcnt(0)" ::: "memory");
        __builtin_amdgcn_s_barrier();
        __asm__ volatile("s_waitcnt vmcnt(6)" ::: "memory");
        __builtin_amdgcn_sched_barrier(0);

        // D1: S^T = K Q^T  (keys as M; swizzled Ks read)
        f32x4 sf[4][2];
        #pragma unroll
        for (int mf = 0; mf < 4; ++mf)
            #pragma unroll
            for (int nf = 0; nf < 2; ++nf) sf[mf][nf] = (f32x4){0.f,0.f,0.f,0.f};
        __builtin_amdgcn_s_setprio(1);
        #pragma unroll
        for (int ks = 0; ks < 2; ++ks)
            #pragma unroll
            for (int mf = 0; mf < 4; ++mf) {
                bf16x8 kf = *(const bf16x8*)&Ks[c][(mf*16 + l16) * 64 +
                                                   (((ks*4 + quad) ^ (l16 & 7)) * 8)];
                sf[mf][0] = mfma16(kf, qf[0][ks], sf[mf][0]);
                sf[mf][1] = mfma16(kf, qf[1][ks], sf[mf][1]);
            }
        __builtin_amdgcn_s_setprio(0);

        // D2: P = exp2(S*scl), packed b64 writes, local row-sum accumulation
        #pragma unroll
        for (int nf = 0; nf < 2; ++nf)
            #pragma unroll
            for (int mf = 0; mf < 4; ++mf) {
                float p0 = exp2f(sf[mf][nf][0] * SCL);
                float p1 = exp2f(sf[mf][nf][1] * SCL);
                float p2 = exp2f(sf[mf][nf][2] * SCL);
                float p3 = exp2f(sf[mf][nf][3] * SCL);
                rs[nf] += (p0 + p1) + (p2 + p3);
                *(bf16x4*)&Pl[wave][(nf * 16 + l16) * LP + mf * 16 + quad * 4] =
                    (bf16x4){(bf16)p0, (bf16)p1, (bf16)p2, (bf16)p3};
            }
        __asm__ volatile("s_waitcnt lgkmcnt(0)" ::: "memory");
        __builtin_amdgcn_sched_barrier(0);

        // D3: O += P@V, Oxv += P@xV
        __builtin_amdgcn_s_setprio(1);
        #pragma unroll
        for (int ks = 0; ks < 2; ++ks) {
            bf16x8 pa0 = *(const bf16x8*)&Pl[wave][(l16)      * LP + ks * 32 + quad * 8];
            bf16x8 pa1 = *(const bf16x8*)&Pl[wave][(16 + l16) * LP + ks * 32 + quad * 8];
            #pragma unroll
            for (int cc = 0; cc < 4; ++cc) {
                bf16x8 bv = *(const bf16x8*)&Vt [(cc * 16 + l16) * LP + ks * 32 + quad * 8];
                ov[0][cc]  = mfma16(pa0, bv, ov[0][cc]);
                ov[1][cc]  = mfma16(pa1, bv, ov[1][cc]);
                bf16x8 bx = *(const bf16x8*)&xVt[(cc * 16 + l16) * LP + ks * 32 + quad * 8];
                oxv[0][cc] = mfma16(pa0, bx, oxv[0][cc]);
                oxv[1][cc] = mfma16(pa1, bx, oxv[1][cc]);
            }
        }
        __builtin_amdgcn_s_setprio(0);

        // E: protect Vt/xVt overwrite next iter
        __builtin_amdgcn_sched_barrier(0);
        __builtin_amdgcn_s_barrier();
        c ^= 1;
    }

    // row-sum finalization: reduce over quads, bounce through LDS
    #pragma unroll
    for (int nf = 0; nf < 2; ++nf) {
        rs[nf] += __shfl_xor(rs[nf], 16, 64);
        rs[nf] += __shfl_xor(rs[nf], 32, 64);
    }
    if (quad == 0) { Lw[wave][l16] = rs[0]; Lw[wave][16 + l16] = rs[1]; }
    __asm__ volatile("s_waitcnt lgkmcnt(0)" ::: "memory");

    #pragma unroll
    for (int mf = 0; mf < 2; ++mf)
        #pragma unroll
        for (int r = 0; r < 4; ++r) {
            const int qrow = mf * 16 + quad * 4 + r;
            const float inv = 1.0f / Lw[wave][qrow];
            const size_t base = hb + (size_t)(q0 + qrow) * DH;
            #pragma unroll
            for (int cc = 0; cc < 4; ++cc) {
                const int d = cc * 16 + l16;
                Q [base + d] = (bf16)(oxv[mf][cc][r] * inv);   // kbar in place
                VB[base + d] = (bf16)(ov[mf][cc][r]  * inv);
            }
        }
}

// ======================= legacy (R6, proven) fallback =======================

__global__ __launch_bounds__(256) void proj_gemm(
    const void* __restrict__ Xv, const float* __restrict__ W,
    const float* __restrict__ bias, void* __restrict__ Yv,
    int in_kind, int out_mode)
{
    __shared__ __align__(16) bf16 As[64 * LP];
    __shared__ __align__(16) bf16 Bs[128 * LP];
    const int tid  = threadIdx.x;
    const int wave = tid >> 6;
    const int lane = tid & 63;
    const int l16  = lane & 15;
    const int quad = lane >> 4;
    const int m0 = blockIdx.y * 64;
    const int n0 = blockIdx.x * 128;
    const int m_w = (wave >> 1) * 32;
    const int n_w = (wave & 1) * 64;
    const int ar = tid >> 2, ac = (tid & 3) * 16;
    const int br = tid >> 1, bc = (tid & 1) * 32;

    f32x4 acc[2][4];
    #pragma unroll
    for (int i = 0; i < 2; ++i)
        #pragma unroll
        for (int j = 0; j < 4; ++j) acc[i][j] = (f32x4){0.f,0.f,0.f,0.f};

    for (int kb = 0; kb < DX / 64; ++kb) {
        __syncthreads();
        if (in_kind == 0) {
            const float* xp = (const float*)Xv + (size_t)(m0 + ar) * DX + kb * 64 + ac;
            *(bf16x8*)&As[ar * LP + ac]     = cvt8(xp);
            *(bf16x8*)&As[ar * LP + ac + 8] = cvt8(xp + 8);
        } else {
            const bf16* xp = (const bf16*)Xv + ((size_t)kb * SEQ + (m0 + ar)) * DH + ac;
            *(bf16x8*)&As[ar * LP + ac]     = *(const bf16x8*)xp;
            *(bf16x8*)&As[ar * LP + ac + 8] = *(const bf16x8*)(xp + 8);
        }
        {
            const float* wp = W + (size_t)(n0 + br) * DX + kb * 64 + bc;
            #pragma unroll
            for (int g = 0; g < 4; ++g)
                *(bf16x8*)&Bs[br * LP + bc + g * 8] = cvt8(wp + g * 8);
        }
        __syncthreads();
        #pragma unroll
        for (int ks = 0; ks < 2; ++ks) {
            bf16x8 a0 = *(const bf16x8*)&As[(m_w + l16)      * LP + ks * 32 + quad * 8];
            bf16x8 a1 = *(const bf16x8*)&As[(m_w + 16 + l16) * LP + ks * 32 + quad * 8];
            #pragma unroll
            for (int nf = 0; nf < 4; ++nf) {
                bf16x8 b = *(const bf16x8*)&Bs[(n_w + nf * 16 + l16) * LP + ks * 32 + quad * 8];
                acc[0][nf] = mfma16(a0, b, acc[0][nf]);
                acc[1][nf] = mfma16(a1, b, acc[1][nf]);
            }
        }
    }
    #pragma unroll
    for (int mf = 0; mf < 2; ++mf)
        #pragma unroll
        for (int nf = 0; nf < 4; ++nf) {
            const int col = n0 + n_w + nf * 16 + l16;
            const float bvv = bias[col];
            #pragma unroll
            for (int r = 0; r < 4; ++r) {
                const int row = m0 + m_w + mf * 16 + quad * 4 + r;
                float v = acc[mf][nf][r] + bvv;
                if (out_mode == 0) {
                    int h = col >> 6, d = col & 63;
                    ((bf16*)Yv)[((size_t)h * SEQ + row) * DH + d] = (bf16)v;
                } else {
                    ((float*)Yv)[(size_t)row * DX + col] = v;
                }
            }
        }
}

__global__ __launch_bounds__(256) void attn_dual(
    bf16* __restrict__ Q, const bf16* __restrict__ K,
    const bf16* __restrict__ V, const bf16* __restrict__ xV,
    bf16* __restrict__ vb)
{
    __shared__ __align__(16) bf16 Ks [64 * LP];
    __shared__ __align__(16) bf16 Vt [64 * LP];
    __shared__ __align__(16) bf16 xVt[64 * LP];
    __shared__ __align__(16) bf16 Pl[4][32 * LP];
    const int tid  = threadIdx.x;
    const int h    = blockIdx.y;
    const int qt   = blockIdx.x;
    const int wave = tid >> 6;
    const int lane = tid & 63;
    const int l16  = lane & 15;
    const int quad = lane >> 4;
    const size_t hb = (size_t)h * SEQ * DH;
    const int q0 = qt * 128 + wave * 32;

    bf16x8 qf[2][2];
    #pragma unroll
    for (int mf = 0; mf < 2; ++mf)
        #pragma unroll
        for (int ks = 0; ks < 2; ++ks)
            qf[mf][ks] = *(const bf16x8*)(Q + hb + (size_t)(q0 + mf*16 + l16) * DH + ks*32 + quad*8);

    float mr[2][4], lr[2][4];
    f32x4 ov[2][4], oxv[2][4];
    #pragma unroll
    for (int mf = 0; mf < 2; ++mf)
        #pragma unroll
        for (int r = 0; r < 4; ++r) { mr[mf][r] = -1e30f; lr[mf][r] = 0.f; }
    #pragma unroll
    for (int mf = 0; mf < 2; ++mf)
        #pragma unroll
        for (int c = 0; c < 4; ++c) {
            ov[mf][c]  = (f32x4){0.f,0.f,0.f,0.f};
            oxv[mf][c] = (f32x4){0.f,0.f,0.f,0.f};
        }
    const int sr = tid >> 2, sc = (tid & 3) * 16;
    const int vkp = (tid & 31) * 2;
    const int vd0 = (tid >> 5) * 8;
    const float SCL = 0.125f * 1.4426950408889634f;

    for (int kt = 0; kt < SEQ; kt += 64) {
        __syncthreads();
        {
            const bf16* kpt = K + hb + (size_t)(kt + sr) * DH + sc;
            *(bf16x8*)&Ks[sr * LP + sc]     = *(const bf16x8*)kpt;
            *(bf16x8*)&Ks[sr * LP + sc + 8] = *(const bf16x8*)(kpt + 8);
            const size_t g0 = hb + (size_t)(kt + vkp) * DH + vd0;
            bf16x8 v0 = *(const bf16x8*)(V + g0);
            bf16x8 v1 = *(const bf16x8*)(V + g0 + DH);
            bf16x8 x0 = *(const bf16x8*)(xV + g0);
            bf16x8 x1 = *(const bf16x8*)(xV + g0 + DH);
            #pragma unroll
            for (int j = 0; j < 8; ++j) {
                *(bf16x2*)&Vt [(vd0 + j) * LP + vkp] = (bf16x2){v0[j], v1[j]};
                *(bf16x2*)&xVt[(vd0 + j) * LP + vkp] = (bf16x2){x0[j], x1[j]};
            }
        }
        __syncthreads();
        f32x4 sf[2][4];
        #pragma unroll
        for (int mf = 0; mf < 2; ++mf)
            #pragma unroll
            for (int nf = 0; nf < 4; ++nf) sf[mf][nf] = (f32x4){0.f,0.f,0.f,0.f};
        #pragma unroll
        for (int ks = 0; ks < 2; ++ks)
            #pragma unroll
            for (int nf = 0; nf < 4; ++nf) {
                bf16x8 bk = *(const bf16x8*)&Ks[(nf * 16 + l16) * LP + ks * 32 + quad * 8];
                sf[0][nf] = mfma16(qf[0][ks], bk, sf[0][nf]);
                sf[1][nf] = mfma16(qf[1][ks], bk, sf[1][nf]);
            }
        float mx[2][4], rs[2][4], alpha[2][4];
        #pragma unroll
        for (int mf = 0; mf < 2; ++mf)
            #pragma unroll
            for (int r = 0; r < 4; ++r) {
                float aa = fmaxf(sf[mf][0][r], sf[mf][1][r]);
                float bb = fmaxf(sf[mf][2][r], sf[mf][3][r]);
                mx[mf][r] = fmaxf(aa, bb) * SCL;
            }
        #pragma unroll
        for (int off = 1; off < 16; off <<= 1)
            #pragma unroll
            for (int mf = 0; mf < 2; ++mf)
                #pragma unroll
                for (int r = 0; r < 4; ++r)
                    mx[mf][r] = fmaxf(mx[mf][r], __shfl_xor(mx[mf][r], off, 64));
        #pragma unroll
        for (int mf = 0; mf < 2; ++mf)
            #pragma unroll
            for (int r = 0; r < 4; ++r) {
                float mnew = fmaxf(mr[mf][r], mx[mf][r]);
                alpha[mf][r] = exp2f(mr[mf][r] - mnew);
                mr[mf][r] = mnew;
            }
        bf16* pw = &Pl[wave][0];
        #pragma unroll
        for (int mf = 0; mf < 2; ++mf)
            #pragma unroll
            for (int r = 0; r < 4; ++r) rs[mf][r] = 0.f;
        #pragma unroll
        for (int mf = 0; mf < 2; ++mf)
            #pragma unroll
            for (int nf = 0; nf < 4; ++nf)
                #pragma unroll
                for (int r = 0; r < 4; ++r) {
                    float p = exp2f(sf[mf][nf][r] * SCL - mr[mf][r]);
                    rs[mf][r] += p;
                    pw[(mf * 16 + quad * 4 + r) * LP + nf * 16 + l16] = (bf16)p;
                }
        #pragma unroll
        for (int off = 1; off < 16; off <<= 1)
            #pragma unroll
            for (int mf = 0; mf < 2; ++mf)
                #pragma unroll
                for (int r = 0; r < 4; ++r)
                    rs[mf][r] += __shfl_xor(rs[mf][r], off, 64);
        #pragma unroll
        for (int mf = 0; mf < 2; ++mf)
            #pragma unroll
            for (int r = 0; r < 4; ++r)
                lr[mf][r] = lr[mf][r] * alpha[mf][r] + rs[mf][r];
        #pragma unroll
        for (int mf = 0; mf < 2; ++mf)
            #pragma unroll
            for (int c = 0; c < 4; ++c)
                #pragma unroll
                for (int r = 0; r < 4; ++r) {
                    ov[mf][c][r]  *= alpha[mf][r];
                    oxv[mf][c][r] *= alpha[mf][r];
                }
        __asm__ volatile("s_waitcnt lgkmcnt(0)" ::: "memory");
        #pragma unroll
        for (int ks = 0; ks < 2; ++ks) {
            bf16x8 pa0 = *(const bf16x8*)&Pl[wave][(l16)      * LP + ks * 32 + quad * 8];
            bf16x8 pa1 = *(const bf16x8*)&Pl[wave][(16 + l16) * LP + ks * 32 + quad * 8];
            #pragma unroll
            for (int c = 0; c < 4; ++c) {
                bf16x8 bv = *(const bf16x8*)&Vt [(c * 16 + l16) * LP + ks * 32 + quad * 8];
                ov[0][c]  = mfma16(pa0, bv, ov[0][c]);
                ov[1][c]  = mfma16(pa1, bv, ov[1][c]);
                bf16x8 bx = *(const bf16x8*)&xVt[(c * 16 + l16) * LP + ks * 32 + quad * 8];
                oxv[0][c] = mfma16(pa0, bx, oxv[0][c]);
                oxv[1][c] = mfma16(pa1, bx, oxv[1][c]);
            }
        }
    }
    #pragma unroll
    for (int mf = 0; mf < 2; ++mf)
        #pragma unroll
        for (int r = 0; r < 4; ++r) {
            const int s = q0 + mf * 16 + quad * 4 + r;
            const float inv = 1.0f / lr[mf][r];
            #pragma unroll
            for (int c = 0; c < 4; ++c) {
                const int d = c * 16 + l16;
                Q [hb + (size_t)s * DH + d] = (bf16)(oxv[mf][c][r] * inv);
                vb[hb + (size_t)s * DH + d] = (bf16)(ov[mf][c][r]  * inv);
            }
        }
}

// ================================ launch ====================================

extern "C" void kernel_launch(void* const* d_in, const int* in_sizes, int n_in,
                              void* d_out, int out_size, void* d_ws, size_t ws_size,
                              hipStream_t stream) {
    const float* query = (const float*)d_in[0];
    const float* key   = (const float*)d_in[1];
    const float* value = (const float*)d_in[2];
    const float* Wq  = (const float*)d_in[3];  const float* bq  = (const float*)d_in[4];
    const float* Wk  = (const float*)d_in[5];  const float* bk  = (const float*)d_in[6];
    const float* Wv  = (const float*)d_in[7];  const float* bv  = (const float*)d_in[8];
    const float* Wxv = (const float*)d_in[9];  const float* bxv = (const float*)d_in[10];
    const float* Wxo = (const float*)d_in[11]; const float* bxo = (const float*)d_in[12];
    const float* Wmo = (const float*)d_in[13]; const float* bmo = (const float*)d_in[14];

    float* out = (float*)d_out;
    const size_t SB = (size_t)SEQ * DX;          // 2,097,152 el
    const size_t M1 = 1ull << 20;

    dim3 blk(256);

    if (ws_size >= (76ull << 20)) {
        // ---------------- Plan A: merged batches, bf16 everywhere -----------
        bf16* ws = (bf16*)d_ws;
        bf16* qb  = ws;                 // 4M el
        bf16* kb  = ws + 4 * M1;
        bf16* vb  = ws + 8 * M1;
        bf16* Wqb = ws + 12 * M1;       // 6 x 1M el
        bf16* Wkb = Wqb + M1;
        bf16* Wvb = Wkb + M1;
        bf16* Wxvb= Wvb + M1;
        bf16* Wxob= Wxvb + M1;
        bf16* Wmob= Wxob + M1;
        bf16* Qs  = ws + 18 * M1;       // bhsd [2][16][2048][64], 4M el each
        bf16* Kss = ws + 22 * M1;
        bf16* Vs  = ws + 26 * M1;
        bf16* xVs = ws + 30 * M1;
        bf16* VBs = ws + 34 * M1;

        cvt_all<<<9216, blk, 0, stream>>>(query, key, value,
                                          Wq, Wk, Wv, Wxv, Wxo, Wmo, ws + 0);
        // note: cvt_all writes segments in order q,k,v,W* starting at ws —
        // matches qb/kb/vb/Wqb.. layout above.

        G4 g1;
        g1.X[0]=qb;  g1.W[0]=Wqb;  g1.B[0]=bq;  g1.Yb[0]=Qs;  g1.Yf[0]=nullptr; g1.xmode[0]=0; g1.ymode[0]=0;
        g1.X[1]=kb;  g1.W[1]=Wkb;  g1.B[1]=bk;  g1.Yb[1]=Kss; g1.Yf[1]=nullptr; g1.xmode[1]=0; g1.ymode[1]=0;
        g1.X[2]=vb;  g1.W[2]=Wvb;  g1.B[2]=bv;  g1.Yb[2]=Vs;  g1.Yf[2]=nullptr; g1.xmode[2]=0; g1.ymode[2]=0;
        g1.X[3]=kb;  g1.W[3]=Wxvb; g1.B[3]=bxv; g1.Yb[3]=xVs; g1.Yf[3]=nullptr; g1.xmode[3]=0; g1.ymode[3]=0;
        gemm_fused<<<dim3(8, 32, 4), blk, 0, stream>>>(g1);

        attn_fast<<<dim3(16, NH, 2), blk, 0, stream>>>(Qs, Kss, Vs, xVs, VBs);

        G4 g2;
        g2.X[0]=Qs;  g2.W[0]=Wxob; g2.B[0]=bxo; g2.Yb[0]=nullptr; g2.Yf[0]=out;          g2.xmode[0]=1; g2.ymode[0]=1;
        g2.X[1]=VBs; g2.W[1]=Wmob; g2.B[1]=bmo; g2.Yb[1]=nullptr; g2.Yf[1]=out + 2*SB;   g2.xmode[1]=1; g2.ymode[1]=1;
        g2.X[2]=Qs;  g2.W[2]=Wxob; g2.B[2]=bxo; g2.Yb[2]=nullptr; g2.Yf[2]=out;          g2.xmode[2]=1; g2.ymode[2]=1;
        g2.X[3]=Qs;  g2.W[3]=Wxob; g2.B[3]=bxo; g2.Yb[3]=nullptr; g2.Yf[3]=out;          g2.xmode[3]=1; g2.ymode[3]=1;
        gemm_fused<<<dim3(8, 32, 2), blk, 0, stream>>>(g2);
    } else {
        // ---------------- fallback: proven R6 path (20 MB ws) ---------------
        bf16* Qs  = (bf16*)d_ws;
        bf16* Ksb = Qs  + SB;
        bf16* Vs  = Ksb + SB;
        bf16* xVs = Vs  + SB;
        bf16* vbs = xVs + SB;
        dim3 pg(8, 32);
        dim3 ag(16, NH);
        for (int b = 0; b < 2; ++b) {
            const float* q_b = query + (size_t)b * SB;
            const float* k_b = key   + (size_t)b * SB;
            const float* v_b = value + (size_t)b * SB;
            float* x_b = out + (size_t)b * SB;
            float* m_b = out + 2 * SB + (size_t)b * SB;
            proj_gemm<<<pg, blk, 0, stream>>>(q_b, Wq,  bq,  Qs,  0, 0);
            proj_gemm<<<pg, blk, 0, stream>>>(k_b, Wk,  bk,  Ksb, 0, 0);
            proj_gemm<<<pg, blk, 0, stream>>>(v_b, Wv,  bv,  Vs,  0, 0);
            proj_gemm<<<pg, blk, 0, stream>>>(k_b, Wxv, bxv, xVs, 0, 0);
            attn_dual<<<ag, blk, 0, stream>>>(Qs, Ksb, Vs, xVs, vbs);
            proj_gemm<<<pg, blk, 0, stream>>>(Qs,  Wxo, bxo, x_b, 1, 1);
            proj_gemm<<<pg, blk, 0, stream>>>(vbs, Wmo, bmo, m_b, 1, 1);
        }
    }
}

// Round 2
// 303.208 us; speedup vs baseline: 1.0684x; 1.0292x over previous
//
#include <hip/hip_runtime.h>
#include <math.h>

typedef __bf16 bf16;
typedef __bf16 bf16x2 __attribute__((ext_vector_type(2)));
typedef __bf16 bf16x4 __attribute__((ext_vector_type(4)));
typedef __bf16 bf16x8 __attribute__((ext_vector_type(8)));
typedef float f32x4 __attribute__((ext_vector_type(4)));

#define SEQ 2048
#define DH 64
#define DX 1024
#define NH 16
#define LP 72   // padded LDS row stride (64+8)

static __device__ __forceinline__ f32x4 mfma16(bf16x8 a, bf16x8 b, f32x4 c) {
    return __builtin_amdgcn_mfma_f32_16x16x32_bf16(a, b, c, 0, 0, 0);
}
static __device__ __forceinline__ bf16x8 cvt8(const float* __restrict__ p) {
    f32x4 a = *(const f32x4*)p;
    f32x4 b = *(const f32x4*)(p + 4);
    bf16x8 r;
    #pragma unroll
    for (int j = 0; j < 4; ++j) { r[j] = (bf16)a[j]; r[4 + j] = (bf16)b[j]; }
    return r;
}

// async global->LDS, 16 B per lane (lands at ldsbase + lane*16)
#define GL16(gp, lp) __builtin_amdgcn_global_load_lds( \
    (const __attribute__((address_space(1))) void*)(gp), \
    (__attribute__((address_space(3))) void*)(lp), 16, 0, 0)

// ============================ PLAN A kernels ================================

// f32 -> bf16 bulk convert: 3 inputs (4M el each) + 6 weights (1M el each)
// into ws at fixed offsets. 18M elements, 8 per thread.
__global__ __launch_bounds__(256) void cvt_all(
    const float* __restrict__ q, const float* __restrict__ k,
    const float* __restrict__ v,
    const float* __restrict__ w0, const float* __restrict__ w1,
    const float* __restrict__ w2, const float* __restrict__ w3,
    const float* __restrict__ w4, const float* __restrict__ w5,
    bf16* __restrict__ out)
{
    const size_t i = (size_t)blockIdx.x * 2048 + threadIdx.x * 8;
    const int seg = (int)(i >> 20);
    const float* s;
    size_t off;
    if (seg < 4)       { s = q; off = i; }
    else if (seg < 8)  { s = k; off = i - (4ull << 20); }
    else if (seg < 12) { s = v; off = i - (8ull << 20); }
    else {
        const float* ww[6] = {w0, w1, w2, w3, w4, w5};
        s = ww[seg - 12]; off = i - ((size_t)seg << 20);
    }
    *(bf16x8*)(out + i) = cvt8(s + off);
}

// fused multi-GEMM: Y_z = X_z @ W_z^T + bias_z, M=4096, N=K=1024, all bf16 in.
// xmode: 0 = X row-major [4096][1024]; 1 = X bhsd [2][16][2048][64]
// ymode: 0 = Y bf16 bhsd;              1 = Y f32 row-major
struct G4 {
    const bf16* X[4]; const bf16* W[4]; const float* B[4];
    bf16* Yb[4]; float* Yf[4]; int xmode[4]; int ymode[4];
};
__global__ __launch_bounds__(256) void gemm_fused(G4 a)
{
    __shared__ __align__(16) bf16 As[128 * 64];
    __shared__ __align__(16) bf16 Bs[128 * 64];

    const int z = blockIdx.z;
    const bf16* __restrict__ X = a.X[z];
    const bf16* __restrict__ W = a.W[z];
    const int xmode = a.xmode[z], ymode = a.ymode[z];

    const int tid  = threadIdx.x;
    const int wave = tid >> 6;
    const int lane = tid & 63;
    const int l16  = lane & 15;
    const int quad = lane >> 4;
    const int m0 = blockIdx.y * 128;
    const int n0 = blockIdx.x * 128;
    const int mw = (wave >> 1) * 64;
    const int nw = (wave & 1) * 64;

    const int srow = wave * 32 + (lane >> 3);  // base stage row (+ j*8)
    const int scol = (lane & 7) * 8;           // 8 bf16 = 16 B

    f32x4 acc[4][4];
    #pragma unroll
    for (int i = 0; i < 4; ++i)
        #pragma unroll
        for (int j = 0; j < 4; ++j) acc[i][j] = (f32x4){0.f,0.f,0.f,0.f};

    for (int kb = 0; kb < DX / 64; ++kb) {
        __syncthreads();
        // stage A (X): wave covers rows wave*32 .. +31, 4 insts
        if (xmode == 0) {
            const bf16* ga = X + (size_t)(m0 + srow) * DX + kb * 64 + scol;
            #pragma unroll
            for (int j = 0; j < 4; ++j)
                GL16(ga + (size_t)j * 8 * DX, &As[(wave * 32 + j * 8) * 64]);
        } else {
            #pragma unroll
            for (int j = 0; j < 4; ++j) {
                const int m = m0 + srow + j * 8;
                const int b = m >> 11, s = m & 2047;
                GL16(X + ((size_t)(b * NH + kb) * SEQ + s) * DH + scol,
                     &As[(wave * 32 + j * 8) * 64]);
            }
        }
        // stage B (W row-major)
        {
            const bf16* gb = W + (size_t)(n0 + srow) * DX + kb * 64 + scol;
            #pragma unroll
            for (int j = 0; j < 4; ++j)
                GL16(gb + (size_t)j * 8 * DX, &Bs[(wave * 32 + j * 8) * 64]);
        }
        __syncthreads();   // drains vmcnt -> LDS visible

        #pragma unroll
        for (int ks = 0; ks < 2; ++ks) {
            bf16x8 af[4], bfr[4];
            #pragma unroll
            for (int mf = 0; mf < 4; ++mf)
                af[mf] = *(const bf16x8*)&As[(mw + mf * 16 + l16) * 64 + ks * 32 + quad * 8];
            #pragma unroll
            for (int nf = 0; nf < 4; ++nf)
                bfr[nf] = *(const bf16x8*)&Bs[(nw + nf * 16 + l16) * 64 + ks * 32 + quad * 8];
            #pragma unroll
            for (int mf = 0; mf < 4; ++mf)
                #pragma unroll
                for (int nf = 0; nf < 4; ++nf)
                    acc[mf][nf] = mfma16(af[mf], bfr[nf], acc[mf][nf]);
        }
    }

    #pragma unroll
    for (int nf = 0; nf < 4; ++nf) {
        const int col = n0 + nw + nf * 16 + l16;
        const float bvv = a.B[z][col];
        #pragma unroll
        for (int mf = 0; mf < 4; ++mf) {
            #pragma unroll
            for (int r = 0; r < 4; ++r) {
                const int row = m0 + mw + mf * 16 + quad * 4 + r;
                const float vv = acc[mf][nf][r] + bvv;
                if (ymode == 0) {
                    const int b = row >> 11, s = row & 2047;
                    const int h = col >> 6, d = col & 63;
                    a.Yb[z][((size_t)(b * NH + h) * SEQ + s) * DH + d] = (bf16)vv;
                } else {
                    a.Yf[z][(size_t)row * DX + col] = vv;
                }
            }
        }
    }
}

// dual flash attention, both batches: grid (qt 16, h 16, b 2), block 256.
// R1: software-pipelined staging (GL16 K dbuf + reg-prefetch V/xV, counted
//     vmcnt(6), setprio around MFMA clusters).
// R2: VALU-diet softmax.
//  - row-sum via MFMA: rs = P @ ones, accumulated on the matrix pipe using
//    the already-loaded P fragments (4 extra MFMA/iter). Replaces 32 VALU
//    adds/iter AND the end-of-kernel shuffle+LDS reduction (Lw deleted).
//    Output layout of mfma(pa, ones): row = quad*4+r = q-row, broadcast
//    over l16 — exactly what the epilogue indexes; no cross-lane fixup.
//    Numerics: rs now sums the same bf16-rounded P used in PV (weights sum
//    to exactly 1 after normalization).
//  - __builtin_amdgcn_exp2f -> single v_exp_f32 per score.
__global__ __launch_bounds__(256) void attn_fast(
    bf16* __restrict__ Q, const bf16* __restrict__ K,
    const bf16* __restrict__ V, const bf16* __restrict__ xV,
    bf16* __restrict__ VB)
{
    __shared__ __align__(16) bf16 Ks[2][64 * 64];   // unpadded, XOR-swizzled
    __shared__ __align__(16) bf16 Vt [64 * LP];
    __shared__ __align__(16) bf16 xVt[64 * LP];
    __shared__ __align__(16) bf16 Pl[4][32 * LP];

    const int tid  = threadIdx.x;
    const int wave = tid >> 6;
    const int lane = tid & 63;
    const int l16  = lane & 15;
    const int quad = lane >> 4;
    const size_t hb = ((size_t)blockIdx.z * NH + blockIdx.y) * SEQ * DH;
    const int q0 = blockIdx.x * 128 + wave * 32;

    bf16x8 qf[2][2];
    #pragma unroll
    for (int mf = 0; mf < 2; ++mf)
        #pragma unroll
        for (int ks = 0; ks < 2; ++ks)
            qf[mf][ks] = *(const bf16x8*)(Q + hb + (size_t)(q0 + mf*16 + l16) * DH + ks*32 + quad*8);

    bf16x8 one8;
    #pragma unroll
    for (int j = 0; j < 8; ++j) one8[j] = (bf16)1.0f;

    f32x4 ov[2][4], oxv[2][4];
    f32x4 rsa[2];
    rsa[0] = (f32x4){0.f,0.f,0.f,0.f};
    rsa[1] = (f32x4){0.f,0.f,0.f,0.f};
    #pragma unroll
    for (int mf = 0; mf < 2; ++mf)
        #pragma unroll
        for (int c = 0; c < 4; ++c) {
            ov[mf][c]  = (f32x4){0.f,0.f,0.f,0.f};
            oxv[mf][c] = (f32x4){0.f,0.f,0.f,0.f};
        }

    // K staging via GL16: wave covers 16 rows (2 calls x 8 rows).
    // lane l writes LDS slot (row = l>>3, chunk = l&7); source chunk is
    // (l&7)^(l>>3) so that read-side XOR recovers linear data.
    const int krow = lane >> 3;             // 0..7
    const int kch  = (lane & 7) ^ krow;     // pre-swizzled source chunk
    // V/xV transpose staging geometry (unchanged)
    const int vkp = (tid & 31) * 2;
    const int vd0 = (tid >> 5) * 8;
    const float SCL = 0.125f * 1.4426950408889634f;

    // ---- prologue: prefetch tile 0 (GL16 K first, then reg loads) ----
    bf16x8 pv0, pv1, px0, px1;
    {
        const bf16* kg = K + hb + (size_t)(wave*16 + krow) * DH + kch*8;
        GL16(kg,            &Ks[0][(wave*16 + 0) * 64]);
        GL16(kg + 8 * DH,   &Ks[0][(wave*16 + 8) * 64]);
        const size_t g0 = hb + (size_t)vkp * DH + vd0;
        pv0 = *(const bf16x8*)(V  + g0);
        pv1 = *(const bf16x8*)(V  + g0 + DH);
        px0 = *(const bf16x8*)(xV + g0);
        px1 = *(const bf16x8*)(xV + g0 + DH);
    }

    int c = 0;
    for (int kt = 0; kt < SEQ; kt += 64) {
        // A: commit prefetched V/xV into transposed LDS tiles
        //    (compiler inserts the vmcnt wait for pv*/px* here)
        #pragma unroll
        for (int j = 0; j < 8; ++j) {
            *(bf16x2*)&Vt [(vd0 + j) * LP + vkp] = (bf16x2){pv0[j], pv1[j]};
            *(bf16x2*)&xVt[(vd0 + j) * LP + vkp] = (bf16x2){px0[j], px1[j]};
        }
        // B: issue prefetch for tile t+1 (6 vmem ops; consumed next iter)
        if (kt + 64 < SEQ) {
            const bf16* kg = K + hb + (size_t)(kt + 64 + wave*16 + krow) * DH + kch*8;
            GL16(kg,          &Ks[c ^ 1][(wave*16 + 0) * 64]);
            GL16(kg + 8 * DH, &Ks[c ^ 1][(wave*16 + 8) * 64]);
            const size_t g0 = hb + (size_t)(kt + 64 + vkp) * DH + vd0;
            pv0 = *(const bf16x8*)(V  + g0);
            pv1 = *(const bf16x8*)(V  + g0 + DH);
            px0 = *(const bf16x8*)(xV + g0);
            px1 = *(const bf16x8*)(xV + g0 + DH);
        }
        // C: make staging visible to all waves; keep prefetch in flight
        __asm__ volatile("s_waitcnt lgkmcnt(0)" ::: "memory");
        __builtin_amdgcn_s_barrier();
        __asm__ volatile("s_waitcnt vmcnt(6)" ::: "memory");
        __builtin_amdgcn_sched_barrier(0);

        // D1: S^T = K Q^T  (keys as M; swizzled Ks read)
        f32x4 sf[4][2];
        #pragma unroll
        for (int mf = 0; mf < 4; ++mf)
            #pragma unroll
            for (int nf = 0; nf < 2; ++nf) sf[mf][nf] = (f32x4){0.f,0.f,0.f,0.f};
        __builtin_amdgcn_s_setprio(1);
        #pragma unroll
        for (int ks = 0; ks < 2; ++ks)
            #pragma unroll
            for (int mf = 0; mf < 4; ++mf) {
                bf16x8 kf = *(const bf16x8*)&Ks[c][(mf*16 + l16) * 64 +
                                                   (((ks*4 + quad) ^ (l16 & 7)) * 8)];
                sf[mf][0] = mfma16(kf, qf[0][ks], sf[mf][0]);
                sf[mf][1] = mfma16(kf, qf[1][ks], sf[mf][1]);
            }
        __builtin_amdgcn_s_setprio(0);

        // D2: P = exp2(S*scl) (raw v_exp_f32), packed b64 writes
        #pragma unroll
        for (int nf = 0; nf < 2; ++nf)
            #pragma unroll
            for (int mf = 0; mf < 4; ++mf) {
                float p0 = __builtin_amdgcn_exp2f(sf[mf][nf][0] * SCL);
                float p1 = __builtin_amdgcn_exp2f(sf[mf][nf][1] * SCL);
                float p2 = __builtin_amdgcn_exp2f(sf[mf][nf][2] * SCL);
                float p3 = __builtin_amdgcn_exp2f(sf[mf][nf][3] * SCL);
                *(bf16x4*)&Pl[wave][(nf * 16 + l16) * LP + mf * 16 + quad * 4] =
                    (bf16x4){(bf16)p0, (bf16)p1, (bf16)p2, (bf16)p3};
            }
        __asm__ volatile("s_waitcnt lgkmcnt(0)" ::: "memory");
        __builtin_amdgcn_sched_barrier(0);

        // D3: O += P@V, Oxv += P@xV, rs += P@1 (row-sum on the matrix pipe)
        __builtin_amdgcn_s_setprio(1);
        #pragma unroll
        for (int ks = 0; ks < 2; ++ks) {
            bf16x8 pa0 = *(const bf16x8*)&Pl[wave][(l16)      * LP + ks * 32 + quad * 8];
            bf16x8 pa1 = *(const bf16x8*)&Pl[wave][(16 + l16) * LP + ks * 32 + quad * 8];
            rsa[0] = mfma16(pa0, one8, rsa[0]);
            rsa[1] = mfma16(pa1, one8, rsa[1]);
            #pragma unroll
            for (int cc = 0; cc < 4; ++cc) {
                bf16x8 bv = *(const bf16x8*)&Vt [(cc * 16 + l16) * LP + ks * 32 + quad * 8];
                ov[0][cc]  = mfma16(pa0, bv, ov[0][cc]);
                ov[1][cc]  = mfma16(pa1, bv, ov[1][cc]);
                bf16x8 bx = *(const bf16x8*)&xVt[(cc * 16 + l16) * LP + ks * 32 + quad * 8];
                oxv[0][cc] = mfma16(pa0, bx, oxv[0][cc]);
                oxv[1][cc] = mfma16(pa1, bx, oxv[1][cc]);
            }
        }
        __builtin_amdgcn_s_setprio(0);

        // E: protect Vt/xVt overwrite next iter
        __builtin_amdgcn_sched_barrier(0);
        __builtin_amdgcn_s_barrier();
        c ^= 1;
    }

    // epilogue: rsa[mf][r] holds the row-sum for q-row mf*16+quad*4+r,
    // broadcast across l16 — normalize directly, no reduction needed.
    #pragma unroll
    for (int mf = 0; mf < 2; ++mf)
        #pragma unroll
        for (int r = 0; r < 4; ++r) {
            const int qrow = mf * 16 + quad * 4 + r;
            const float inv = 1.0f / rsa[mf][r];
            const size_t base = hb + (size_t)(q0 + qrow) * DH;
            #pragma unroll
            for (int cc = 0; cc < 4; ++cc) {
                const int d = cc * 16 + l16;
                Q [base + d] = (bf16)(oxv[mf][cc][r] * inv);   // kbar in place
                VB[base + d] = (bf16)(ov[mf][cc][r]  * inv);
            }
        }
}

// ======================= legacy (R6, proven) fallback =======================

__global__ __launch_bounds__(256) void proj_gemm(
    const void* __restrict__ Xv, const float* __restrict__ W,
    const float* __restrict__ bias, void* __restrict__ Yv,
    int in_kind, int out_mode)
{
    __shared__ __align__(16) bf16 As[64 * LP];
    __shared__ __align__(16) bf16 Bs[128 * LP];
    const int tid  = threadIdx.x;
    const int wave = tid >> 6;
    const int lane = tid & 63;
    const int l16  = lane & 15;
    const int quad = lane >> 4;
    const int m0 = blockIdx.y * 64;
    const int n0 = blockIdx.x * 128;
    const int m_w = (wave >> 1) * 32;
    const int n_w = (wave & 1) * 64;
    const int ar = tid >> 2, ac = (tid & 3) * 16;
    const int br = tid >> 1, bc = (tid & 1) * 32;

    f32x4 acc[2][4];
    #pragma unroll
    for (int i = 0; i < 2; ++i)
        #pragma unroll
        for (int j = 0; j < 4; ++j) acc[i][j] = (f32x4){0.f,0.f,0.f,0.f};

    for (int kb = 0; kb < DX / 64; ++kb) {
        __syncthreads();
        if (in_kind == 0) {
            const float* xp = (const float*)Xv + (size_t)(m0 + ar) * DX + kb * 64 + ac;
            *(bf16x8*)&As[ar * LP + ac]     = cvt8(xp);
            *(bf16x8*)&As[ar * LP + ac + 8] = cvt8(xp + 8);
        } else {
            const bf16* xp = (const bf16*)Xv + ((size_t)kb * SEQ + (m0 + ar)) * DH + ac;
            *(bf16x8*)&As[ar * LP + ac]     = *(const bf16x8*)xp;
            *(bf16x8*)&As[ar * LP + ac + 8] = *(const bf16x8*)(xp + 8);
        }
        {
            const float* wp = W + (size_t)(n0 + br) * DX + kb * 64 + bc;
            #pragma unroll
            for (int g = 0; g < 4; ++g)
                *(bf16x8*)&Bs[br * LP + bc + g * 8] = cvt8(wp + g * 8);
        }
        __syncthreads();
        #pragma unroll
        for (int ks = 0; ks < 2; ++ks) {
            bf16x8 a0 = *(const bf16x8*)&As[(m_w + l16)      * LP + ks * 32 + quad * 8];
            bf16x8 a1 = *(const bf16x8*)&As[(m_w + 16 + l16) * LP + ks * 32 + quad * 8];
            #pragma unroll
            for (int nf = 0; nf < 4; ++nf) {
                bf16x8 b = *(const bf16x8*)&Bs[(n_w + nf * 16 + l16) * LP + ks * 32 + quad * 8];
                acc[0][nf] = mfma16(a0, b, acc[0][nf]);
                acc[1][nf] = mfma16(a1, b, acc[1][nf]);
            }
        }
    }
    #pragma unroll
    for (int mf = 0; mf < 2; ++mf)
        #pragma unroll
        for (int nf = 0; nf < 4; ++nf) {
            const int col = n0 + n_w + nf * 16 + l16;
            const float bvv = bias[col];
            #pragma unroll
            for (int r = 0; r < 4; ++r) {
                const int row = m0 + m_w + mf * 16 + quad * 4 + r;
                float v = acc[mf][nf][r] + bvv;
                if (out_mode == 0) {
                    int h = col >> 6, d = col & 63;
                    ((bf16*)Yv)[((size_t)h * SEQ + row) * DH + d] = (bf16)v;
                } else {
                    ((float*)Yv)[(size_t)row * DX + col] = v;
                }
            }
        }
}

__global__ __launch_bounds__(256) void attn_dual(
    bf16* __restrict__ Q, const bf16* __restrict__ K,
    const bf16* __restrict__ V, const bf16* __restrict__ xV,
    bf16* __restrict__ vb)
{
    __shared__ __align__(16) bf16 Ks [64 * LP];
    __shared__ __align__(16) bf16 Vt [64 * LP];
    __shared__ __align__(16) bf16 xVt[64 * LP];
    __shared__ __align__(16) bf16 Pl[4][32 * LP];
    const int tid  = threadIdx.x;
    const int h    = blockIdx.y;
    const int qt   = blockIdx.x;
    const int wave = tid >> 6;
    const int lane = tid & 63;
    const int l16  = lane & 15;
    const int quad = lane >> 4;
    const size_t hb = (size_t)h * SEQ * DH;
    const int q0 = qt * 128 + wave * 32;

    bf16x8 qf[2][2];
    #pragma unroll
    for (int mf = 0; mf < 2; ++mf)
        #pragma unroll
        for (int ks = 0; ks < 2; ++ks)
            qf[mf][ks] = *(const bf16x8*)(Q + hb + (size_t)(q0 + mf*16 + l16) * DH + ks*32 + quad*8);

    float mr[2][4], lr[2][4];
    f32x4 ov[2][4], oxv[2][4];
    #pragma unroll
    for (int mf = 0; mf < 2; ++mf)
        #pragma unroll
        for (int r = 0; r < 4; ++r) { mr[mf][r] = -1e30f; lr[mf][r] = 0.f; }
    #pragma unroll
    for (int mf = 0; mf < 2; ++mf)
        #pragma unroll
        for (int c = 0; c < 4; ++c) {
            ov[mf][c]  = (f32x4){0.f,0.f,0.f,0.f};
            oxv[mf][c] = (f32x4){0.f,0.f,0.f,0.f};
        }
    const int sr = tid >> 2, sc = (tid & 3) * 16;
    const int vkp = (tid & 31) * 2;
    const int vd0 = (tid >> 5) * 8;
    const float SCL = 0.125f * 1.4426950408889634f;

    for (int kt = 0; kt < SEQ; kt += 64) {
        __syncthreads();
        {
            const bf16* kpt = K + hb + (size_t)(kt + sr) * DH + sc;
            *(bf16x8*)&Ks[sr * LP + sc]     = *(const bf16x8*)kpt;
            *(bf16x8*)&Ks[sr * LP + sc + 8] = *(const bf16x8*)(kpt + 8);
            const size_t g0 = hb + (size_t)(kt + vkp) * DH + vd0;
            bf16x8 v0 = *(const bf16x8*)(V + g0);
            bf16x8 v1 = *(const bf16x8*)(V + g0 + DH);
            bf16x8 x0 = *(const bf16x8*)(xV + g0);
            bf16x8 x1 = *(const bf16x8*)(xV + g0 + DH);
            #pragma unroll
            for (int j = 0; j < 8; ++j) {
                *(bf16x2*)&Vt [(vd0 + j) * LP + vkp] = (bf16x2){v0[j], v1[j]};
                *(bf16x2*)&xVt[(vd0 + j) * LP + vkp] = (bf16x2){x0[j], x1[j]};
            }
        }
        __syncthreads();
        f32x4 sf[2][4];
        #pragma unroll
        for (int mf = 0; mf < 2; ++mf)
            #pragma unroll
            for (int nf = 0; nf < 4; ++nf) sf[mf][nf] = (f32x4){0.f,0.f,0.f,0.f};
        #pragma unroll
        for (int ks = 0; ks < 2; ++ks)
            #pragma unroll
            for (int nf = 0; nf < 4; ++nf) {
                bf16x8 bk = *(const bf16x8*)&Ks[(nf * 16 + l16) * LP + ks * 32 + quad * 8];
                sf[0][nf] = mfma16(qf[0][ks], bk, sf[0][nf]);
                sf[1][nf] = mfma16(qf[1][ks], bk, sf[1][nf]);
            }
        float mx[2][4], rs[2][4], alpha[2][4];
        #pragma unroll
        for (int mf = 0; mf < 2; ++mf)
            #pragma unroll
            for (int r = 0; r < 4; ++r) {
                float aa = fmaxf(sf[mf][0][r], sf[mf][1][r]);
                float bb = fmaxf(sf[mf][2][r], sf[mf][3][r]);
                mx[mf][r] = fmaxf(aa, bb) * SCL;
            }
        #pragma unroll
        for (int off = 1; off < 16; off <<= 1)
            #pragma unroll
            for (int mf = 0; mf < 2; ++mf)
                #pragma unroll
                for (int r = 0; r < 4; ++r)
                    mx[mf][r] = fmaxf(mx[mf][r], __shfl_xor(mx[mf][r], off, 64));
        #pragma unroll
        for (int mf = 0; mf < 2; ++mf)
            #pragma unroll
            for (int r = 0; r < 4; ++r) {
                float mnew = fmaxf(mr[mf][r], mx[mf][r]);
                alpha[mf][r] = exp2f(mr[mf][r] - mnew);
                mr[mf][r] = mnew;
            }
        bf16* pw = &Pl[wave][0];
        #pragma unroll
        for (int mf = 0; mf < 2; ++mf)
            #pragma unroll
            for (int r = 0; r < 4; ++r) rs[mf][r] = 0.f;
        #pragma unroll
        for (int mf = 0; mf < 2; ++mf)
            #pragma unroll
            for (int nf = 0; nf < 4; ++nf)
                #pragma unroll
                for (int r = 0; r < 4; ++r) {
                    float p = exp2f(sf[mf][nf][r] * SCL - mr[mf][r]);
                    rs[mf][r] += p;
                    pw[(mf * 16 + quad * 4 + r) * LP + nf * 16 + l16] = (bf16)p;
                }
        #pragma unroll
        for (int off = 1; off < 16; off <<= 1)
            #pragma unroll
            for (int mf = 0; mf < 2; ++mf)
                #pragma unroll
                for (int r = 0; r < 4; ++r)
                    rs[mf][r] += __shfl_xor(rs[mf][r], off, 64);
        #pragma unroll
        for (int mf = 0; mf < 2; ++mf)
            #pragma unroll
            for (int r = 0; r < 4; ++r)
                lr[mf][r] = lr[mf][r] * alpha[mf][r] + rs[mf][r];
        #pragma unroll
        for (int mf = 0; mf < 2; ++mf)
            #pragma unroll
            for (int c = 0; c < 4; ++c)
                #pragma unroll
                for (int r = 0; r < 4; ++r) {
                    ov[mf][c][r]  *= alpha[mf][r];
                    oxv[mf][c][r] *= alpha[mf][r];
                }
        __asm__ volatile("s_waitcnt lgkmcnt(0)" ::: "memory");
        #pragma unroll
        for (int ks = 0; ks < 2; ++ks) {
            bf16x8 pa0 = *(const bf16x8*)&Pl[wave][(l16)      * LP + ks * 32 + quad * 8];
            bf16x8 pa1 = *(const bf16x8*)&Pl[wave][(16 + l16) * LP + ks * 32 + quad * 8];
            #pragma unroll
            for (int c = 0; c < 4; ++c) {
                bf16x8 bv = *(const bf16x8*)&Vt [(c * 16 + l16) * LP + ks * 32 + quad * 8];
                ov[0][c]  = mfma16(pa0, bv, ov[0][c]);
                ov[1][c]  = mfma16(pa1, bv, ov[1][c]);
                bf16x8 bx = *(const bf16x8*)&xVt[(c * 16 + l16) * LP + ks * 32 + quad * 8];
                oxv[0][c] = mfma16(pa0, bx, oxv[0][c]);
                oxv[1][c] = mfma16(pa1, bx, oxv[1][c]);
            }
        }
    }
    #pragma unroll
    for (int mf = 0; mf < 2; ++mf)
        #pragma unroll
        for (int r = 0; r < 4; ++r) {
            const int s = q0 + mf * 16 + quad * 4 + r;
            const float inv = 1.0f / lr[mf][r];
            #pragma unroll
            for (int c = 0; c < 4; ++c) {
                const int d = c * 16 + l16;
                Q [hb + (size_t)s * DH + d] = (bf16)(oxv[mf][c][r] * inv);
                vb[hb + (size_t)s * DH + d] = (bf16)(ov[mf][c][r]  * inv);
            }
        }
}

// ================================ launch ====================================

extern "C" void kernel_launch(void* const* d_in, const int* in_sizes, int n_in,
                              void* d_out, int out_size, void* d_ws, size_t ws_size,
                              hipStream_t stream) {
    const float* query = (const float*)d_in[0];
    const float* key   = (const float*)d_in[1];
    const float* value = (const float*)d_in[2];
    const float* Wq  = (const float*)d_in[3];  const float* bq  = (const float*)d_in[4];
    const float* Wk  = (const float*)d_in[5];  const float* bk  = (const float*)d_in[6];
    const float* Wv  = (const float*)d_in[7];  const float* bv  = (const float*)d_in[8];
    const float* Wxv = (const float*)d_in[9];  const float* bxv = (const float*)d_in[10];
    const float* Wxo = (const float*)d_in[11]; const float* bxo = (const float*)d_in[12];
    const float* Wmo = (const float*)d_in[13]; const float* bmo = (const float*)d_in[14];

    float* out = (float*)d_out;
    const size_t SB = (size_t)SEQ * DX;          // 2,097,152 el
    const size_t M1 = 1ull << 20;

    dim3 blk(256);

    if (ws_size >= (76ull << 20)) {
        // ---------------- Plan A: merged batches, bf16 everywhere -----------
        bf16* ws = (bf16*)d_ws;
        bf16* qb  = ws;                 // 4M el
        bf16* kb  = ws + 4 * M1;
        bf16* vb  = ws + 8 * M1;
        bf16* Wqb = ws + 12 * M1;       // 6 x 1M el
        bf16* Wkb = Wqb + M1;
        bf16* Wvb = Wkb + M1;
        bf16* Wxvb= Wvb + M1;
        bf16* Wxob= Wxvb + M1;
        bf16* Wmob= Wxob + M1;
        bf16* Qs  = ws + 18 * M1;       // bhsd [2][16][2048][64], 4M el each
        bf16* Kss = ws + 22 * M1;
        bf16* Vs  = ws + 26 * M1;
        bf16* xVs = ws + 30 * M1;
        bf16* VBs = ws + 34 * M1;

        cvt_all<<<9216, blk, 0, stream>>>(query, key, value,
                                          Wq, Wk, Wv, Wxv, Wxo, Wmo, ws + 0);
        // note: cvt_all writes segments in order q,k,v,W* starting at ws —
        // matches qb/kb/vb/Wqb.. layout above.

        G4 g1;
        g1.X[0]=qb;  g1.W[0]=Wqb;  g1.B[0]=bq;  g1.Yb[0]=Qs;  g1.Yf[0]=nullptr; g1.xmode[0]=0; g1.ymode[0]=0;
        g1.X[1]=kb;  g1.W[1]=Wkb;  g1.B[1]=bk;  g1.Yb[1]=Kss; g1.Yf[1]=nullptr; g1.xmode[1]=0; g1.ymode[1]=0;
        g1.X[2]=vb;  g1.W[2]=Wvb;  g1.B[2]=bv;  g1.Yb[2]=Vs;  g1.Yf[2]=nullptr; g1.xmode[2]=0; g1.ymode[2]=0;
        g1.X[3]=kb;  g1.W[3]=Wxvb; g1.B[3]=bxv; g1.Yb[3]=xVs; g1.Yf[3]=nullptr; g1.xmode[3]=0; g1.ymode[3]=0;
        gemm_fused<<<dim3(8, 32, 4), blk, 0, stream>>>(g1);

        attn_fast<<<dim3(16, NH, 2), blk, 0, stream>>>(Qs, Kss, Vs, xVs, VBs);

        G4 g2;
        g2.X[0]=Qs;  g2.W[0]=Wxob; g2.B[0]=bxo; g2.Yb[0]=nullptr; g2.Yf[0]=out;          g2.xmode[0]=1; g2.ymode[0]=1;
        g2.X[1]=VBs; g2.W[1]=Wmob; g2.B[1]=bmo; g2.Yb[1]=nullptr; g2.Yf[1]=out + 2*SB;   g2.xmode[1]=1; g2.ymode[1]=1;
        g2.X[2]=Qs;  g2.W[2]=Wxob; g2.B[2]=bxo; g2.Yb[2]=nullptr; g2.Yf[2]=out;          g2.xmode[2]=1; g2.ymode[2]=1;
        g2.X[3]=Qs;  g2.W[3]=Wxob; g2.B[3]=bxo; g2.Yb[3]=nullptr; g2.Yf[3]=out;          g2.xmode[3]=1; g2.ymode[3]=1;
        gemm_fused<<<dim3(8, 32, 2), blk, 0, stream>>>(g2);
    } else {
        // ---------------- fallback: proven R6 path (20 MB ws) ---------------
        bf16* Qs  = (bf16*)d_ws;
        bf16* Ksb = Qs  + SB;
        bf16* Vs  = Ksb + SB;
        bf16* xVs = Vs  + SB;
        bf16* vbs = xVs + SB;
        dim3 pg(8, 32);
        dim3 ag(16, NH);
        for (int b = 0; b < 2; ++b) {
            const float* q_b = query + (size_t)b * SB;
            const float* k_b = key   + (size_t)b * SB;
            const float* v_b = value + (size_t)b * SB;
            float* x_b = out + (size_t)b * SB;
            float* m_b = out + 2 * SB + (size_t)b * SB;
            proj_gemm<<<pg, blk, 0, stream>>>(q_b, Wq,  bq,  Qs,  0, 0);
            proj_gemm<<<pg, blk, 0, stream>>>(k_b, Wk,  bk,  Ksb, 0, 0);
            proj_gemm<<<pg, blk, 0, stream>>>(v_b, Wv,  bv,  Vs,  0, 0);
            proj_gemm<<<pg, blk, 0, stream>>>(k_b, Wxv, bxv, xVs, 0, 0);
            attn_dual<<<ag, blk, 0, stream>>>(Qs, Ksb, Vs, xVs, vbs);
            proj_gemm<<<pg, blk, 0, stream>>>(Qs,  Wxo, bxo, x_b, 1, 1);
            proj_gemm<<<pg, blk, 0, stream>>>(vbs, Wmo, bmo, m_b, 1, 1);
        }
    }
}

// Round 3
// 290.929 us; speedup vs baseline: 1.1135x; 1.0422x over previous
//
#include <hip/hip_runtime.h>
#include <math.h>

typedef __bf16 bf16;
typedef __bf16 bf16x2 __attribute__((ext_vector_type(2)));
typedef __bf16 bf16x4 __attribute__((ext_vector_type(4)));
typedef __bf16 bf16x8 __attribute__((ext_vector_type(8)));
typedef float f32x4 __attribute__((ext_vector_type(4)));

#define SEQ 2048
#define DH 64
#define DX 1024
#define NH 16
#define LP 72   // padded LDS row stride (64+8)

static __device__ __forceinline__ f32x4 mfma16(bf16x8 a, bf16x8 b, f32x4 c) {
    return __builtin_amdgcn_mfma_f32_16x16x32_bf16(a, b, c, 0, 0, 0);
}
static __device__ __forceinline__ bf16x8 cvt8(const float* __restrict__ p) {
    f32x4 a = *(const f32x4*)p;
    f32x4 b = *(const f32x4*)(p + 4);
    bf16x8 r;
    #pragma unroll
    for (int j = 0; j < 4; ++j) { r[j] = (bf16)a[j]; r[4 + j] = (bf16)b[j]; }
    return r;
}

// async global->LDS, 16 B per lane (lands at ldsbase + lane*16)
#define GL16(gp, lp) __builtin_amdgcn_global_load_lds( \
    (const __attribute__((address_space(1))) void*)(gp), \
    (__attribute__((address_space(3))) void*)(lp), 16, 0, 0)

// ============================ PLAN A kernels ================================

// f32 -> bf16 bulk convert: 3 inputs (4M el each) + 6 weights (1M el each)
// into ws at fixed offsets. 18M elements, 8 per thread.
__global__ __launch_bounds__(256) void cvt_all(
    const float* __restrict__ q, const float* __restrict__ k,
    const float* __restrict__ v,
    const float* __restrict__ w0, const float* __restrict__ w1,
    const float* __restrict__ w2, const float* __restrict__ w3,
    const float* __restrict__ w4, const float* __restrict__ w5,
    bf16* __restrict__ out)
{
    const size_t i = (size_t)blockIdx.x * 2048 + threadIdx.x * 8;
    const int seg = (int)(i >> 20);
    const float* s;
    size_t off;
    if (seg < 4)       { s = q; off = i; }
    else if (seg < 8)  { s = k; off = i - (4ull << 20); }
    else if (seg < 12) { s = v; off = i - (8ull << 20); }
    else {
        const float* ww[6] = {w0, w1, w2, w3, w4, w5};
        s = ww[seg - 12]; off = i - ((size_t)seg << 20);
    }
    *(bf16x8*)(out + i) = cvt8(s + off);
}

// fused multi-GEMM: Y_z = X_z @ W_z^T + bias_z, M=4096, N=K=1024, all bf16 in.
// xmode: 0 = X row-major [4096][1024]; 1 = X bhsd [2][16][2048][64]
// ymode: 0 = Y bf16 bhsd;              1 = Y f32 row-major
struct G4 {
    const bf16* X[4]; const bf16* W[4]; const float* B[4];
    bf16* Yb[4]; float* Yf[4]; int xmode[4]; int ymode[4];
};

// R3: 256-wide-N tile, BK=64, 8 waves (2M x 4N), double-buffered LDS,
// T3 minimum-2-phase schedule: per K-tile {STAGE(buf^1,t+1) -> compute
// buf[cur] -> ONE __syncthreads (vmcnt+lgkm drain)}. GL16 staging with
// both-sides XOR swizzle (chunk ^= row&7): linear GL16 dest, pre-swizzled
// global source, swizzled ds_read -> conflict-free b128 fragment reads.
// BM template: 256 for g1 (grid 4x16xZ), 128 for g2 (grid 4x32xZ, keeps
// 256 wg so all CUs stay covered).
template<int BM>
__global__ __launch_bounds__(512) void gemm256(G4 a)
{
    constexpr int MREP = BM / 32;           // M fragments per wave (8 or 4)
    __shared__ __align__(16) bf16 As[2][BM * 64];
    __shared__ __align__(16) bf16 Bs[2][256 * 64];

    const int z = blockIdx.z;
    const bf16* __restrict__ X = a.X[z];
    const bf16* __restrict__ W = a.W[z];
    const int xmode = a.xmode[z], ymode = a.ymode[z];

    const int tid  = threadIdx.x;
    const int wid  = tid >> 6;
    const int lane = tid & 63;
    const int l16  = lane & 15;
    const int quad = lane >> 4;
    const int wm   = wid >> 2;              // 0..1
    const int wn   = wid & 3;               // 0..3
    const int m0 = blockIdx.y * BM;
    const int n0 = blockIdx.x * 256;

    // staging geometry: per GL16 call a wave covers 8 rows x 64 cols.
    // LDS[row][c] = global[row][c ^ (row&7)]  (linear dest, swizzled src)
    const int srow8 = lane >> 3;            // row within 8-row group
    const int sch   = (lane & 7) ^ srow8;   // pre-swizzled source chunk

    f32x4 acc[MREP][4];
    #pragma unroll
    for (int i = 0; i < MREP; ++i)
        #pragma unroll
        for (int j = 0; j < 4; ++j) acc[i][j] = (f32x4){0.f,0.f,0.f,0.f};

    auto stage = [&](int buf, int kb) {
        #pragma unroll
        for (int g = 0; g < BM / 64; ++g) {
            const int row = g * 64 + wid * 8 + srow8;   // row in A tile
            const bf16* src;
            if (xmode == 0) {
                src = X + (size_t)(m0 + row) * DX + kb * 64 + sch * 8;
            } else {
                const int m = m0 + row;
                const int b = m >> 11, s = m & 2047;
                src = X + ((size_t)(b * NH + kb) * SEQ + s) * DH + sch * 8;
            }
            GL16(src, &As[buf][(g * 64 + wid * 8) * 64]);
        }
        #pragma unroll
        for (int g = 0; g < 4; ++g) {
            const int row = g * 64 + wid * 8 + srow8;   // row in B tile
            const bf16* src = W + (size_t)(n0 + row) * DX + kb * 64 + sch * 8;
            GL16(src, &Bs[buf][(g * 64 + wid * 8) * 64]);
        }
    };

    stage(0, 0);
    __syncthreads();

    int cur = 0;
    for (int kb = 0; kb < DX / 64; ++kb) {
        if (kb + 1 < DX / 64) stage(cur ^ 1, kb + 1);   // flies under MFMA
        #pragma unroll
        for (int ks = 0; ks < 2; ++ks) {
            bf16x8 af[MREP], bfr[4];
            const int cc = (ks * 4 + quad) ^ (l16 & 7); // swizzled chunk
            #pragma unroll
            for (int mf = 0; mf < MREP; ++mf)
                af[mf] = *(const bf16x8*)&As[cur][(wm * (BM/2) + mf * 16 + l16) * 64 + cc * 8];
            #pragma unroll
            for (int nf = 0; nf < 4; ++nf)
                bfr[nf] = *(const bf16x8*)&Bs[cur][(wn * 64 + nf * 16 + l16) * 64 + cc * 8];
            #pragma unroll
            for (int mf = 0; mf < MREP; ++mf)
                #pragma unroll
                for (int nf = 0; nf < 4; ++nf)
                    acc[mf][nf] = mfma16(af[mf], bfr[nf], acc[mf][nf]);
        }
        __syncthreads();   // drains vmcnt -> next buffer staged & visible
        cur ^= 1;
    }

    #pragma unroll
    for (int nf = 0; nf < 4; ++nf) {
        const int col = n0 + wn * 64 + nf * 16 + l16;
        const float bvv = a.B[z][col];
        #pragma unroll
        for (int mf = 0; mf < MREP; ++mf) {
            #pragma unroll
            for (int r = 0; r < 4; ++r) {
                const int row = m0 + wm * (BM/2) + mf * 16 + quad * 4 + r;
                const float vv = acc[mf][nf][r] + bvv;
                if (ymode == 0) {
                    const int b = row >> 11, s = row & 2047;
                    const int h = col >> 6, d = col & 63;
                    a.Yb[z][((size_t)(b * NH + h) * SEQ + s) * DH + d] = (bf16)vv;
                } else {
                    a.Yf[z][(size_t)row * DX + col] = vv;
                }
            }
        }
    }
}

// dual flash attention, both batches: grid (qt 16, h 16, b 2), block 256.
// R1: software-pipelined staging (GL16 K dbuf + reg-prefetch V/xV, counted
//     vmcnt(6), setprio around MFMA clusters).
// R2: VALU-diet softmax (row-sum via MFMA P@1, raw v_exp_f32).
__global__ __launch_bounds__(256) void attn_fast(
    bf16* __restrict__ Q, const bf16* __restrict__ K,
    const bf16* __restrict__ V, const bf16* __restrict__ xV,
    bf16* __restrict__ VB)
{
    __shared__ __align__(16) bf16 Ks[2][64 * 64];   // unpadded, XOR-swizzled
    __shared__ __align__(16) bf16 Vt [64 * LP];
    __shared__ __align__(16) bf16 xVt[64 * LP];
    __shared__ __align__(16) bf16 Pl[4][32 * LP];

    const int tid  = threadIdx.x;
    const int wave = tid >> 6;
    const int lane = tid & 63;
    const int l16  = lane & 15;
    const int quad = lane >> 4;
    const size_t hb = ((size_t)blockIdx.z * NH + blockIdx.y) * SEQ * DH;
    const int q0 = blockIdx.x * 128 + wave * 32;

    bf16x8 qf[2][2];
    #pragma unroll
    for (int mf = 0; mf < 2; ++mf)
        #pragma unroll
        for (int ks = 0; ks < 2; ++ks)
            qf[mf][ks] = *(const bf16x8*)(Q + hb + (size_t)(q0 + mf*16 + l16) * DH + ks*32 + quad*8);

    bf16x8 one8;
    #pragma unroll
    for (int j = 0; j < 8; ++j) one8[j] = (bf16)1.0f;

    f32x4 ov[2][4], oxv[2][4];
    f32x4 rsa[2];
    rsa[0] = (f32x4){0.f,0.f,0.f,0.f};
    rsa[1] = (f32x4){0.f,0.f,0.f,0.f};
    #pragma unroll
    for (int mf = 0; mf < 2; ++mf)
        #pragma unroll
        for (int c = 0; c < 4; ++c) {
            ov[mf][c]  = (f32x4){0.f,0.f,0.f,0.f};
            oxv[mf][c] = (f32x4){0.f,0.f,0.f,0.f};
        }

    // K staging via GL16: wave covers 16 rows (2 calls x 8 rows).
    const int krow = lane >> 3;             // 0..7
    const int kch  = (lane & 7) ^ krow;     // pre-swizzled source chunk
    // V/xV transpose staging geometry
    const int vkp = (tid & 31) * 2;
    const int vd0 = (tid >> 5) * 8;
    const float SCL = 0.125f * 1.4426950408889634f;

    // ---- prologue: prefetch tile 0 (GL16 K first, then reg loads) ----
    bf16x8 pv0, pv1, px0, px1;
    {
        const bf16* kg = K + hb + (size_t)(wave*16 + krow) * DH + kch*8;
        GL16(kg,            &Ks[0][(wave*16 + 0) * 64]);
        GL16(kg + 8 * DH,   &Ks[0][(wave*16 + 8) * 64]);
        const size_t g0 = hb + (size_t)vkp * DH + vd0;
        pv0 = *(const bf16x8*)(V  + g0);
        pv1 = *(const bf16x8*)(V  + g0 + DH);
        px0 = *(const bf16x8*)(xV + g0);
        px1 = *(const bf16x8*)(xV + g0 + DH);
    }

    int c = 0;
    for (int kt = 0; kt < SEQ; kt += 64) {
        // A: commit prefetched V/xV into transposed LDS tiles
        #pragma unroll
        for (int j = 0; j < 8; ++j) {
            *(bf16x2*)&Vt [(vd0 + j) * LP + vkp] = (bf16x2){pv0[j], pv1[j]};
            *(bf16x2*)&xVt[(vd0 + j) * LP + vkp] = (bf16x2){px0[j], px1[j]};
        }
        // B: issue prefetch for tile t+1 (6 vmem ops; consumed next iter)
        if (kt + 64 < SEQ) {
            const bf16* kg = K + hb + (size_t)(kt + 64 + wave*16 + krow) * DH + kch*8;
            GL16(kg,          &Ks[c ^ 1][(wave*16 + 0) * 64]);
            GL16(kg + 8 * DH, &Ks[c ^ 1][(wave*16 + 8) * 64]);
            const size_t g0 = hb + (size_t)(kt + 64 + vkp) * DH + vd0;
            pv0 = *(const bf16x8*)(V  + g0);
            pv1 = *(const bf16x8*)(V  + g0 + DH);
            px0 = *(const bf16x8*)(xV + g0);
            px1 = *(const bf16x8*)(xV + g0 + DH);
        }
        // C: make staging visible to all waves; keep prefetch in flight
        __asm__ volatile("s_waitcnt lgkmcnt(0)" ::: "memory");
        __builtin_amdgcn_s_barrier();
        __asm__ volatile("s_waitcnt vmcnt(6)" ::: "memory");
        __builtin_amdgcn_sched_barrier(0);

        // D1: S^T = K Q^T  (keys as M; swizzled Ks read)
        f32x4 sf[4][2];
        #pragma unroll
        for (int mf = 0; mf < 4; ++mf)
            #pragma unroll
            for (int nf = 0; nf < 2; ++nf) sf[mf][nf] = (f32x4){0.f,0.f,0.f,0.f};
        __builtin_amdgcn_s_setprio(1);
        #pragma unroll
        for (int ks = 0; ks < 2; ++ks)
            #pragma unroll
            for (int mf = 0; mf < 4; ++mf) {
                bf16x8 kf = *(const bf16x8*)&Ks[c][(mf*16 + l16) * 64 +
                                                   (((ks*4 + quad) ^ (l16 & 7)) * 8)];
                sf[mf][0] = mfma16(kf, qf[0][ks], sf[mf][0]);
                sf[mf][1] = mfma16(kf, qf[1][ks], sf[mf][1]);
            }
        __builtin_amdgcn_s_setprio(0);

        // D2: P = exp2(S*scl) (raw v_exp_f32), packed b64 writes
        #pragma unroll
        for (int nf = 0; nf < 2; ++nf)
            #pragma unroll
            for (int mf = 0; mf < 4; ++mf) {
                float p0 = __builtin_amdgcn_exp2f(sf[mf][nf][0] * SCL);
                float p1 = __builtin_amdgcn_exp2f(sf[mf][nf][1] * SCL);
                float p2 = __builtin_amdgcn_exp2f(sf[mf][nf][2] * SCL);
                float p3 = __builtin_amdgcn_exp2f(sf[mf][nf][3] * SCL);
                *(bf16x4*)&Pl[wave][(nf * 16 + l16) * LP + mf * 16 + quad * 4] =
                    (bf16x4){(bf16)p0, (bf16)p1, (bf16)p2, (bf16)p3};
            }
        __asm__ volatile("s_waitcnt lgkmcnt(0)" ::: "memory");
        __builtin_amdgcn_sched_barrier(0);

        // D3: O += P@V, Oxv += P@xV, rs += P@1 (row-sum on the matrix pipe)
        __builtin_amdgcn_s_setprio(1);
        #pragma unroll
        for (int ks = 0; ks < 2; ++ks) {
            bf16x8 pa0 = *(const bf16x8*)&Pl[wave][(l16)      * LP + ks * 32 + quad * 8];
            bf16x8 pa1 = *(const bf16x8*)&Pl[wave][(16 + l16) * LP + ks * 32 + quad * 8];
            rsa[0] = mfma16(pa0, one8, rsa[0]);
            rsa[1] = mfma16(pa1, one8, rsa[1]);
            #pragma unroll
            for (int cc = 0; cc < 4; ++cc) {
                bf16x8 bv = *(const bf16x8*)&Vt [(cc * 16 + l16) * LP + ks * 32 + quad * 8];
                ov[0][cc]  = mfma16(pa0, bv, ov[0][cc]);
                ov[1][cc]  = mfma16(pa1, bv, ov[1][cc]);
                bf16x8 bx = *(const bf16x8*)&xVt[(cc * 16 + l16) * LP + ks * 32 + quad * 8];
                oxv[0][cc] = mfma16(pa0, bx, oxv[0][cc]);
                oxv[1][cc] = mfma16(pa1, bx, oxv[1][cc]);
            }
        }
        __builtin_amdgcn_s_setprio(0);

        // E: protect Vt/xVt overwrite next iter
        __builtin_amdgcn_sched_barrier(0);
        __builtin_amdgcn_s_barrier();
        c ^= 1;
    }

    // epilogue: rsa[mf][r] holds the row-sum for q-row mf*16+quad*4+r,
    // broadcast across l16 — normalize directly, no reduction needed.
    #pragma unroll
    for (int mf = 0; mf < 2; ++mf)
        #pragma unroll
        for (int r = 0; r < 4; ++r) {
            const int qrow = mf * 16 + quad * 4 + r;
            const float inv = 1.0f / rsa[mf][r];
            const size_t base = hb + (size_t)(q0 + qrow) * DH;
            #pragma unroll
            for (int cc = 0; cc < 4; ++cc) {
                const int d = cc * 16 + l16;
                Q [base + d] = (bf16)(oxv[mf][cc][r] * inv);   // kbar in place
                VB[base + d] = (bf16)(ov[mf][cc][r]  * inv);
            }
        }
}

// ======================= legacy (R6, proven) fallback =======================

__global__ __launch_bounds__(256) void proj_gemm(
    const void* __restrict__ Xv, const float* __restrict__ W,
    const float* __restrict__ bias, void* __restrict__ Yv,
    int in_kind, int out_mode)
{
    __shared__ __align__(16) bf16 As[64 * LP];
    __shared__ __align__(16) bf16 Bs[128 * LP];
    const int tid  = threadIdx.x;
    const int wave = tid >> 6;
    const int lane = tid & 63;
    const int l16  = lane & 15;
    const int quad = lane >> 4;
    const int m0 = blockIdx.y * 64;
    const int n0 = blockIdx.x * 128;
    const int m_w = (wave >> 1) * 32;
    const int n_w = (wave & 1) * 64;
    const int ar = tid >> 2, ac = (tid & 3) * 16;
    const int br = tid >> 1, bc = (tid & 1) * 32;

    f32x4 acc[2][4];
    #pragma unroll
    for (int i = 0; i < 2; ++i)
        #pragma unroll
        for (int j = 0; j < 4; ++j) acc[i][j] = (f32x4){0.f,0.f,0.f,0.f};

    for (int kb = 0; kb < DX / 64; ++kb) {
        __syncthreads();
        if (in_kind == 0) {
            const float* xp = (const float*)Xv + (size_t)(m0 + ar) * DX + kb * 64 + ac;
            *(bf16x8*)&As[ar * LP + ac]     = cvt8(xp);
            *(bf16x8*)&As[ar * LP + ac + 8] = cvt8(xp + 8);
        } else {
            const bf16* xp = (const bf16*)Xv + ((size_t)kb * SEQ + (m0 + ar)) * DH + ac;
            *(bf16x8*)&As[ar * LP + ac]     = *(const bf16x8*)xp;
            *(bf16x8*)&As[ar * LP + ac + 8] = *(const bf16x8*)(xp + 8);
        }
        {
            const float* wp = W + (size_t)(n0 + br) * DX + kb * 64 + bc;
            #pragma unroll
            for (int g = 0; g < 4; ++g)
                *(bf16x8*)&Bs[br * LP + bc + g * 8] = cvt8(wp + g * 8);
        }
        __syncthreads();
        #pragma unroll
        for (int ks = 0; ks < 2; ++ks) {
            bf16x8 a0 = *(const bf16x8*)&As[(m_w + l16)      * LP + ks * 32 + quad * 8];
            bf16x8 a1 = *(const bf16x8*)&As[(m_w + 16 + l16) * LP + ks * 32 + quad * 8];
            #pragma unroll
            for (int nf = 0; nf < 4; ++nf) {
                bf16x8 b = *(const bf16x8*)&Bs[(n_w + nf * 16 + l16) * LP + ks * 32 + quad * 8];
                acc[0][nf] = mfma16(a0, b, acc[0][nf]);
                acc[1][nf] = mfma16(a1, b, acc[1][nf]);
            }
        }
    }
    #pragma unroll
    for (int mf = 0; mf < 2; ++mf)
        #pragma unroll
        for (int nf = 0; nf < 4; ++nf) {
            const int col = n0 + n_w + nf * 16 + l16;
            const float bvv = bias[col];
            #pragma unroll
            for (int r = 0; r < 4; ++r) {
                const int row = m0 + m_w + mf * 16 + quad * 4 + r;
                float v = acc[mf][nf][r] + bvv;
                if (out_mode == 0) {
                    int h = col >> 6, d = col & 63;
                    ((bf16*)Yv)[((size_t)h * SEQ + row) * DH + d] = (bf16)v;
                } else {
                    ((float*)Yv)[(size_t)row * DX + col] = v;
                }
            }
        }
}

__global__ __launch_bounds__(256) void attn_dual(
    bf16* __restrict__ Q, const bf16* __restrict__ K,
    const bf16* __restrict__ V, const bf16* __restrict__ xV,
    bf16* __restrict__ vb)
{
    __shared__ __align__(16) bf16 Ks [64 * LP];
    __shared__ __align__(16) bf16 Vt [64 * LP];
    __shared__ __align__(16) bf16 xVt[64 * LP];
    __shared__ __align__(16) bf16 Pl[4][32 * LP];
    const int tid  = threadIdx.x;
    const int h    = blockIdx.y;
    const int qt   = blockIdx.x;
    const int wave = tid >> 6;
    const int lane = tid & 63;
    const int l16  = lane & 15;
    const int quad = lane >> 4;
    const size_t hb = (size_t)h * SEQ * DH;
    const int q0 = qt * 128 + wave * 32;

    bf16x8 qf[2][2];
    #pragma unroll
    for (int mf = 0; mf < 2; ++mf)
        #pragma unroll
        for (int ks = 0; ks < 2; ++ks)
            qf[mf][ks] = *(const bf16x8*)(Q + hb + (size_t)(q0 + mf*16 + l16) * DH + ks*32 + quad*8);

    float mr[2][4], lr[2][4];
    f32x4 ov[2][4], oxv[2][4];
    #pragma unroll
    for (int mf = 0; mf < 2; ++mf)
        #pragma unroll
        for (int r = 0; r < 4; ++r) { mr[mf][r] = -1e30f; lr[mf][r] = 0.f; }
    #pragma unroll
    for (int mf = 0; mf < 2; ++mf)
        #pragma unroll
        for (int c = 0; c < 4; ++c) {
            ov[mf][c]  = (f32x4){0.f,0.f,0.f,0.f};
            oxv[mf][c] = (f32x4){0.f,0.f,0.f,0.f};
        }
    const int sr = tid >> 2, sc = (tid & 3) * 16;
    const int vkp = (tid & 31) * 2;
    const int vd0 = (tid >> 5) * 8;
    const float SCL = 0.125f * 1.4426950408889634f;

    for (int kt = 0; kt < SEQ; kt += 64) {
        __syncthreads();
        {
            const bf16* kpt = K + hb + (size_t)(kt + sr) * DH + sc;
            *(bf16x8*)&Ks[sr * LP + sc]     = *(const bf16x8*)kpt;
            *(bf16x8*)&Ks[sr * LP + sc + 8] = *(const bf16x8*)(kpt + 8);
            const size_t g0 = hb + (size_t)(kt + vkp) * DH + vd0;
            bf16x8 v0 = *(const bf16x8*)(V + g0);
            bf16x8 v1 = *(const bf16x8*)(V + g0 + DH);
            bf16x8 x0 = *(const bf16x8*)(xV + g0);
            bf16x8 x1 = *(const bf16x8*)(xV + g0 + DH);
            #pragma unroll
            for (int j = 0; j < 8; ++j) {
                *(bf16x2*)&Vt [(vd0 + j) * LP + vkp] = (bf16x2){v0[j], v1[j]};
                *(bf16x2*)&xVt[(vd0 + j) * LP + vkp] = (bf16x2){x0[j], x1[j]};
            }
        }
        __syncthreads();
        f32x4 sf[2][4];
        #pragma unroll
        for (int mf = 0; mf < 2; ++mf)
            #pragma unroll
            for (int nf = 0; nf < 4; ++nf) sf[mf][nf] = (f32x4){0.f,0.f,0.f,0.f};
        #pragma unroll
        for (int ks = 0; ks < 2; ++ks)
            #pragma unroll
            for (int nf = 0; nf < 4; ++nf) {
                bf16x8 bk = *(const bf16x8*)&Ks[(nf * 16 + l16) * LP + ks * 32 + quad * 8];
                sf[0][nf] = mfma16(qf[0][ks], bk, sf[0][nf]);
                sf[1][nf] = mfma16(qf[1][ks], bk, sf[1][nf]);
            }
        float mx[2][4], rs[2][4], alpha[2][4];
        #pragma unroll
        for (int mf = 0; mf < 2; ++mf)
            #pragma unroll
            for (int r = 0; r < 4; ++r) {
                float aa = fmaxf(sf[mf][0][r], sf[mf][1][r]);
                float bb = fmaxf(sf[mf][2][r], sf[mf][3][r]);
                mx[mf][r] = fmaxf(aa, bb) * SCL;
            }
        #pragma unroll
        for (int off = 1; off < 16; off <<= 1)
            #pragma unroll
            for (int mf = 0; mf < 2; ++mf)
                #pragma unroll
                for (int r = 0; r < 4; ++r)
                    mx[mf][r] = fmaxf(mx[mf][r], __shfl_xor(mx[mf][r], off, 64));
        #pragma unroll
        for (int mf = 0; mf < 2; ++mf)
            #pragma unroll
            for (int r = 0; r < 4; ++r) {
                float mnew = fmaxf(mr[mf][r], mx[mf][r]);
                alpha[mf][r] = exp2f(mr[mf][r] - mnew);
                mr[mf][r] = mnew;
            }
        bf16* pw = &Pl[wave][0];
        #pragma unroll
        for (int mf = 0; mf < 2; ++mf)
            #pragma unroll
            for (int r = 0; r < 4; ++r) rs[mf][r] = 0.f;
        #pragma unroll
        for (int mf = 0; mf < 2; ++mf)
            #pragma unroll
            for (int nf = 0; nf < 4; ++nf)
                #pragma unroll
                for (int r = 0; r < 4; ++r) {
                    float p = exp2f(sf[mf][nf][r] * SCL - mr[mf][r]);
                    rs[mf][r] += p;
                    pw[(mf * 16 + quad * 4 + r) * LP + nf * 16 + l16] = (bf16)p;
                }
        #pragma unroll
        for (int off = 1; off < 16; off <<= 1)
            #pragma unroll
            for (int mf = 0; mf < 2; ++mf)
                #pragma unroll
                for (int r = 0; r < 4; ++r)
                    rs[mf][r] += __shfl_xor(rs[mf][r], off, 64);
        #pragma unroll
        for (int mf = 0; mf < 2; ++mf)
            #pragma unroll
            for (int r = 0; r < 4; ++r)
                lr[mf][r] = lr[mf][r] * alpha[mf][r] + rs[mf][r];
        #pragma unroll
        for (int mf = 0; mf < 2; ++mf)
            #pragma unroll
            for (int c = 0; c < 4; ++c)
                #pragma unroll
                for (int r = 0; r < 4; ++r) {
                    ov[mf][c][r]  *= alpha[mf][r];
                    oxv[mf][c][r] *= alpha[mf][r];
                }
        __asm__ volatile("s_waitcnt lgkmcnt(0)" ::: "memory");
        #pragma unroll
        for (int ks = 0; ks < 2; ++ks) {
            bf16x8 pa0 = *(const bf16x8*)&Pl[wave][(l16)      * LP + ks * 32 + quad * 8];
            bf16x8 pa1 = *(const bf16x8*)&Pl[wave][(16 + l16) * LP + ks * 32 + quad * 8];
            #pragma unroll
            for (int c = 0; c < 4; ++c) {
                bf16x8 bv = *(const bf16x8*)&Vt [(c * 16 + l16) * LP + ks * 32 + quad * 8];
                ov[0][c]  = mfma16(pa0, bv, ov[0][c]);
                ov[1][c]  = mfma16(pa1, bv, ov[1][c]);
                bf16x8 bx = *(const bf16x8*)&xVt[(c * 16 + l16) * LP + ks * 32 + quad * 8];
                oxv[0][c] = mfma16(pa0, bx, oxv[0][c]);
                oxv[1][c] = mfma16(pa1, bx, oxv[1][c]);
            }
        }
    }
    #pragma unroll
    for (int mf = 0; mf < 2; ++mf)
        #pragma unroll
        for (int r = 0; r < 4; ++r) {
            const int s = q0 + mf * 16 + quad * 4 + r;
            const float inv = 1.0f / lr[mf][r];
            #pragma unroll
            for (int c = 0; c < 4; ++c) {
                const int d = c * 16 + l16;
                Q [hb + (size_t)s * DH + d] = (bf16)(oxv[mf][c][r] * inv);
                vb[hb + (size_t)s * DH + d] = (bf16)(ov[mf][c][r]  * inv);
            }
        }
}

// ================================ launch ====================================

extern "C" void kernel_launch(void* const* d_in, const int* in_sizes, int n_in,
                              void* d_out, int out_size, void* d_ws, size_t ws_size,
                              hipStream_t stream) {
    const float* query = (const float*)d_in[0];
    const float* key   = (const float*)d_in[1];
    const float* value = (const float*)d_in[2];
    const float* Wq  = (const float*)d_in[3];  const float* bq  = (const float*)d_in[4];
    const float* Wk  = (const float*)d_in[5];  const float* bk  = (const float*)d_in[6];
    const float* Wv  = (const float*)d_in[7];  const float* bv  = (const float*)d_in[8];
    const float* Wxv = (const float*)d_in[9];  const float* bxv = (const float*)d_in[10];
    const float* Wxo = (const float*)d_in[11]; const float* bxo = (const float*)d_in[12];
    const float* Wmo = (const float*)d_in[13]; const float* bmo = (const float*)d_in[14];

    float* out = (float*)d_out;
    const size_t SB = (size_t)SEQ * DX;          // 2,097,152 el
    const size_t M1 = 1ull << 20;

    dim3 blk(256);

    if (ws_size >= (76ull << 20)) {
        // ---------------- Plan A: merged batches, bf16 everywhere -----------
        bf16* ws = (bf16*)d_ws;
        bf16* qb  = ws;                 // 4M el
        bf16* kb  = ws + 4 * M1;
        bf16* vb  = ws + 8 * M1;
        bf16* Wqb = ws + 12 * M1;       // 6 x 1M el
        bf16* Wkb = Wqb + M1;
        bf16* Wvb = Wkb + M1;
        bf16* Wxvb= Wvb + M1;
        bf16* Wxob= Wxvb + M1;
        bf16* Wmob= Wxob + M1;
        bf16* Qs  = ws + 18 * M1;       // bhsd [2][16][2048][64], 4M el each
        bf16* Kss = ws + 22 * M1;
        bf16* Vs  = ws + 26 * M1;
        bf16* xVs = ws + 30 * M1;
        bf16* VBs = ws + 34 * M1;

        cvt_all<<<9216, blk, 0, stream>>>(query, key, value,
                                          Wq, Wk, Wv, Wxv, Wxo, Wmo, ws + 0);
        // note: cvt_all writes segments in order q,k,v,W* starting at ws —
        // matches qb/kb/vb/Wqb.. layout above.

        G4 g1;
        g1.X[0]=qb;  g1.W[0]=Wqb;  g1.B[0]=bq;  g1.Yb[0]=Qs;  g1.Yf[0]=nullptr; g1.xmode[0]=0; g1.ymode[0]=0;
        g1.X[1]=kb;  g1.W[1]=Wkb;  g1.B[1]=bk;  g1.Yb[1]=Kss; g1.Yf[1]=nullptr; g1.xmode[1]=0; g1.ymode[1]=0;
        g1.X[2]=vb;  g1.W[2]=Wvb;  g1.B[2]=bv;  g1.Yb[2]=Vs;  g1.Yf[2]=nullptr; g1.xmode[2]=0; g1.ymode[2]=0;
        g1.X[3]=kb;  g1.W[3]=Wxvb; g1.B[3]=bxv; g1.Yb[3]=xVs; g1.Yf[3]=nullptr; g1.xmode[3]=0; g1.ymode[3]=0;
        gemm256<256><<<dim3(4, 16, 4), dim3(512), 0, stream>>>(g1);

        attn_fast<<<dim3(16, NH, 2), blk, 0, stream>>>(Qs, Kss, Vs, xVs, VBs);

        G4 g2;
        g2.X[0]=Qs;  g2.W[0]=Wxob; g2.B[0]=bxo; g2.Yb[0]=nullptr; g2.Yf[0]=out;          g2.xmode[0]=1; g2.ymode[0]=1;
        g2.X[1]=VBs; g2.W[1]=Wmob; g2.B[1]=bmo; g2.Yb[1]=nullptr; g2.Yf[1]=out + 2*SB;   g2.xmode[1]=1; g2.ymode[1]=1;
        g2.X[2]=Qs;  g2.W[2]=Wxob; g2.B[2]=bxo; g2.Yb[2]=nullptr; g2.Yf[2]=out;          g2.xmode[2]=1; g2.ymode[2]=1;
        g2.X[3]=Qs;  g2.W[3]=Wxob; g2.B[3]=bxo; g2.Yb[3]=nullptr; g2.Yf[3]=out;          g2.xmode[3]=1; g2.ymode[3]=1;
        gemm256<128><<<dim3(4, 32, 2), dim3(512), 0, stream>>>(g2);
    } else {
        // ---------------- fallback: proven R6 path (20 MB ws) ---------------
        bf16* Qs  = (bf16*)d_ws;
        bf16* Ksb = Qs  + SB;
        bf16* Vs  = Ksb + SB;
        bf16* xVs = Vs  + SB;
        bf16* vbs = xVs + SB;
        dim3 pg(8, 32);
        dim3 ag(16, NH);
        for (int b = 0; b < 2; ++b) {
            const float* q_b = query + (size_t)b * SB;
            const float* k_b = key   + (size_t)b * SB;
            const float* v_b = value + (size_t)b * SB;
            float* x_b = out + (size_t)b * SB;
            float* m_b = out + 2 * SB + (size_t)b * SB;
            proj_gemm<<<pg, blk, 0, stream>>>(q_b, Wq,  bq,  Qs,  0, 0);
            proj_gemm<<<pg, blk, 0, stream>>>(k_b, Wk,  bk,  Ksb, 0, 0);
            proj_gemm<<<pg, blk, 0, stream>>>(v_b, Wv,  bv,  Vs,  0, 0);
            proj_gemm<<<pg, blk, 0, stream>>>(k_b, Wxv, bxv, xVs, 0, 0);
            attn_dual<<<ag, blk, 0, stream>>>(Qs, Ksb, Vs, xVs, vbs);
            proj_gemm<<<pg, blk, 0, stream>>>(Qs,  Wxo, bxo, x_b, 1, 1);
            proj_gemm<<<pg, blk, 0, stream>>>(vbs, Wmo, bmo, m_b, 1, 1);
        }
    }
}

// Round 4
// 288.193 us; speedup vs baseline: 1.1240x; 1.0095x over previous
//
#include <hip/hip_runtime.h>
#include <math.h>

typedef __bf16 bf16;
typedef __bf16 bf16x2 __attribute__((ext_vector_type(2)));
typedef __bf16 bf16x4 __attribute__((ext_vector_type(4)));
typedef __bf16 bf16x8 __attribute__((ext_vector_type(8)));
typedef float f32x4 __attribute__((ext_vector_type(4)));

#define SEQ 2048
#define DH 64
#define DX 1024
#define NH 16
#define LP 72   // padded LDS row stride (64+8)

static __device__ __forceinline__ f32x4 mfma16(bf16x8 a, bf16x8 b, f32x4 c) {
    return __builtin_amdgcn_mfma_f32_16x16x32_bf16(a, b, c, 0, 0, 0);
}
static __device__ __forceinline__ bf16x8 cvt8(const float* __restrict__ p) {
    f32x4 a = *(const f32x4*)p;
    f32x4 b = *(const f32x4*)(p + 4);
    bf16x8 r;
    #pragma unroll
    for (int j = 0; j < 4; ++j) { r[j] = (bf16)a[j]; r[4 + j] = (bf16)b[j]; }
    return r;
}

// async global->LDS, 16 B per lane (lands at ldsbase + lane*16)
#define GL16(gp, lp) __builtin_amdgcn_global_load_lds( \
    (const __attribute__((address_space(1))) void*)(gp), \
    (__attribute__((address_space(3))) void*)(lp), 16, 0, 0)

// ============================ PLAN A kernels ================================

// f32 -> bf16 bulk convert: 3 inputs (4M el each) + 6 weights (1M el each)
// into ws at fixed offsets. 18M elements, 8 per thread.
__global__ __launch_bounds__(256) void cvt_all(
    const float* __restrict__ q, const float* __restrict__ k,
    const float* __restrict__ v,
    const float* __restrict__ w0, const float* __restrict__ w1,
    const float* __restrict__ w2, const float* __restrict__ w3,
    const float* __restrict__ w4, const float* __restrict__ w5,
    bf16* __restrict__ out)
{
    const size_t i = (size_t)blockIdx.x * 2048 + threadIdx.x * 8;
    const int seg = (int)(i >> 20);
    const float* s;
    size_t off;
    if (seg < 4)       { s = q; off = i; }
    else if (seg < 8)  { s = k; off = i - (4ull << 20); }
    else if (seg < 12) { s = v; off = i - (8ull << 20); }
    else {
        const float* ww[6] = {w0, w1, w2, w3, w4, w5};
        s = ww[seg - 12]; off = i - ((size_t)seg << 20);
    }
    *(bf16x8*)(out + i) = cvt8(s + off);
}

// fused multi-GEMM: Y_z = X_z @ W_z^T + bias_z, M=4096, N=K=1024, all bf16 in.
// xmode: 0 = X row-major [4096][1024]; 1 = X bhsd [2][16][2048][64]
// ymode: 0 = Y bf16 bhsd;              1 = Y f32 row-major
struct G4 {
    const bf16* X[4]; const bf16* W[4]; const float* B[4];
    bf16* Yb[4]; float* Yf[4]; int xmode[4]; int ymode[4];
};

// R3: 256-wide-N tile, BK=64, 8 waves (2M x 4N), double-buffered LDS,
// 2-phase schedule. GL16 staging, both-sides XOR swizzle (chunk ^= row&7).
// R4: XCD-bijective block swizzle: the 4 blocks sharing an A-panel (same
// by, all bx) are placed on the SAME XCD so the panel is fetched once into
// that XCD's L2 (T1 mechanism). nt%8==0 for both launches -> bijective.
template<int BM>
__global__ __launch_bounds__(512) void gemm256(G4 a)
{
    constexpr int MREP = BM / 32;           // M fragments per wave (8 or 4)
    __shared__ __align__(16) bf16 As[2][BM * 64];
    __shared__ __align__(16) bf16 Bs[2][256 * 64];

    const int z = blockIdx.z;
    const bf16* __restrict__ X = a.X[z];
    const bf16* __restrict__ W = a.W[z];
    const int xmode = a.xmode[z], ymode = a.ymode[z];

    const int tid  = threadIdx.x;
    const int wid  = tid >> 6;
    const int lane = tid & 63;
    const int l16  = lane & 15;
    const int quad = lane >> 4;
    const int wm   = wid >> 2;              // 0..1
    const int wn   = wid & 3;               // 0..3

    // XCD swizzle: t = linear 2D id; XCD k gets contiguous chunk of tiles
    // (x-major) -> all 4 x-blocks of a given y run on one XCD.
    const int nx = gridDim.x;               // 4
    const int nt = nx * gridDim.y;          // 64 (g1) / 128 (g2), %8 == 0
    int t = blockIdx.x + nx * blockIdx.y;
    t = (t & 7) * (nt >> 3) + (t >> 3);
    const int n0 = (t % nx) * 256;
    const int m0 = (t / nx) * BM;

    // staging geometry: per GL16 call a wave covers 8 rows x 64 cols.
    // LDS[row][c] = global[row][c ^ (row&7)]  (linear dest, swizzled src)
    const int srow8 = lane >> 3;            // row within 8-row group
    const int sch   = (lane & 7) ^ srow8;   // pre-swizzled source chunk

    f32x4 acc[MREP][4];
    #pragma unroll
    for (int i = 0; i < MREP; ++i)
        #pragma unroll
        for (int j = 0; j < 4; ++j) acc[i][j] = (f32x4){0.f,0.f,0.f,0.f};

    auto stage = [&](int buf, int kb) {
        #pragma unroll
        for (int g = 0; g < BM / 64; ++g) {
            const int row = g * 64 + wid * 8 + srow8;   // row in A tile
            const bf16* src;
            if (xmode == 0) {
                src = X + (size_t)(m0 + row) * DX + kb * 64 + sch * 8;
            } else {
                const int m = m0 + row;
                const int b = m >> 11, s = m & 2047;
                src = X + ((size_t)(b * NH + kb) * SEQ + s) * DH + sch * 8;
            }
            GL16(src, &As[buf][(g * 64 + wid * 8) * 64]);
        }
        #pragma unroll
        for (int g = 0; g < 4; ++g) {
            const int row = g * 64 + wid * 8 + srow8;   // row in B tile
            const bf16* src = W + (size_t)(n0 + row) * DX + kb * 64 + sch * 8;
            GL16(src, &Bs[buf][(g * 64 + wid * 8) * 64]);
        }
    };

    stage(0, 0);
    __syncthreads();

    int cur = 0;
    for (int kb = 0; kb < DX / 64; ++kb) {
        if (kb + 1 < DX / 64) stage(cur ^ 1, kb + 1);   // flies under MFMA
        #pragma unroll
        for (int ks = 0; ks < 2; ++ks) {
            bf16x8 af[MREP], bfr[4];
            const int cc = (ks * 4 + quad) ^ (l16 & 7); // swizzled chunk
            #pragma unroll
            for (int mf = 0; mf < MREP; ++mf)
                af[mf] = *(const bf16x8*)&As[cur][(wm * (BM/2) + mf * 16 + l16) * 64 + cc * 8];
            #pragma unroll
            for (int nf = 0; nf < 4; ++nf)
                bfr[nf] = *(const bf16x8*)&Bs[cur][(wn * 64 + nf * 16 + l16) * 64 + cc * 8];
            #pragma unroll
            for (int mf = 0; mf < MREP; ++mf)
                #pragma unroll
                for (int nf = 0; nf < 4; ++nf)
                    acc[mf][nf] = mfma16(af[mf], bfr[nf], acc[mf][nf]);
        }
        __syncthreads();   // drains vmcnt -> next buffer staged & visible
        cur ^= 1;
    }

    #pragma unroll
    for (int nf = 0; nf < 4; ++nf) {
        const int col = n0 + wn * 64 + nf * 16 + l16;
        const float bvv = a.B[z][col];
        #pragma unroll
        for (int mf = 0; mf < MREP; ++mf) {
            #pragma unroll
            for (int r = 0; r < 4; ++r) {
                const int row = m0 + wm * (BM/2) + mf * 16 + quad * 4 + r;
                const float vv = acc[mf][nf][r] + bvv;
                if (ymode == 0) {
                    const int b = row >> 11, s = row & 2047;
                    const int h = col >> 6, d = col & 63;
                    a.Yb[z][((size_t)(b * NH + h) * SEQ + s) * DH + d] = (bf16)vv;
                } else {
                    a.Yf[z][(size_t)row * DX + col] = vv;
                }
            }
        }
    }
}

// R4 dual flash attention, wave-paired: grid (qt 8, h 16, b 2), block 512.
// LDS-BW diet: q-tile 256/block, 8 waves in 4 pairs; pair p owns q rows
// [p*64, p*64+64). Within a pair, wave A does P@V -> VB, wave B does
// P@xV -> Q: each wave reads ONE value tile (8 KB) instead of both, and
// P/K reads amortize over 64 q instead of 32 -> per-q LDS traffic 2.2x
// lower. Each wave computes QK^T + exp for only its 32-q half; P is
// shared through LDS (extra barrier between D2 and D3).
// Pipeline (from R1/R2, proven): GL16 K dbuf, reg-prefetch V/xV, counted
// vmcnt(3) (= 1 GL16 + 2 reg loads per wave in flight), setprio on MFMA.
// Softmax (from R2): no-max exp2 direct, row-sum via MFMA P@1.
__global__ __launch_bounds__(512) void attn_pair(
    bf16* __restrict__ Q, const bf16* __restrict__ K,
    const bf16* __restrict__ V, const bf16* __restrict__ xV,
    bf16* __restrict__ VB)
{
    __shared__ __align__(16) bf16 Ks[2][64 * 64];   // XOR-swizzled (GL16)
    __shared__ __align__(16) bf16 Vt [64 * LP];     // [d][k] transposed
    __shared__ __align__(16) bf16 xVt[64 * LP];
    __shared__ __align__(16) bf16 Pl[4][64 * LP];   // per-pair [q][k]

    const int tid  = threadIdx.x;
    const int wid  = tid >> 6;
    const int lane = tid & 63;
    const int l16  = lane & 15;
    const int quad = lane >> 4;
    const int pair = wid >> 1;
    const int half = wid & 1;                // 0: V->VB, 1: xV->Q
    const size_t hb = ((size_t)blockIdx.z * NH + blockIdx.y) * SEQ * DH;
    const int qp = blockIdx.x * 256 + pair * 64;   // pair base
    const int q0 = qp + half * 32;                 // this wave's QK^T half

    bf16x8 qf[2][2];
    #pragma unroll
    for (int nf = 0; nf < 2; ++nf)
        #pragma unroll
        for (int ks = 0; ks < 2; ++ks)
            qf[nf][ks] = *(const bf16x8*)(Q + hb + (size_t)(q0 + nf*16 + l16) * DH + ks*32 + quad*8);

    bf16x8 one8;
    #pragma unroll
    for (int j = 0; j < 8; ++j) one8[j] = (bf16)1.0f;

    f32x4 ov[4][4];          // 64 q x 64 d (one value array)
    f32x4 rsa[4];            // row-sums for 64 q
    #pragma unroll
    for (int mf = 0; mf < 4; ++mf) {
        rsa[mf] = (f32x4){0.f,0.f,0.f,0.f};
        #pragma unroll
        for (int c = 0; c < 4; ++c) ov[mf][c] = (f32x4){0.f,0.f,0.f,0.f};
    }

    // K staging: wave w stages rows w*8..w*8+7 (1 GL16), XOR pre-swizzled
    const int krow = lane >> 3;
    const int kch  = (lane & 7) ^ krow;
    // V/xV staging: threads 0-255 stage V, 256-511 stage xV (same pattern)
    const bf16* __restrict__ vsrc = (tid & 256) ? xV : V;
    bf16* __restrict__ vdst = (tid & 256) ? xVt : Vt;
    const int t8  = tid & 255;
    const int vkp = (t8 & 31) * 2;
    const int vd0 = (t8 >> 5) * 8;
    const float SCL = 0.125f * 1.4426950408889634f;

    // ---- prologue: prefetch tile 0 ----
    bf16x8 pv0, pv1;
    {
        const bf16* kg = K + hb + (size_t)(wid*8 + krow) * DH + kch*8;
        GL16(kg, &Ks[0][(wid*8) * 64]);
        const size_t g0 = hb + (size_t)vkp * DH + vd0;
        pv0 = *(const bf16x8*)(vsrc + g0);
        pv1 = *(const bf16x8*)(vsrc + g0 + DH);
    }

    int c = 0;
    for (int kt = 0; kt < SEQ; kt += 64) {
        // A: commit prefetched V/xV column-slices (compiler waits pv here)
        #pragma unroll
        for (int j = 0; j < 8; ++j)
            *(bf16x2*)&vdst[(vd0 + j) * LP + vkp] = (bf16x2){pv0[j], pv1[j]};
        // B: issue prefetch for tile t+1 (3 vmem ops/wave)
        if (kt + 64 < SEQ) {
            const bf16* kg = K + hb + (size_t)(kt + 64 + wid*8 + krow) * DH + kch*8;
            GL16(kg, &Ks[c ^ 1][(wid*8) * 64]);
            const size_t g0 = hb + (size_t)(kt + 64 + vkp) * DH + vd0;
            pv0 = *(const bf16x8*)(vsrc + g0);
            pv1 = *(const bf16x8*)(vsrc + g0 + DH);
        }
        // C: staging visible to all waves; keep t+1 prefetch in flight
        __asm__ volatile("s_waitcnt lgkmcnt(0)" ::: "memory");
        __builtin_amdgcn_s_barrier();
        __asm__ volatile("s_waitcnt vmcnt(3)" ::: "memory");
        __builtin_amdgcn_sched_barrier(0);

        // D1: S^T = K Q^T for this wave's 32 q (swizzled Ks read)
        f32x4 sf[4][2];
        #pragma unroll
        for (int mf = 0; mf < 4; ++mf)
            #pragma unroll
            for (int nf = 0; nf < 2; ++nf) sf[mf][nf] = (f32x4){0.f,0.f,0.f,0.f};
        __builtin_amdgcn_s_setprio(1);
        #pragma unroll
        for (int ks = 0; ks < 2; ++ks)
            #pragma unroll
            for (int mf = 0; mf < 4; ++mf) {
                bf16x8 kf = *(const bf16x8*)&Ks[c][(mf*16 + l16) * 64 +
                                                   (((ks*4 + quad) ^ (l16 & 7)) * 8)];
                sf[mf][0] = mfma16(kf, qf[0][ks], sf[mf][0]);
                sf[mf][1] = mfma16(kf, qf[1][ks], sf[mf][1]);
            }
        __builtin_amdgcn_s_setprio(0);

        // D2: P = exp2(S*scl), write this wave's 32-q half of the pair's P
        #pragma unroll
        for (int nf = 0; nf < 2; ++nf)
            #pragma unroll
            for (int mf = 0; mf < 4; ++mf) {
                float p0 = __builtin_amdgcn_exp2f(sf[mf][nf][0] * SCL);
                float p1 = __builtin_amdgcn_exp2f(sf[mf][nf][1] * SCL);
                float p2 = __builtin_amdgcn_exp2f(sf[mf][nf][2] * SCL);
                float p3 = __builtin_amdgcn_exp2f(sf[mf][nf][3] * SCL);
                *(bf16x4*)&Pl[pair][(half*32 + nf*16 + l16) * LP + mf*16 + quad*4] =
                    (bf16x4){(bf16)p0, (bf16)p1, (bf16)p2, (bf16)p3};
            }
        // P is read by the pair partner -> full barrier (writes drained first)
        __asm__ volatile("s_waitcnt lgkmcnt(0)" ::: "memory");
        __builtin_amdgcn_s_barrier();
        __builtin_amdgcn_sched_barrier(0);

        // D3: O += P @ (V or xV) over the pair's 64 q; rs += P @ 1
        __builtin_amdgcn_s_setprio(1);
        #pragma unroll
        for (int ks = 0; ks < 2; ++ks) {
            bf16x8 pa[4];
            #pragma unroll
            for (int mf = 0; mf < 4; ++mf)
                pa[mf] = *(const bf16x8*)&Pl[pair][(mf*16 + l16) * LP + ks*32 + quad*8];
            #pragma unroll
            for (int mf = 0; mf < 4; ++mf)
                rsa[mf] = mfma16(pa[mf], one8, rsa[mf]);
            const bf16* __restrict__ tile = half ? xVt : Vt;
            #pragma unroll
            for (int cc = 0; cc < 4; ++cc) {
                bf16x8 bv = *(const bf16x8*)&tile[(cc*16 + l16) * LP + ks*32 + quad*8];
                #pragma unroll
                for (int mf = 0; mf < 4; ++mf)
                    ov[mf][cc] = mfma16(pa[mf], bv, ov[mf][cc]);
            }
        }
        __builtin_amdgcn_s_setprio(0);

        // E: protect Vt/xVt/Pl overwrite next iter
        __builtin_amdgcn_sched_barrier(0);
        __builtin_amdgcn_s_barrier();
        c ^= 1;
    }

    // epilogue: rsa[mf][r] = row-sum for pair q-row mf*16+quad*4+r
    // (broadcast over l16). Wave A -> VB (vbar), wave B -> Q (kbar).
    bf16* __restrict__ outp = half ? Q : VB;
    #pragma unroll
    for (int mf = 0; mf < 4; ++mf)
        #pragma unroll
        for (int r = 0; r < 4; ++r) {
            const int qrow = mf * 16 + quad * 4 + r;
            const float inv = 1.0f / rsa[mf][r];
            const size_t base = hb + (size_t)(qp + qrow) * DH;
            #pragma unroll
            for (int cc = 0; cc < 4; ++cc)
                outp[base + cc*16 + l16] = (bf16)(ov[mf][cc][r] * inv);
        }
}

// ======================= legacy (R6, proven) fallback =======================

__global__ __launch_bounds__(256) void proj_gemm(
    const void* __restrict__ Xv, const float* __restrict__ W,
    const float* __restrict__ bias, void* __restrict__ Yv,
    int in_kind, int out_mode)
{
    __shared__ __align__(16) bf16 As[64 * LP];
    __shared__ __align__(16) bf16 Bs[128 * LP];
    const int tid  = threadIdx.x;
    const int wave = tid >> 6;
    const int lane = tid & 63;
    const int l16  = lane & 15;
    const int quad = lane >> 4;
    const int m0 = blockIdx.y * 64;
    const int n0 = blockIdx.x * 128;
    const int m_w = (wave >> 1) * 32;
    const int n_w = (wave & 1) * 64;
    const int ar = tid >> 2, ac = (tid & 3) * 16;
    const int br = tid >> 1, bc = (tid & 1) * 32;

    f32x4 acc[2][4];
    #pragma unroll
    for (int i = 0; i < 2; ++i)
        #pragma unroll
        for (int j = 0; j < 4; ++j) acc[i][j] = (f32x4){0.f,0.f,0.f,0.f};

    for (int kb = 0; kb < DX / 64; ++kb) {
        __syncthreads();
        if (in_kind == 0) {
            const float* xp = (const float*)Xv + (size_t)(m0 + ar) * DX + kb * 64 + ac;
            *(bf16x8*)&As[ar * LP + ac]     = cvt8(xp);
            *(bf16x8*)&As[ar * LP + ac + 8] = cvt8(xp + 8);
        } else {
            const bf16* xp = (const bf16*)Xv + ((size_t)kb * SEQ + (m0 + ar)) * DH + ac;
            *(bf16x8*)&As[ar * LP + ac]     = *(const bf16x8*)xp;
            *(bf16x8*)&As[ar * LP + ac + 8] = *(const bf16x8*)(xp + 8);
        }
        {
            const float* wp = W + (size_t)(n0 + br) * DX + kb * 64 + bc;
            #pragma unroll
            for (int g = 0; g < 4; ++g)
                *(bf16x8*)&Bs[br * LP + bc + g * 8] = cvt8(wp + g * 8);
        }
        __syncthreads();
        #pragma unroll
        for (int ks = 0; ks < 2; ++ks) {
            bf16x8 a0 = *(const bf16x8*)&As[(m_w + l16)      * LP + ks * 32 + quad * 8];
            bf16x8 a1 = *(const bf16x8*)&As[(m_w + 16 + l16) * LP + ks * 32 + quad * 8];
            #pragma unroll
            for (int nf = 0; nf < 4; ++nf) {
                bf16x8 b = *(const bf16x8*)&Bs[(n_w + nf * 16 + l16) * LP + ks * 32 + quad * 8];
                acc[0][nf] = mfma16(a0, b, acc[0][nf]);
                acc[1][nf] = mfma16(a1, b, acc[1][nf]);
            }
        }
    }
    #pragma unroll
    for (int mf = 0; mf < 2; ++mf)
        #pragma unroll
        for (int nf = 0; nf < 4; ++nf) {
            const int col = n0 + n_w + nf * 16 + l16;
            const float bvv = bias[col];
            #pragma unroll
            for (int r = 0; r < 4; ++r) {
                const int row = m0 + m_w + mf * 16 + quad * 4 + r;
                float v = acc[mf][nf][r] + bvv;
                if (out_mode == 0) {
                    int h = col >> 6, d = col & 63;
                    ((bf16*)Yv)[((size_t)h * SEQ + row) * DH + d] = (bf16)v;
                } else {
                    ((float*)Yv)[(size_t)row * DX + col] = v;
                }
            }
        }
}

__global__ __launch_bounds__(256) void attn_dual(
    bf16* __restrict__ Q, const bf16* __restrict__ K,
    const bf16* __restrict__ V, const bf16* __restrict__ xV,
    bf16* __restrict__ vb)
{
    __shared__ __align__(16) bf16 Ks [64 * LP];
    __shared__ __align__(16) bf16 Vt [64 * LP];
    __shared__ __align__(16) bf16 xVt[64 * LP];
    __shared__ __align__(16) bf16 Pl[4][32 * LP];
    const int tid  = threadIdx.x;
    const int h    = blockIdx.y;
    const int qt   = blockIdx.x;
    const int wave = tid >> 6;
    const int lane = tid & 63;
    const int l16  = lane & 15;
    const int quad = lane >> 4;
    const size_t hb = (size_t)h * SEQ * DH;
    const int q0 = qt * 128 + wave * 32;

    bf16x8 qf[2][2];
    #pragma unroll
    for (int mf = 0; mf < 2; ++mf)
        #pragma unroll
        for (int ks = 0; ks < 2; ++ks)
            qf[mf][ks] = *(const bf16x8*)(Q + hb + (size_t)(q0 + mf*16 + l16) * DH + ks*32 + quad*8);

    float mr[2][4], lr[2][4];
    f32x4 ov[2][4], oxv[2][4];
    #pragma unroll
    for (int mf = 0; mf < 2; ++mf)
        #pragma unroll
        for (int r = 0; r < 4; ++r) { mr[mf][r] = -1e30f; lr[mf][r] = 0.f; }
    #pragma unroll
    for (int mf = 0; mf < 2; ++mf)
        #pragma unroll
        for (int c = 0; c < 4; ++c) {
            ov[mf][c]  = (f32x4){0.f,0.f,0.f,0.f};
            oxv[mf][c] = (f32x4){0.f,0.f,0.f,0.f};
        }
    const int sr = tid >> 2, sc = (tid & 3) * 16;
    const int vkp = (tid & 31) * 2;
    const int vd0 = (tid >> 5) * 8;
    const float SCL = 0.125f * 1.4426950408889634f;

    for (int kt = 0; kt < SEQ; kt += 64) {
        __syncthreads();
        {
            const bf16* kpt = K + hb + (size_t)(kt + sr) * DH + sc;
            *(bf16x8*)&Ks[sr * LP + sc]     = *(const bf16x8*)kpt;
            *(bf16x8*)&Ks[sr * LP + sc + 8] = *(const bf16x8*)(kpt + 8);
            const size_t g0 = hb + (size_t)(kt + vkp) * DH + vd0;
            bf16x8 v0 = *(const bf16x8*)(V + g0);
            bf16x8 v1 = *(const bf16x8*)(V + g0 + DH);
            bf16x8 x0 = *(const bf16x8*)(xV + g0);
            bf16x8 x1 = *(const bf16x8*)(xV + g0 + DH);
            #pragma unroll
            for (int j = 0; j < 8; ++j) {
                *(bf16x2*)&Vt [(vd0 + j) * LP + vkp] = (bf16x2){v0[j], v1[j]};
                *(bf16x2*)&xVt[(vd0 + j) * LP + vkp] = (bf16x2){x0[j], x1[j]};
            }
        }
        __syncthreads();
        f32x4 sf[2][4];
        #pragma unroll
        for (int mf = 0; mf < 2; ++mf)
            #pragma unroll
            for (int nf = 0; nf < 4; ++nf) sf[mf][nf] = (f32x4){0.f,0.f,0.f,0.f};
        #pragma unroll
        for (int ks = 0; ks < 2; ++ks)
            #pragma unroll
            for (int nf = 0; nf < 4; ++nf) {
                bf16x8 bk = *(const bf16x8*)&Ks[(nf * 16 + l16) * LP + ks * 32 + quad * 8];
                sf[0][nf] = mfma16(qf[0][ks], bk, sf[0][nf]);
                sf[1][nf] = mfma16(qf[1][ks], bk, sf[1][nf]);
            }
        float mx[2][4], rs[2][4], alpha[2][4];
        #pragma unroll
        for (int mf = 0; mf < 2; ++mf)
            #pragma unroll
            for (int r = 0; r < 4; ++r) {
                float aa = fmaxf(sf[mf][0][r], sf[mf][1][r]);
                float bb = fmaxf(sf[mf][2][r], sf[mf][3][r]);
                mx[mf][r] = fmaxf(aa, bb) * SCL;
            }
        #pragma unroll
        for (int off = 1; off < 16; off <<= 1)
            #pragma unroll
            for (int mf = 0; mf < 2; ++mf)
                #pragma unroll
                for (int r = 0; r < 4; ++r)
                    mx[mf][r] = fmaxf(mx[mf][r], __shfl_xor(mx[mf][r], off, 64));
        #pragma unroll
        for (int mf = 0; mf < 2; ++mf)
            #pragma unroll
            for (int r = 0; r < 4; ++r) {
                float mnew = fmaxf(mr[mf][r], mx[mf][r]);
                alpha[mf][r] = exp2f(mr[mf][r] - mnew);
                mr[mf][r] = mnew;
            }
        bf16* pw = &Pl[wave][0];
        #pragma unroll
        for (int mf = 0; mf < 2; ++mf)
            #pragma unroll
            for (int r = 0; r < 4; ++r) rs[mf][r] = 0.f;
        #pragma unroll
        for (int mf = 0; mf < 2; ++mf)
            #pragma unroll
            for (int nf = 0; nf < 4; ++nf)
                #pragma unroll
                for (int r = 0; r < 4; ++r) {
                    float p = exp2f(sf[mf][nf][r] * SCL - mr[mf][r]);
                    rs[mf][r] += p;
                    pw[(mf * 16 + quad * 4 + r) * LP + nf * 16 + l16] = (bf16)p;
                }
        #pragma unroll
        for (int off = 1; off < 16; off <<= 1)
            #pragma unroll
            for (int mf = 0; mf < 2; ++mf)
                #pragma unroll
                for (int r = 0; r < 4; ++r)
                    rs[mf][r] += __shfl_xor(rs[mf][r], off, 64);
        #pragma unroll
        for (int mf = 0; mf < 2; ++mf)
            #pragma unroll
            for (int r = 0; r < 4; ++r)
                lr[mf][r] = lr[mf][r] * alpha[mf][r] + rs[mf][r];
        #pragma unroll
        for (int mf = 0; mf < 2; ++mf)
            #pragma unroll
            for (int c = 0; c < 4; ++c)
                #pragma unroll
                for (int r = 0; r < 4; ++r) {
                    ov[mf][c][r]  *= alpha[mf][r];
                    oxv[mf][c][r] *= alpha[mf][r];
                }
        __asm__ volatile("s_waitcnt lgkmcnt(0)" ::: "memory");
        #pragma unroll
        for (int ks = 0; ks < 2; ++ks) {
            bf16x8 pa0 = *(const bf16x8*)&Pl[wave][(l16)      * LP + ks * 32 + quad * 8];
            bf16x8 pa1 = *(const bf16x8*)&Pl[wave][(16 + l16) * LP + ks * 32 + quad * 8];
            #pragma unroll
            for (int c = 0; c < 4; ++c) {
                bf16x8 bv = *(const bf16x8*)&Vt [(c * 16 + l16) * LP + ks * 32 + quad * 8];
                ov[0][c]  = mfma16(pa0, bv, ov[0][c]);
                ov[1][c]  = mfma16(pa1, bv, ov[1][c]);
                bf16x8 bx = *(const bf16x8*)&xVt[(c * 16 + l16) * LP + ks * 32 + quad * 8];
                oxv[0][c] = mfma16(pa0, bx, oxv[0][c]);
                oxv[1][c] = mfma16(pa1, bx, oxv[1][c]);
            }
        }
    }
    #pragma unroll
    for (int mf = 0; mf < 2; ++mf)
        #pragma unroll
        for (int r = 0; r < 4; ++r) {
            const int s = q0 + mf * 16 + quad * 4 + r;
            const float inv = 1.0f / lr[mf][r];
            #pragma unroll
            for (int c = 0; c < 4; ++c) {
                const int d = c * 16 + l16;
                Q [hb + (size_t)s * DH + d] = (bf16)(oxv[mf][c][r] * inv);
                vb[hb + (size_t)s * DH + d] = (bf16)(ov[mf][c][r]  * inv);
            }
        }
}

// ================================ launch ====================================

extern "C" void kernel_launch(void* const* d_in, const int* in_sizes, int n_in,
                              void* d_out, int out_size, void* d_ws, size_t ws_size,
                              hipStream_t stream) {
    const float* query = (const float*)d_in[0];
    const float* key   = (const float*)d_in[1];
    const float* value = (const float*)d_in[2];
    const float* Wq  = (const float*)d_in[3];  const float* bq  = (const float*)d_in[4];
    const float* Wk  = (const float*)d_in[5];  const float* bk  = (const float*)d_in[6];
    const float* Wv  = (const float*)d_in[7];  const float* bv  = (const float*)d_in[8];
    const float* Wxv = (const float*)d_in[9];  const float* bxv = (const float*)d_in[10];
    const float* Wxo = (const float*)d_in[11]; const float* bxo = (const float*)d_in[12];
    const float* Wmo = (const float*)d_in[13]; const float* bmo = (const float*)d_in[14];

    float* out = (float*)d_out;
    const size_t SB = (size_t)SEQ * DX;          // 2,097,152 el
    const size_t M1 = 1ull << 20;

    dim3 blk(256);

    if (ws_size >= (76ull << 20)) {
        // ---------------- Plan A: merged batches, bf16 everywhere -----------
        bf16* ws = (bf16*)d_ws;
        bf16* qb  = ws;                 // 4M el
        bf16* kb  = ws + 4 * M1;
        bf16* vb  = ws + 8 * M1;
        bf16* Wqb = ws + 12 * M1;       // 6 x 1M el
        bf16* Wkb = Wqb + M1;
        bf16* Wvb = Wkb + M1;
        bf16* Wxvb= Wvb + M1;
        bf16* Wxob= Wxvb + M1;
        bf16* Wmob= Wxob + M1;
        bf16* Qs  = ws + 18 * M1;       // bhsd [2][16][2048][64], 4M el each
        bf16* Kss = ws + 22 * M1;
        bf16* Vs  = ws + 26 * M1;
        bf16* xVs = ws + 30 * M1;
        bf16* VBs = ws + 34 * M1;

        cvt_all<<<9216, blk, 0, stream>>>(query, key, value,
                                          Wq, Wk, Wv, Wxv, Wxo, Wmo, ws + 0);

        G4 g1;
        g1.X[0]=qb;  g1.W[0]=Wqb;  g1.B[0]=bq;  g1.Yb[0]=Qs;  g1.Yf[0]=nullptr; g1.xmode[0]=0; g1.ymode[0]=0;
        g1.X[1]=kb;  g1.W[1]=Wkb;  g1.B[1]=bk;  g1.Yb[1]=Kss; g1.Yf[1]=nullptr; g1.xmode[1]=0; g1.ymode[1]=0;
        g1.X[2]=vb;  g1.W[2]=Wvb;  g1.B[2]=bv;  g1.Yb[2]=Vs;  g1.Yf[2]=nullptr; g1.xmode[2]=0; g1.ymode[2]=0;
        g1.X[3]=kb;  g1.W[3]=Wxvb; g1.B[3]=bxv; g1.Yb[3]=xVs; g1.Yf[3]=nullptr; g1.xmode[3]=0; g1.ymode[3]=0;
        gemm256<256><<<dim3(4, 16, 4), dim3(512), 0, stream>>>(g1);

        attn_pair<<<dim3(8, NH, 2), dim3(512), 0, stream>>>(Qs, Kss, Vs, xVs, VBs);

        G4 g2;
        g2.X[0]=Qs;  g2.W[0]=Wxob; g2.B[0]=bxo; g2.Yb[0]=nullptr; g2.Yf[0]=out;          g2.xmode[0]=1; g2.ymode[0]=1;
        g2.X[1]=VBs; g2.W[1]=Wmob; g2.B[1]=bmo; g2.Yb[1]=nullptr; g2.Yf[1]=out + 2*SB;   g2.xmode[1]=1; g2.ymode[1]=1;
        g2.X[2]=Qs;  g2.W[2]=Wxob; g2.B[2]=bxo; g2.Yb[2]=nullptr; g2.Yf[2]=out;          g2.xmode[2]=1; g2.ymode[2]=1;
        g2.X[3]=Qs;  g2.W[3]=Wxob; g2.B[3]=bxo; g2.Yb[3]=nullptr; g2.Yf[3]=out;          g2.xmode[3]=1; g2.ymode[3]=1;
        gemm256<128><<<dim3(4, 32, 2), dim3(512), 0, stream>>>(g2);
    } else {
        // ---------------- fallback: proven R6 path (20 MB ws) ---------------
        bf16* Qs  = (bf16*)d_ws;
        bf16* Ksb = Qs  + SB;
        bf16* Vs  = Ksb + SB;
        bf16* xVs = Vs  + SB;
        bf16* vbs = xVs + SB;
        dim3 pg(8, 32);
        dim3 ag(16, NH);
        for (int b = 0; b < 2; ++b) {
            const float* q_b = query + (size_t)b * SB;
            const float* k_b = key   + (size_t)b * SB;
            const float* v_b = value + (size_t)b * SB;
            float* x_b = out + (size_t)b * SB;
            float* m_b = out + 2 * SB + (size_t)b * SB;
            proj_gemm<<<pg, blk, 0, stream>>>(q_b, Wq,  bq,  Qs,  0, 0);
            proj_gemm<<<pg, blk, 0, stream>>>(k_b, Wk,  bk,  Ksb, 0, 0);
            proj_gemm<<<pg, blk, 0, stream>>>(v_b, Wv,  bv,  Vs,  0, 0);
            proj_gemm<<<pg, blk, 0, stream>>>(k_b, Wxv, bxv, xVs, 0, 0);
            attn_dual<<<ag, blk, 0, stream>>>(Qs, Ksb, Vs, xVs, vbs);
            proj_gemm<<<pg, blk, 0, stream>>>(Qs,  Wxo, bxo, x_b, 1, 1);
            proj_gemm<<<pg, blk, 0, stream>>>(vbs, Wmo, bmo, m_b, 1, 1);
        }
    }
}

// Round 5
// 283.641 us; speedup vs baseline: 1.1421x; 1.0160x over previous
//
#include <hip/hip_runtime.h>
#include <math.h>

typedef __bf16 bf16;
typedef __bf16 bf16x2 __attribute__((ext_vector_type(2)));
typedef __bf16 bf16x4 __attribute__((ext_vector_type(4)));
typedef __bf16 bf16x8 __attribute__((ext_vector_type(8)));
typedef float f32x4 __attribute__((ext_vector_type(4)));

#define SEQ 2048
#define DH 64
#define DX 1024
#define NH 16
#define LP 72   // padded LDS row stride (64+8)

static __device__ __forceinline__ f32x4 mfma16(bf16x8 a, bf16x8 b, f32x4 c) {
    return __builtin_amdgcn_mfma_f32_16x16x32_bf16(a, b, c, 0, 0, 0);
}
static __device__ __forceinline__ bf16x8 cvt8(const float* __restrict__ p) {
    f32x4 a = *(const f32x4*)p;
    f32x4 b = *(const f32x4*)(p + 4);
    bf16x8 r;
    #pragma unroll
    for (int j = 0; j < 4; ++j) { r[j] = (bf16)a[j]; r[4 + j] = (bf16)b[j]; }
    return r;
}

// async global->LDS, 16 B per lane (lands at ldsbase + lane*16)
#define GL16(gp, lp) __builtin_amdgcn_global_load_lds( \
    (const __attribute__((address_space(1))) void*)(gp), \
    (__attribute__((address_space(3))) void*)(lp), 16, 0, 0)

// ============================ PLAN A kernels ================================

// f32 -> bf16 bulk convert: 3 inputs (4M el each) + 6 weights (1M el each)
// into ws at fixed offsets. 18M elements, 8 per thread.
__global__ __launch_bounds__(256) void cvt_all(
    const float* __restrict__ q, const float* __restrict__ k,
    const float* __restrict__ v,
    const float* __restrict__ w0, const float* __restrict__ w1,
    const float* __restrict__ w2, const float* __restrict__ w3,
    const float* __restrict__ w4, const float* __restrict__ w5,
    bf16* __restrict__ out)
{
    const size_t i = (size_t)blockIdx.x * 2048 + threadIdx.x * 8;
    const int seg = (int)(i >> 20);
    const float* s;
    size_t off;
    if (seg < 4)       { s = q; off = i; }
    else if (seg < 8)  { s = k; off = i - (4ull << 20); }
    else if (seg < 12) { s = v; off = i - (8ull << 20); }
    else {
        const float* ww[6] = {w0, w1, w2, w3, w4, w5};
        s = ww[seg - 12]; off = i - ((size_t)seg << 20);
    }
    *(bf16x8*)(out + i) = cvt8(s + off);
}

// fused multi-GEMM: Y_z = X_z @ W_z^T + bias_z, M=4096, N=K=1024, all bf16 in.
// xmode: 0 = X row-major [4096][1024]; 1 = X bhsd [2][16][2048][64]
// ymode: 0 = Y bf16 bhsd;              1 = Y f32 row-major
struct G4 {
    const bf16* X[4]; const bf16* W[4]; const float* B[4];
    bf16* Yb[4]; float* Yf[4]; int xmode[4]; int ymode[4];
};

// R3: 256-wide-N tile, BK=64, 8 waves (2M x 4N), double-buffered LDS,
// 2-phase schedule. GL16 staging, both-sides XOR swizzle (chunk ^= row&7).
// R4: XCD-bijective block swizzle (T1): A-panel-sharing blocks co-located.
template<int BM>
__global__ __launch_bounds__(512) void gemm256(G4 a)
{
    constexpr int MREP = BM / 32;           // M fragments per wave (8 or 4)
    __shared__ __align__(16) bf16 As[2][BM * 64];
    __shared__ __align__(16) bf16 Bs[2][256 * 64];

    const int z = blockIdx.z;
    const bf16* __restrict__ X = a.X[z];
    const bf16* __restrict__ W = a.W[z];
    const int xmode = a.xmode[z], ymode = a.ymode[z];

    const int tid  = threadIdx.x;
    const int wid  = tid >> 6;
    const int lane = tid & 63;
    const int l16  = lane & 15;
    const int quad = lane >> 4;
    const int wm   = wid >> 2;              // 0..1
    const int wn   = wid & 3;               // 0..3

    // XCD swizzle: t = linear 2D id; XCD k gets contiguous chunk of tiles
    // (x-major) -> all 4 x-blocks of a given y run on one XCD.
    const int nx = gridDim.x;               // 4
    const int nt = nx * gridDim.y;          // 64 (g1) / 128 (g2), %8 == 0
    int t = blockIdx.x + nx * blockIdx.y;
    t = (t & 7) * (nt >> 3) + (t >> 3);
    const int n0 = (t % nx) * 256;
    const int m0 = (t / nx) * BM;

    // staging geometry: per GL16 call a wave covers 8 rows x 64 cols.
    // LDS[row][c] = global[row][c ^ (row&7)]  (linear dest, swizzled src)
    const int srow8 = lane >> 3;            // row within 8-row group
    const int sch   = (lane & 7) ^ srow8;   // pre-swizzled source chunk

    f32x4 acc[MREP][4];
    #pragma unroll
    for (int i = 0; i < MREP; ++i)
        #pragma unroll
        for (int j = 0; j < 4; ++j) acc[i][j] = (f32x4){0.f,0.f,0.f,0.f};

    auto stage = [&](int buf, int kb) {
        #pragma unroll
        for (int g = 0; g < BM / 64; ++g) {
            const int row = g * 64 + wid * 8 + srow8;   // row in A tile
            const bf16* src;
            if (xmode == 0) {
                src = X + (size_t)(m0 + row) * DX + kb * 64 + sch * 8;
            } else {
                const int m = m0 + row;
                const int b = m >> 11, s = m & 2047;
                src = X + ((size_t)(b * NH + kb) * SEQ + s) * DH + sch * 8;
            }
            GL16(src, &As[buf][(g * 64 + wid * 8) * 64]);
        }
        #pragma unroll
        for (int g = 0; g < 4; ++g) {
            const int row = g * 64 + wid * 8 + srow8;   // row in B tile
            const bf16* src = W + (size_t)(n0 + row) * DX + kb * 64 + sch * 8;
            GL16(src, &Bs[buf][(g * 64 + wid * 8) * 64]);
        }
    };

    stage(0, 0);
    __syncthreads();

    int cur = 0;
    for (int kb = 0; kb < DX / 64; ++kb) {
        if (kb + 1 < DX / 64) stage(cur ^ 1, kb + 1);   // flies under MFMA
        #pragma unroll
        for (int ks = 0; ks < 2; ++ks) {
            bf16x8 af[MREP], bfr[4];
            const int cc = (ks * 4 + quad) ^ (l16 & 7); // swizzled chunk
            #pragma unroll
            for (int mf = 0; mf < MREP; ++mf)
                af[mf] = *(const bf16x8*)&As[cur][(wm * (BM/2) + mf * 16 + l16) * 64 + cc * 8];
            #pragma unroll
            for (int nf = 0; nf < 4; ++nf)
                bfr[nf] = *(const bf16x8*)&Bs[cur][(wn * 64 + nf * 16 + l16) * 64 + cc * 8];
            #pragma unroll
            for (int mf = 0; mf < MREP; ++mf)
                #pragma unroll
                for (int nf = 0; nf < 4; ++nf)
                    acc[mf][nf] = mfma16(af[mf], bfr[nf], acc[mf][nf]);
        }
        __syncthreads();   // drains vmcnt -> next buffer staged & visible
        cur ^= 1;
    }

    #pragma unroll
    for (int nf = 0; nf < 4; ++nf) {
        const int col = n0 + wn * 64 + nf * 16 + l16;
        const float bvv = a.B[z][col];
        #pragma unroll
        for (int mf = 0; mf < MREP; ++mf) {
            #pragma unroll
            for (int r = 0; r < 4; ++r) {
                const int row = m0 + wm * (BM/2) + mf * 16 + quad * 4 + r;
                const float vv = acc[mf][nf][r] + bvv;
                if (ymode == 0) {
                    const int b = row >> 11, s = row & 2047;
                    const int h = col >> 6, d = col & 63;
                    a.Yb[z][((size_t)(b * NH + h) * SEQ + s) * DH + d] = (bf16)vv;
                } else {
                    a.Yf[z][(size_t)row * DX + col] = vv;
                }
            }
        }
    }
}

// R5 dual flash attention: grid (qt 16, h 16, b 2) = 512 blocks, block 512.
// TLP fix: q-tile 128/block -> grid 512 -> 2 blocks/CU co-resident
// (16 waves/CU = 4 waves/SIMD, was 2). Two independent barrier groups per
// CU interleave: one block computes while the other waits at a barrier.
// Pair structure (R4): 8 waves in 4 pairs; pair p owns q rows
// [p*32, p*32+32). Wave A (half=0) does P@V -> VB, wave B (half=1) does
// P@xV -> Q; each wave computes QK^T + exp for its 16-q half; P shared
// through LDS (barrier between D2 and D3).
// Pipeline (R1/R2, proven): GL16 K dbuf (XOR-swizzled), reg-prefetch
// V/xV, counted vmcnt(3), setprio on MFMA. Softmax: no-max exp2 direct,
// row-sum via MFMA P@1. LDS 52 KB -> fits 2 blocks/CU.
__global__ __launch_bounds__(512) void attn_pair(
    bf16* __restrict__ Q, const bf16* __restrict__ K,
    const bf16* __restrict__ V, const bf16* __restrict__ xV,
    bf16* __restrict__ VB)
{
    __shared__ __align__(16) bf16 Ks[2][64 * 64];   // XOR-swizzled (GL16)
    __shared__ __align__(16) bf16 Vt [64 * LP];     // [d][k] transposed
    __shared__ __align__(16) bf16 xVt[64 * LP];
    __shared__ __align__(16) bf16 Pl[4][32 * LP];   // per-pair [q 32][k 64]

    const int tid  = threadIdx.x;
    const int wid  = tid >> 6;
    const int lane = tid & 63;
    const int l16  = lane & 15;
    const int quad = lane >> 4;
    const int pair = wid >> 1;
    const int half = wid & 1;                // 0: V->VB, 1: xV->Q
    const size_t hb = ((size_t)blockIdx.z * NH + blockIdx.y) * SEQ * DH;
    const int qp = blockIdx.x * 128 + pair * 32;   // pair base (32 q)
    const int q0 = qp + half * 16;                 // this wave's 16-q half

    bf16x8 qf[2];
    #pragma unroll
    for (int ks = 0; ks < 2; ++ks)
        qf[ks] = *(const bf16x8*)(Q + hb + (size_t)(q0 + l16) * DH + ks*32 + quad*8);

    bf16x8 one8;
    #pragma unroll
    for (int j = 0; j < 8; ++j) one8[j] = (bf16)1.0f;

    f32x4 ov[2][4];          // 32 q x 64 d (one value array)
    f32x4 rsa[2];            // row-sums for 32 q
    #pragma unroll
    for (int mf = 0; mf < 2; ++mf) {
        rsa[mf] = (f32x4){0.f,0.f,0.f,0.f};
        #pragma unroll
        for (int c = 0; c < 4; ++c) ov[mf][c] = (f32x4){0.f,0.f,0.f,0.f};
    }

    // K staging: wave w stages rows w*8..w*8+7 (1 GL16), XOR pre-swizzled
    const int krow = lane >> 3;
    const int kch  = (lane & 7) ^ krow;
    // V/xV staging: threads 0-255 stage V, 256-511 stage xV (same pattern)
    const bf16* __restrict__ vsrc = (tid & 256) ? xV : V;
    bf16* __restrict__ vdst = (tid & 256) ? xVt : Vt;
    const int t8  = tid & 255;
    const int vkp = (t8 & 31) * 2;
    const int vd0 = (t8 >> 5) * 8;
    const float SCL = 0.125f * 1.4426950408889634f;

    // ---- prologue: prefetch tile 0 ----
    bf16x8 pv0, pv1;
    {
        const bf16* kg = K + hb + (size_t)(wid*8 + krow) * DH + kch*8;
        GL16(kg, &Ks[0][(wid*8) * 64]);
        const size_t g0 = hb + (size_t)vkp * DH + vd0;
        pv0 = *(const bf16x8*)(vsrc + g0);
        pv1 = *(const bf16x8*)(vsrc + g0 + DH);
    }

    int c = 0;
    for (int kt = 0; kt < SEQ; kt += 64) {
        // A: commit prefetched V/xV column-slices (compiler waits pv here)
        #pragma unroll
        for (int j = 0; j < 8; ++j)
            *(bf16x2*)&vdst[(vd0 + j) * LP + vkp] = (bf16x2){pv0[j], pv1[j]};
        // B: issue prefetch for tile t+1 (3 vmem ops/wave)
        if (kt + 64 < SEQ) {
            const bf16* kg = K + hb + (size_t)(kt + 64 + wid*8 + krow) * DH + kch*8;
            GL16(kg, &Ks[c ^ 1][(wid*8) * 64]);
            const size_t g0 = hb + (size_t)(kt + 64 + vkp) * DH + vd0;
            pv0 = *(const bf16x8*)(vsrc + g0);
            pv1 = *(const bf16x8*)(vsrc + g0 + DH);
        }
        // C: staging visible to all waves; keep t+1 prefetch in flight
        __asm__ volatile("s_waitcnt lgkmcnt(0)" ::: "memory");
        __builtin_amdgcn_s_barrier();
        __asm__ volatile("s_waitcnt vmcnt(3)" ::: "memory");
        __builtin_amdgcn_sched_barrier(0);

        // D1: S^T = K Q^T for this wave's 16 q (swizzled Ks read)
        f32x4 sf[4];
        #pragma unroll
        for (int mf = 0; mf < 4; ++mf) sf[mf] = (f32x4){0.f,0.f,0.f,0.f};
        __builtin_amdgcn_s_setprio(1);
        #pragma unroll
        for (int ks = 0; ks < 2; ++ks)
            #pragma unroll
            for (int mf = 0; mf < 4; ++mf) {
                bf16x8 kf = *(const bf16x8*)&Ks[c][(mf*16 + l16) * 64 +
                                                   (((ks*4 + quad) ^ (l16 & 7)) * 8)];
                sf[mf] = mfma16(kf, qf[ks], sf[mf]);
            }
        __builtin_amdgcn_s_setprio(0);

        // D2: P = exp2(S*scl), write this wave's 16-q half of the pair's P
        #pragma unroll
        for (int mf = 0; mf < 4; ++mf) {
            float p0 = __builtin_amdgcn_exp2f(sf[mf][0] * SCL);
            float p1 = __builtin_amdgcn_exp2f(sf[mf][1] * SCL);
            float p2 = __builtin_amdgcn_exp2f(sf[mf][2] * SCL);
            float p3 = __builtin_amdgcn_exp2f(sf[mf][3] * SCL);
            *(bf16x4*)&Pl[pair][(half*16 + l16) * LP + mf*16 + quad*4] =
                (bf16x4){(bf16)p0, (bf16)p1, (bf16)p2, (bf16)p3};
        }
        // P is read by the pair partner -> full barrier (writes drained first)
        __asm__ volatile("s_waitcnt lgkmcnt(0)" ::: "memory");
        __builtin_amdgcn_s_barrier();
        __builtin_amdgcn_sched_barrier(0);

        // D3: O += P @ (V or xV) over the pair's 32 q; rs += P @ 1
        __builtin_amdgcn_s_setprio(1);
        #pragma unroll
        for (int ks = 0; ks < 2; ++ks) {
            bf16x8 pa[2];
            #pragma unroll
            for (int mf = 0; mf < 2; ++mf)
                pa[mf] = *(const bf16x8*)&Pl[pair][(mf*16 + l16) * LP + ks*32 + quad*8];
            #pragma unroll
            for (int mf = 0; mf < 2; ++mf)
                rsa[mf] = mfma16(pa[mf], one8, rsa[mf]);
            const bf16* __restrict__ tile = half ? xVt : Vt;
            #pragma unroll
            for (int cc = 0; cc < 4; ++cc) {
                bf16x8 bv = *(const bf16x8*)&tile[(cc*16 + l16) * LP + ks*32 + quad*8];
                #pragma unroll
                for (int mf = 0; mf < 2; ++mf)
                    ov[mf][cc] = mfma16(pa[mf], bv, ov[mf][cc]);
            }
        }
        __builtin_amdgcn_s_setprio(0);

        // E: protect Vt/xVt/Pl overwrite next iter
        __builtin_amdgcn_sched_barrier(0);
        __builtin_amdgcn_s_barrier();
        c ^= 1;
    }

    // epilogue: rsa[mf][r] = row-sum for pair q-row mf*16+quad*4+r
    // (broadcast over l16). Wave A -> VB (vbar), wave B -> Q (kbar).
    bf16* __restrict__ outp = half ? Q : VB;
    #pragma unroll
    for (int mf = 0; mf < 2; ++mf)
        #pragma unroll
        for (int r = 0; r < 4; ++r) {
            const int qrow = mf * 16 + quad * 4 + r;
            const float inv = 1.0f / rsa[mf][r];
            const size_t base = hb + (size_t)(qp + qrow) * DH;
            #pragma unroll
            for (int cc = 0; cc < 4; ++cc)
                outp[base + cc*16 + l16] = (bf16)(ov[mf][cc][r] * inv);
        }
}

// ======================= legacy (R6, proven) fallback =======================

__global__ __launch_bounds__(256) void proj_gemm(
    const void* __restrict__ Xv, const float* __restrict__ W,
    const float* __restrict__ bias, void* __restrict__ Yv,
    int in_kind, int out_mode)
{
    __shared__ __align__(16) bf16 As[64 * LP];
    __shared__ __align__(16) bf16 Bs[128 * LP];
    const int tid  = threadIdx.x;
    const int wave = tid >> 6;
    const int lane = tid & 63;
    const int l16  = lane & 15;
    const int quad = lane >> 4;
    const int m0 = blockIdx.y * 64;
    const int n0 = blockIdx.x * 128;
    const int m_w = (wave >> 1) * 32;
    const int n_w = (wave & 1) * 64;
    const int ar = tid >> 2, ac = (tid & 3) * 16;
    const int br = tid >> 1, bc = (tid & 1) * 32;

    f32x4 acc[2][4];
    #pragma unroll
    for (int i = 0; i < 2; ++i)
        #pragma unroll
        for (int j = 0; j < 4; ++j) acc[i][j] = (f32x4){0.f,0.f,0.f,0.f};

    for (int kb = 0; kb < DX / 64; ++kb) {
        __syncthreads();
        if (in_kind == 0) {
            const float* xp = (const float*)Xv + (size_t)(m0 + ar) * DX + kb * 64 + ac;
            *(bf16x8*)&As[ar * LP + ac]     = cvt8(xp);
            *(bf16x8*)&As[ar * LP + ac + 8] = cvt8(xp + 8);
        } else {
            const bf16* xp = (const bf16*)Xv + ((size_t)kb * SEQ + (m0 + ar)) * DH + ac;
            *(bf16x8*)&As[ar * LP + ac]     = *(const bf16x8*)xp;
            *(bf16x8*)&As[ar * LP + ac + 8] = *(const bf16x8*)(xp + 8);
        }
        {
            const float* wp = W + (size_t)(n0 + br) * DX + kb * 64 + bc;
            #pragma unroll
            for (int g = 0; g < 4; ++g)
                *(bf16x8*)&Bs[br * LP + bc + g * 8] = cvt8(wp + g * 8);
        }
        __syncthreads();
        #pragma unroll
        for (int ks = 0; ks < 2; ++ks) {
            bf16x8 a0 = *(const bf16x8*)&As[(m_w + l16)      * LP + ks * 32 + quad * 8];
            bf16x8 a1 = *(const bf16x8*)&As[(m_w + 16 + l16) * LP + ks * 32 + quad * 8];
            #pragma unroll
            for (int nf = 0; nf < 4; ++nf) {
                bf16x8 b = *(const bf16x8*)&Bs[(n_w + nf * 16 + l16) * LP + ks * 32 + quad * 8];
                acc[0][nf] = mfma16(a0, b, acc[0][nf]);
                acc[1][nf] = mfma16(a1, b, acc[1][nf]);
            }
        }
    }
    #pragma unroll
    for (int mf = 0; mf < 2; ++mf)
        #pragma unroll
        for (int nf = 0; nf < 4; ++nf) {
            const int col = n0 + n_w + nf * 16 + l16;
            const float bvv = bias[col];
            #pragma unroll
            for (int r = 0; r < 4; ++r) {
                const int row = m0 + m_w + mf * 16 + quad * 4 + r;
                float v = acc[mf][nf][r] + bvv;
                if (out_mode == 0) {
                    int h = col >> 6, d = col & 63;
                    ((bf16*)Yv)[((size_t)h * SEQ + row) * DH + d] = (bf16)v;
                } else {
                    ((float*)Yv)[(size_t)row * DX + col] = v;
                }
            }
        }
}

__global__ __launch_bounds__(256) void attn_dual(
    bf16* __restrict__ Q, const bf16* __restrict__ K,
    const bf16* __restrict__ V, const bf16* __restrict__ xV,
    bf16* __restrict__ vb)
{
    __shared__ __align__(16) bf16 Ks [64 * LP];
    __shared__ __align__(16) bf16 Vt [64 * LP];
    __shared__ __align__(16) bf16 xVt[64 * LP];
    __shared__ __align__(16) bf16 Pl[4][32 * LP];
    const int tid  = threadIdx.x;
    const int h    = blockIdx.y;
    const int qt   = blockIdx.x;
    const int wave = tid >> 6;
    const int lane = tid & 63;
    const int l16  = lane & 15;
    const int quad = lane >> 4;
    const size_t hb = (size_t)h * SEQ * DH;
    const int q0 = qt * 128 + wave * 32;

    bf16x8 qf[2][2];
    #pragma unroll
    for (int mf = 0; mf < 2; ++mf)
        #pragma unroll
        for (int ks = 0; ks < 2; ++ks)
            qf[mf][ks] = *(const bf16x8*)(Q + hb + (size_t)(q0 + mf*16 + l16) * DH + ks*32 + quad*8);

    float mr[2][4], lr[2][4];
    f32x4 ov[2][4], oxv[2][4];
    #pragma unroll
    for (int mf = 0; mf < 2; ++mf)
        #pragma unroll
        for (int r = 0; r < 4; ++r) { mr[mf][r] = -1e30f; lr[mf][r] = 0.f; }
    #pragma unroll
    for (int mf = 0; mf < 2; ++mf)
        #pragma unroll
        for (int c = 0; c < 4; ++c) {
            ov[mf][c]  = (f32x4){0.f,0.f,0.f,0.f};
            oxv[mf][c] = (f32x4){0.f,0.f,0.f,0.f};
        }
    const int sr = tid >> 2, sc = (tid & 3) * 16;
    const int vkp = (tid & 31) * 2;
    const int vd0 = (tid >> 5) * 8;
    const float SCL = 0.125f * 1.4426950408889634f;

    for (int kt = 0; kt < SEQ; kt += 64) {
        __syncthreads();
        {
            const bf16* kpt = K + hb + (size_t)(kt + sr) * DH + sc;
            *(bf16x8*)&Ks[sr * LP + sc]     = *(const bf16x8*)kpt;
            *(bf16x8*)&Ks[sr * LP + sc + 8] = *(const bf16x8*)(kpt + 8);
            const size_t g0 = hb + (size_t)(kt + vkp) * DH + vd0;
            bf16x8 v0 = *(const bf16x8*)(V + g0);
            bf16x8 v1 = *(const bf16x8*)(V + g0 + DH);
            bf16x8 x0 = *(const bf16x8*)(xV + g0);
            bf16x8 x1 = *(const bf16x8*)(xV + g0 + DH);
            #pragma unroll
            for (int j = 0; j < 8; ++j) {
                *(bf16x2*)&Vt [(vd0 + j) * LP + vkp] = (bf16x2){v0[j], v1[j]};
                *(bf16x2*)&xVt[(vd0 + j) * LP + vkp] = (bf16x2){x0[j], x1[j]};
            }
        }
        __syncthreads();
        f32x4 sf[2][4];
        #pragma unroll
        for (int mf = 0; mf < 2; ++mf)
            #pragma unroll
            for (int nf = 0; nf < 4; ++nf) sf[mf][nf] = (f32x4){0.f,0.f,0.f,0.f};
        #pragma unroll
        for (int ks = 0; ks < 2; ++ks)
            #pragma unroll
            for (int nf = 0; nf < 4; ++nf) {
                bf16x8 bk = *(const bf16x8*)&Ks[(nf * 16 + l16) * LP + ks * 32 + quad * 8];
                sf[0][nf] = mfma16(qf[0][ks], bk, sf[0][nf]);
                sf[1][nf] = mfma16(qf[1][ks], bk, sf[1][nf]);
            }
        float mx[2][4], rs[2][4], alpha[2][4];
        #pragma unroll
        for (int mf = 0; mf < 2; ++mf)
            #pragma unroll
            for (int r = 0; r < 4; ++r) {
                float aa = fmaxf(sf[mf][0][r], sf[mf][1][r]);
                float bb = fmaxf(sf[mf][2][r], sf[mf][3][r]);
                mx[mf][r] = fmaxf(aa, bb) * SCL;
            }
        #pragma unroll
        for (int off = 1; off < 16; off <<= 1)
            #pragma unroll
            for (int mf = 0; mf < 2; ++mf)
                #pragma unroll
                for (int r = 0; r < 4; ++r)
                    mx[mf][r] = fmaxf(mx[mf][r], __shfl_xor(mx[mf][r], off, 64));
        #pragma unroll
        for (int mf = 0; mf < 2; ++mf)
            #pragma unroll
            for (int r = 0; r < 4; ++r) {
                float mnew = fmaxf(mr[mf][r], mx[mf][r]);
                alpha[mf][r] = exp2f(mr[mf][r] - mnew);
                mr[mf][r] = mnew;
            }
        bf16* pw = &Pl[wave][0];
        #pragma unroll
        for (int mf = 0; mf < 2; ++mf)
            #pragma unroll
            for (int r = 0; r < 4; ++r) rs[mf][r] = 0.f;
        #pragma unroll
        for (int mf = 0; mf < 2; ++mf)
            #pragma unroll
            for (int nf = 0; nf < 4; ++nf)
                #pragma unroll
                for (int r = 0; r < 4; ++r) {
                    float p = exp2f(sf[mf][nf][r] * SCL - mr[mf][r]);
                    rs[mf][r] += p;
                    pw[(mf * 16 + quad * 4 + r) * LP + nf * 16 + l16] = (bf16)p;
                }
        #pragma unroll
        for (int off = 1; off < 16; off <<= 1)
            #pragma unroll
            for (int mf = 0; mf < 2; ++mf)
                #pragma unroll
                for (int r = 0; r < 4; ++r)
                    rs[mf][r] += __shfl_xor(rs[mf][r], off, 64);
        #pragma unroll
        for (int mf = 0; mf < 2; ++mf)
            #pragma unroll
            for (int r = 0; r < 4; ++r)
                lr[mf][r] = lr[mf][r] * alpha[mf][r] + rs[mf][r];
        #pragma unroll
        for (int mf = 0; mf < 2; ++mf)
            #pragma unroll
            for (int c = 0; c < 4; ++c)
                #pragma unroll
                for (int r = 0; r < 4; ++r) {
                    ov[mf][c][r]  *= alpha[mf][r];
                    oxv[mf][c][r] *= alpha[mf][r];
                }
        __asm__ volatile("s_waitcnt lgkmcnt(0)" ::: "memory");
        #pragma unroll
        for (int ks = 0; ks < 2; ++ks) {
            bf16x8 pa0 = *(const bf16x8*)&Pl[wave][(l16)      * LP + ks * 32 + quad * 8];
            bf16x8 pa1 = *(const bf16x8*)&Pl[wave][(16 + l16) * LP + ks * 32 + quad * 8];
            #pragma unroll
            for (int c = 0; c < 4; ++c) {
                bf16x8 bv = *(const bf16x8*)&Vt [(c * 16 + l16) * LP + ks * 32 + quad * 8];
                ov[0][c]  = mfma16(pa0, bv, ov[0][c]);
                ov[1][c]  = mfma16(pa1, bv, ov[1][c]);
                bf16x8 bx = *(const bf16x8*)&xVt[(c * 16 + l16) * LP + ks * 32 + quad * 8];
                oxv[0][c] = mfma16(pa0, bx, oxv[0][c]);
                oxv[1][c] = mfma16(pa1, bx, oxv[1][c]);
            }
        }
    }
    #pragma unroll
    for (int mf = 0; mf < 2; ++mf)
        #pragma unroll
        for (int r = 0; r < 4; ++r) {
            const int s = q0 + mf * 16 + quad * 4 + r;
            const float inv = 1.0f / lr[mf][r];
            #pragma unroll
            for (int c = 0; c < 4; ++c) {
                const int d = c * 16 + l16;
                Q [hb + (size_t)s * DH + d] = (bf16)(oxv[mf][c][r] * inv);
                vb[hb + (size_t)s * DH + d] = (bf16)(ov[mf][c][r]  * inv);
            }
        }
}

// ================================ launch ====================================

extern "C" void kernel_launch(void* const* d_in, const int* in_sizes, int n_in,
                              void* d_out, int out_size, void* d_ws, size_t ws_size,
                              hipStream_t stream) {
    const float* query = (const float*)d_in[0];
    const float* key   = (const float*)d_in[1];
    const float* value = (const float*)d_in[2];
    const float* Wq  = (const float*)d_in[3];  const float* bq  = (const float*)d_in[4];
    const float* Wk  = (const float*)d_in[5];  const float* bk  = (const float*)d_in[6];
    const float* Wv  = (const float*)d_in[7];  const float* bv  = (const float*)d_in[8];
    const float* Wxv = (const float*)d_in[9];  const float* bxv = (const float*)d_in[10];
    const float* Wxo = (const float*)d_in[11]; const float* bxo = (const float*)d_in[12];
    const float* Wmo = (const float*)d_in[13]; const float* bmo = (const float*)d_in[14];

    float* out = (float*)d_out;
    const size_t SB = (size_t)SEQ * DX;          // 2,097,152 el
    const size_t M1 = 1ull << 20;

    dim3 blk(256);

    if (ws_size >= (76ull << 20)) {
        // ---------------- Plan A: merged batches, bf16 everywhere -----------
        bf16* ws = (bf16*)d_ws;
        bf16* qb  = ws;                 // 4M el
        bf16* kb  = ws + 4 * M1;
        bf16* vb  = ws + 8 * M1;
        bf16* Wqb = ws + 12 * M1;       // 6 x 1M el
        bf16* Wkb = Wqb + M1;
        bf16* Wvb = Wkb + M1;
        bf16* Wxvb= Wvb + M1;
        bf16* Wxob= Wxvb + M1;
        bf16* Wmob= Wxob + M1;
        bf16* Qs  = ws + 18 * M1;       // bhsd [2][16][2048][64], 4M el each
        bf16* Kss = ws + 22 * M1;
        bf16* Vs  = ws + 26 * M1;
        bf16* xVs = ws + 30 * M1;
        bf16* VBs = ws + 34 * M1;

        cvt_all<<<9216, blk, 0, stream>>>(query, key, value,
                                          Wq, Wk, Wv, Wxv, Wxo, Wmo, ws + 0);

        G4 g1;
        g1.X[0]=qb;  g1.W[0]=Wqb;  g1.B[0]=bq;  g1.Yb[0]=Qs;  g1.Yf[0]=nullptr; g1.xmode[0]=0; g1.ymode[0]=0;
        g1.X[1]=kb;  g1.W[1]=Wkb;  g1.B[1]=bk;  g1.Yb[1]=Kss; g1.Yf[1]=nullptr; g1.xmode[1]=0; g1.ymode[1]=0;
        g1.X[2]=vb;  g1.W[2]=Wvb;  g1.B[2]=bv;  g1.Yb[2]=Vs;  g1.Yf[2]=nullptr; g1.xmode[2]=0; g1.ymode[2]=0;
        g1.X[3]=kb;  g1.W[3]=Wxvb; g1.B[3]=bxv; g1.Yb[3]=xVs; g1.Yf[3]=nullptr; g1.xmode[3]=0; g1.ymode[3]=0;
        gemm256<256><<<dim3(4, 16, 4), dim3(512), 0, stream>>>(g1);

        attn_pair<<<dim3(16, NH, 2), dim3(512), 0, stream>>>(Qs, Kss, Vs, xVs, VBs);

        G4 g2;
        g2.X[0]=Qs;  g2.W[0]=Wxob; g2.B[0]=bxo; g2.Yb[0]=nullptr; g2.Yf[0]=out;          g2.xmode[0]=1; g2.ymode[0]=1;
        g2.X[1]=VBs; g2.W[1]=Wmob; g2.B[1]=bmo; g2.Yb[1]=nullptr; g2.Yf[1]=out + 2*SB;   g2.xmode[1]=1; g2.ymode[1]=1;
        g2.X[2]=Qs;  g2.W[2]=Wxob; g2.B[2]=bxo; g2.Yb[2]=nullptr; g2.Yf[2]=out;          g2.xmode[2]=1; g2.ymode[2]=1;
        g2.X[3]=Qs;  g2.W[3]=Wxob; g2.B[3]=bxo; g2.Yb[3]=nullptr; g2.Yf[3]=out;          g2.xmode[3]=1; g2.ymode[3]=1;
        gemm256<128><<<dim3(4, 32, 2), dim3(512), 0, stream>>>(g2);
    } else {
        // ---------------- fallback: proven R6 path (20 MB ws) ---------------
        bf16* Qs  = (bf16*)d_ws;
        bf16* Ksb = Qs  + SB;
        bf16* Vs  = Ksb + SB;
        bf16* xVs = Vs  + SB;
        bf16* vbs = xVs + SB;
        dim3 pg(8, 32);
        dim3 ag(16, NH);
        for (int b = 0; b < 2; ++b) {
            const float* q_b = query + (size_t)b * SB;
            const float* k_b = key   + (size_t)b * SB;
            const float* v_b = value + (size_t)b * SB;
            float* x_b = out + (size_t)b * SB;
            float* m_b = out + 2 * SB + (size_t)b * SB;
            proj_gemm<<<pg, blk, 0, stream>>>(q_b, Wq,  bq,  Qs,  0, 0);
            proj_gemm<<<pg, blk, 0, stream>>>(k_b, Wk,  bk,  Ksb, 0, 0);
            proj_gemm<<<pg, blk, 0, stream>>>(v_b, Wv,  bv,  Vs,  0, 0);
            proj_gemm<<<pg, blk, 0, stream>>>(k_b, Wxv, bxv, xVs, 0, 0);
            attn_dual<<<ag, blk, 0, stream>>>(Qs, Ksb, Vs, xVs, vbs);
            proj_gemm<<<pg, blk, 0, stream>>>(Qs,  Wxo, bxo, x_b, 1, 1);
            proj_gemm<<<pg, blk, 0, stream>>>(vbs, Wmo, bmo, m_b, 1, 1);
        }
    }
}

// Round 6
// 265.538 us; speedup vs baseline: 1.2199x; 1.0682x over previous
//
#include <hip/hip_runtime.h>
#include <math.h>

typedef __bf16 bf16;
typedef __bf16 bf16x2 __attribute__((ext_vector_type(2)));
typedef __bf16 bf16x4 __attribute__((ext_vector_type(4)));
typedef __bf16 bf16x8 __attribute__((ext_vector_type(8)));
typedef float f32x4 __attribute__((ext_vector_type(4)));

#define SEQ 2048
#define DH 64
#define DX 1024
#define NH 16
#define LP 72   // padded LDS row stride (64+8)

static __device__ __forceinline__ f32x4 mfma16(bf16x8 a, bf16x8 b, f32x4 c) {
    return __builtin_amdgcn_mfma_f32_16x16x32_bf16(a, b, c, 0, 0, 0);
}
static __device__ __forceinline__ bf16x8 cvt8(const float* __restrict__ p) {
    f32x4 a = *(const f32x4*)p;
    f32x4 b = *(const f32x4*)(p + 4);
    bf16x8 r;
    #pragma unroll
    for (int j = 0; j < 4; ++j) { r[j] = (bf16)a[j]; r[4 + j] = (bf16)b[j]; }
    return r;
}

// async global->LDS, 16 B per lane (lands at ldsbase + lane*16)
#define GL16(gp, lp) __builtin_amdgcn_global_load_lds( \
    (const __attribute__((address_space(1))) void*)(gp), \
    (__attribute__((address_space(3))) void*)(lp), 16, 0, 0)

// ============================ PLAN A kernels ================================

// f32 -> bf16 bulk convert: 3 inputs (4M el each) + 6 weights (1M el each)
// into ws at fixed offsets. 18M elements, 8 per thread.
__global__ __launch_bounds__(256) void cvt_all(
    const float* __restrict__ q, const float* __restrict__ k,
    const float* __restrict__ v,
    const float* __restrict__ w0, const float* __restrict__ w1,
    const float* __restrict__ w2, const float* __restrict__ w3,
    const float* __restrict__ w4, const float* __restrict__ w5,
    bf16* __restrict__ out)
{
    const size_t i = (size_t)blockIdx.x * 2048 + threadIdx.x * 8;
    const int seg = (int)(i >> 20);
    const float* s;
    size_t off;
    if (seg < 4)       { s = q; off = i; }
    else if (seg < 8)  { s = k; off = i - (4ull << 20); }
    else if (seg < 12) { s = v; off = i - (8ull << 20); }
    else {
        const float* ww[6] = {w0, w1, w2, w3, w4, w5};
        s = ww[seg - 12]; off = i - ((size_t)seg << 20);
    }
    *(bf16x8*)(out + i) = cvt8(s + off);
}

// fused multi-GEMM: Y_z = X_z @ W_z^T + bias_z, M=4096, N=K=1024, all bf16 in.
// xmode: 0 = X row-major [4096][1024]; 1 = X bhsd [2][16][2048][64]
// ymode: 0 = Y bf16 bhsd;              1 = Y f32 row-major
struct G4 {
    const bf16* X[4]; const bf16* W[4]; const float* B[4];
    bf16* Yb[4]; float* Yf[4]; int xmode[4]; int ymode[4];
};

// R3: 256-wide-N tile, BK=64, 8 waves (2M x 4N), double-buffered LDS.
// R4: XCD-bijective block swizzle (T1).
// R6: (a) counted-vmcnt pipeline (T4): stage(next) -> s_waitcnt vmcnt(N)
//     (N = GL16s just issued; all older = current buffer -> landed) ->
//     s_barrier -> compute -> s_barrier. Prefetch stays in flight across
//     the whole compute phase instead of being drained by __syncthreads.
//     vmcnt BEFORE the barrier (m201 discipline) gives the cross-wave
//     guarantee: after the barrier every wave has verified its own share.
//     (b) bhsd epilogue repack via LDS: acc -> LDS (stride 264) -> bf16x8
//     row-contiguous stores (full 128-B head chunks). Removes the 2.4x
//     write amplification (78 MB -> ~34 MB) of scattered 2-B stores.
template<int BM>
__global__ __launch_bounds__(512) void gemm256(G4 a)
{
    constexpr int MREP = BM / 32;           // M fragments per wave (8 or 4)
    constexpr int NT   = DX / 64;           // 16 K-steps
    constexpr int AEL  = BM * 64;
    constexpr int BEL  = 256 * 64;
    constexpr int SN   = BM / 64 + 4;       // GL16 per wave per stage (8 / 6)
    __shared__ __align__(16) bf16 smem[2 * AEL + 2 * BEL];

    const int z = blockIdx.z;
    const bf16* __restrict__ X = a.X[z];
    const bf16* __restrict__ W = a.W[z];
    const int xmode = a.xmode[z], ymode = a.ymode[z];

    const int tid  = threadIdx.x;
    const int wid  = tid >> 6;
    const int lane = tid & 63;
    const int l16  = lane & 15;
    const int quad = lane >> 4;
    const int wm   = wid >> 2;              // 0..1
    const int wn   = wid & 3;               // 0..3

    // XCD swizzle: t = linear 2D id; XCD k gets contiguous chunk of tiles
    // (x-major) -> all 4 x-blocks of a given y run on one XCD.
    const int nx = gridDim.x;               // 4
    const int nt = nx * gridDim.y;          // 64 (g1) / 128 (g2), %8 == 0
    int t = blockIdx.x + nx * blockIdx.y;
    t = (t & 7) * (nt >> 3) + (t >> 3);
    const int n0 = (t % nx) * 256;
    const int m0 = (t / nx) * BM;

    // staging geometry: per GL16 call a wave covers 8 rows x 64 cols.
    // LDS[row][c] = global[row][c ^ (row&7)]  (linear dest, swizzled src)
    const int srow8 = lane >> 3;            // row within 8-row group
    const int sch   = (lane & 7) ^ srow8;   // pre-swizzled source chunk

    f32x4 acc[MREP][4];
    #pragma unroll
    for (int i = 0; i < MREP; ++i)
        #pragma unroll
        for (int j = 0; j < 4; ++j) acc[i][j] = (f32x4){0.f,0.f,0.f,0.f};

    auto stage = [&](int buf, int kb) {
        bf16* Ab = smem + buf * AEL;
        bf16* Bb = smem + 2 * AEL + buf * BEL;
        #pragma unroll
        for (int g = 0; g < BM / 64; ++g) {
            const int row = g * 64 + wid * 8 + srow8;   // row in A tile
            const bf16* src;
            if (xmode == 0) {
                src = X + (size_t)(m0 + row) * DX + kb * 64 + sch * 8;
            } else {
                const int m = m0 + row;
                const int b = m >> 11, s = m & 2047;
                src = X + ((size_t)(b * NH + kb) * SEQ + s) * DH + sch * 8;
            }
            GL16(src, Ab + (g * 64 + wid * 8) * 64);
        }
        #pragma unroll
        for (int g = 0; g < 4; ++g) {
            const int row = g * 64 + wid * 8 + srow8;   // row in B tile
            const bf16* src = W + (size_t)(n0 + row) * DX + kb * 64 + sch * 8;
            GL16(src, Bb + (g * 64 + wid * 8) * 64);
        }
    };

    stage(0, 0);

    int cur = 0;
    for (int kb = 0; kb < NT; ++kb) {
        if (kb + 1 < NT) {
            stage(cur ^ 1, kb + 1);        // SN newer vmem ops in flight
            if constexpr (SN == 8) {
                __asm__ volatile("s_waitcnt vmcnt(8)" ::: "memory");
            } else {
                __asm__ volatile("s_waitcnt vmcnt(6)" ::: "memory");
            }
        } else {
            __asm__ volatile("s_waitcnt vmcnt(0)" ::: "memory");
        }
        __builtin_amdgcn_s_barrier();      // all waves' cur-buffer loads landed
        __builtin_amdgcn_sched_barrier(0);

        const bf16* Ab = smem + cur * AEL;
        const bf16* Bb = smem + 2 * AEL + cur * BEL;
        #pragma unroll
        for (int ks = 0; ks < 2; ++ks) {
            bf16x8 af[MREP], bfr[4];
            const int cc = (ks * 4 + quad) ^ (l16 & 7); // swizzled chunk
            #pragma unroll
            for (int mf = 0; mf < MREP; ++mf)
                af[mf] = *(const bf16x8*)&Ab[(wm * (BM/2) + mf * 16 + l16) * 64 + cc * 8];
            #pragma unroll
            for (int nf = 0; nf < 4; ++nf)
                bfr[nf] = *(const bf16x8*)&Bb[(wn * 64 + nf * 16 + l16) * 64 + cc * 8];
            #pragma unroll
            for (int mf = 0; mf < MREP; ++mf)
                #pragma unroll
                for (int nf = 0; nf < 4; ++nf)
                    acc[mf][nf] = mfma16(af[mf], bfr[nf], acc[mf][nf]);
        }
        __builtin_amdgcn_sched_barrier(0);
        __builtin_amdgcn_s_barrier();      // all reads of cur done before
        cur ^= 1;                          // it is re-staged next iter
    }

    if (ymode == 0) {
        // bhsd bf16 out: repack through LDS (reuse staging buffers),
        // 128-row passes, row stride 264 el (bank stagger).
        constexpr int EPS = 264;
        constexpr int PR  = 128;
        constexpr int NP  = BM / PR;        // 2 (BM=256) / 1 (BM=128)
        bf16* Ep = smem;
        #pragma unroll
        for (int p = 0; p < NP; ++p) {
            __builtin_amdgcn_s_barrier();
            if (NP == 1 || wm == p) {
                #pragma unroll
                for (int nf = 0; nf < 4; ++nf) {
                    const int col = wn * 64 + nf * 16 + l16;
                    const float bvv = a.B[z][n0 + col];
                    #pragma unroll
                    for (int mf = 0; mf < MREP; ++mf) {
                        const int rb = wm * (BM/2) + mf * 16 + quad * 4 - p * PR;
                        #pragma unroll
                        for (int r = 0; r < 4; ++r)
                            Ep[(rb + r) * EPS + col] = (bf16)(acc[mf][nf][r] + bvv);
                    }
                }
            }
            __asm__ volatile("s_waitcnt lgkmcnt(0)" ::: "memory");
            __builtin_amdgcn_s_barrier();
            #pragma unroll
            for (int j = 0; j < 8; ++j) {          // 128*256/8/512 = 8
                const int g    = j * 512 + tid;
                const int lrow = g >> 5;
                const int cg   = g & 31;
                bf16x8 vv = *(const bf16x8*)&Ep[lrow * EPS + cg * 8];
                const int row = m0 + p * PR + lrow;
                const int b = row >> 11, s = row & 2047;
                const int col = n0 + cg * 8;
                const int h = col >> 6, d = col & 63;
                *(bf16x8*)&a.Yb[z][((size_t)(b * NH + h) * SEQ + s) * DH + d] = vv;
            }
        }
    } else {
        // f32 row-major out: direct stores (64-B contiguous per quad-row,
        // full lines -> no amplification).
        #pragma unroll
        for (int nf = 0; nf < 4; ++nf) {
            const int col = n0 + wn * 64 + nf * 16 + l16;
            const float bvv = a.B[z][col];
            #pragma unroll
            for (int mf = 0; mf < MREP; ++mf) {
                #pragma unroll
                for (int r = 0; r < 4; ++r) {
                    const int row = m0 + wm * (BM/2) + mf * 16 + quad * 4 + r;
                    a.Yf[z][(size_t)row * DX + col] = acc[mf][nf][r] + bvv;
                }
            }
        }
    }
}

// R5 dual flash attention: grid (qt 16, h 16, b 2) = 512 blocks, block 512.
// 2 blocks/CU (4 waves/SIMD). Pair structure: 8 waves in 4 pairs; pair p
// owns q rows [p*32, p*32+32). Wave A does P@V -> VB, wave B does
// P@xV -> Q; each wave computes QK^T + exp for its 16-q half; P shared
// through LDS. Pipeline: GL16 K dbuf (XOR-swizzled), reg-prefetch V/xV,
// counted vmcnt, setprio on MFMA. Softmax: no-max exp2, row-sum via P@1.
// R6: vmcnt moved BEFORE the barrier (m201 cross-wave discipline).
__global__ __launch_bounds__(512) void attn_pair(
    bf16* __restrict__ Q, const bf16* __restrict__ K,
    const bf16* __restrict__ V, const bf16* __restrict__ xV,
    bf16* __restrict__ VB)
{
    __shared__ __align__(16) bf16 Ks[2][64 * 64];   // XOR-swizzled (GL16)
    __shared__ __align__(16) bf16 Vt [64 * LP];     // [d][k] transposed
    __shared__ __align__(16) bf16 xVt[64 * LP];
    __shared__ __align__(16) bf16 Pl[4][32 * LP];   // per-pair [q 32][k 64]

    const int tid  = threadIdx.x;
    const int wid  = tid >> 6;
    const int lane = tid & 63;
    const int l16  = lane & 15;
    const int quad = lane >> 4;
    const int pair = wid >> 1;
    const int half = wid & 1;                // 0: V->VB, 1: xV->Q
    const size_t hb = ((size_t)blockIdx.z * NH + blockIdx.y) * SEQ * DH;
    const int qp = blockIdx.x * 128 + pair * 32;   // pair base (32 q)
    const int q0 = qp + half * 16;                 // this wave's 16-q half

    bf16x8 qf[2];
    #pragma unroll
    for (int ks = 0; ks < 2; ++ks)
        qf[ks] = *(const bf16x8*)(Q + hb + (size_t)(q0 + l16) * DH + ks*32 + quad*8);

    bf16x8 one8;
    #pragma unroll
    for (int j = 0; j < 8; ++j) one8[j] = (bf16)1.0f;

    f32x4 ov[2][4];          // 32 q x 64 d (one value array)
    f32x4 rsa[2];            // row-sums for 32 q
    #pragma unroll
    for (int mf = 0; mf < 2; ++mf) {
        rsa[mf] = (f32x4){0.f,0.f,0.f,0.f};
        #pragma unroll
        for (int c = 0; c < 4; ++c) ov[mf][c] = (f32x4){0.f,0.f,0.f,0.f};
    }

    // K staging: wave w stages rows w*8..w*8+7 (1 GL16), XOR pre-swizzled
    const int krow = lane >> 3;
    const int kch  = (lane & 7) ^ krow;
    // V/xV staging: threads 0-255 stage V, 256-511 stage xV (same pattern)
    const bf16* __restrict__ vsrc = (tid & 256) ? xV : V;
    bf16* __restrict__ vdst = (tid & 256) ? xVt : Vt;
    const int t8  = tid & 255;
    const int vkp = (t8 & 31) * 2;
    const int vd0 = (t8 >> 5) * 8;
    const float SCL = 0.125f * 1.4426950408889634f;

    // ---- prologue: prefetch tile 0 ----
    bf16x8 pv0, pv1;
    {
        const bf16* kg = K + hb + (size_t)(wid*8 + krow) * DH + kch*8;
        GL16(kg, &Ks[0][(wid*8) * 64]);
        const size_t g0 = hb + (size_t)vkp * DH + vd0;
        pv0 = *(const bf16x8*)(vsrc + g0);
        pv1 = *(const bf16x8*)(vsrc + g0 + DH);
    }

    int c = 0;
    for (int kt = 0; kt < SEQ; kt += 64) {
        // A: commit prefetched V/xV column-slices (compiler waits pv here)
        #pragma unroll
        for (int j = 0; j < 8; ++j)
            *(bf16x2*)&vdst[(vd0 + j) * LP + vkp] = (bf16x2){pv0[j], pv1[j]};
        // B: issue prefetch for tile t+1 (3 vmem ops/wave)
        if (kt + 64 < SEQ) {
            const bf16* kg = K + hb + (size_t)(kt + 64 + wid*8 + krow) * DH + kch*8;
            GL16(kg, &Ks[c ^ 1][(wid*8) * 64]);
            const size_t g0 = hb + (size_t)(kt + 64 + vkp) * DH + vd0;
            pv0 = *(const bf16x8*)(vsrc + g0);
            pv1 = *(const bf16x8*)(vsrc + g0 + DH);
        }
        // C: own loads verified (vmcnt BEFORE barrier), then sync
        __asm__ volatile("s_waitcnt lgkmcnt(0)" ::: "memory");
        __asm__ volatile("s_waitcnt vmcnt(3)" ::: "memory");
        __builtin_amdgcn_s_barrier();
        __builtin_amdgcn_sched_barrier(0);

        // D1: S^T = K Q^T for this wave's 16 q (swizzled Ks read)
        f32x4 sf[4];
        #pragma unroll
        for (int mf = 0; mf < 4; ++mf) sf[mf] = (f32x4){0.f,0.f,0.f,0.f};
        __builtin_amdgcn_s_setprio(1);
        #pragma unroll
        for (int ks = 0; ks < 2; ++ks)
            #pragma unroll
            for (int mf = 0; mf < 4; ++mf) {
                bf16x8 kf = *(const bf16x8*)&Ks[c][(mf*16 + l16) * 64 +
                                                   (((ks*4 + quad) ^ (l16 & 7)) * 8)];
                sf[mf] = mfma16(kf, qf[ks], sf[mf]);
            }
        __builtin_amdgcn_s_setprio(0);

        // D2: P = exp2(S*scl), write this wave's 16-q half of the pair's P
        #pragma unroll
        for (int mf = 0; mf < 4; ++mf) {
            float p0 = __builtin_amdgcn_exp2f(sf[mf][0] * SCL);
            float p1 = __builtin_amdgcn_exp2f(sf[mf][1] * SCL);
            float p2 = __builtin_amdgcn_exp2f(sf[mf][2] * SCL);
            float p3 = __builtin_amdgcn_exp2f(sf[mf][3] * SCL);
            *(bf16x4*)&Pl[pair][(half*16 + l16) * LP + mf*16 + quad*4] =
                (bf16x4){(bf16)p0, (bf16)p1, (bf16)p2, (bf16)p3};
        }
        // P is read by the pair partner -> full barrier (writes drained first)
        __asm__ volatile("s_waitcnt lgkmcnt(0)" ::: "memory");
        __builtin_amdgcn_s_barrier();
        __builtin_amdgcn_sched_barrier(0);

        // D3: O += P @ (V or xV) over the pair's 32 q; rs += P @ 1
        __builtin_amdgcn_s_setprio(1);
        #pragma unroll
        for (int ks = 0; ks < 2; ++ks) {
            bf16x8 pa[2];
            #pragma unroll
            for (int mf = 0; mf < 2; ++mf)
                pa[mf] = *(const bf16x8*)&Pl[pair][(mf*16 + l16) * LP + ks*32 + quad*8];
            #pragma unroll
            for (int mf = 0; mf < 2; ++mf)
                rsa[mf] = mfma16(pa[mf], one8, rsa[mf]);
            const bf16* __restrict__ tile = half ? xVt : Vt;
            #pragma unroll
            for (int cc = 0; cc < 4; ++cc) {
                bf16x8 bv = *(const bf16x8*)&tile[(cc*16 + l16) * LP + ks*32 + quad*8];
                #pragma unroll
                for (int mf = 0; mf < 2; ++mf)
                    ov[mf][cc] = mfma16(pa[mf], bv, ov[mf][cc]);
            }
        }
        __builtin_amdgcn_s_setprio(0);

        // E: protect Vt/xVt/Pl overwrite next iter
        __builtin_amdgcn_sched_barrier(0);
        __builtin_amdgcn_s_barrier();
        c ^= 1;
    }

    // epilogue: rsa[mf][r] = row-sum for pair q-row mf*16+quad*4+r
    // (broadcast over l16). Wave A -> VB (vbar), wave B -> Q (kbar).
    bf16* __restrict__ outp = half ? Q : VB;
    #pragma unroll
    for (int mf = 0; mf < 2; ++mf)
        #pragma unroll
        for (int r = 0; r < 4; ++r) {
            const int qrow = mf * 16 + quad * 4 + r;
            const float inv = 1.0f / rsa[mf][r];
            const size_t base = hb + (size_t)(qp + qrow) * DH;
            #pragma unroll
            for (int cc = 0; cc < 4; ++cc)
                outp[base + cc*16 + l16] = (bf16)(ov[mf][cc][r] * inv);
        }
}

// ======================= legacy (R6, proven) fallback =======================

__global__ __launch_bounds__(256) void proj_gemm(
    const void* __restrict__ Xv, const float* __restrict__ W,
    const float* __restrict__ bias, void* __restrict__ Yv,
    int in_kind, int out_mode)
{
    __shared__ __align__(16) bf16 As[64 * LP];
    __shared__ __align__(16) bf16 Bs[128 * LP];
    const int tid  = threadIdx.x;
    const int wave = tid >> 6;
    const int lane = tid & 63;
    const int l16  = lane & 15;
    const int quad = lane >> 4;
    const int m0 = blockIdx.y * 64;
    const int n0 = blockIdx.x * 128;
    const int m_w = (wave >> 1) * 32;
    const int n_w = (wave & 1) * 64;
    const int ar = tid >> 2, ac = (tid & 3) * 16;
    const int br = tid >> 1, bc = (tid & 1) * 32;

    f32x4 acc[2][4];
    #pragma unroll
    for (int i = 0; i < 2; ++i)
        #pragma unroll
        for (int j = 0; j < 4; ++j) acc[i][j] = (f32x4){0.f,0.f,0.f,0.f};

    for (int kb = 0; kb < DX / 64; ++kb) {
        __syncthreads();
        if (in_kind == 0) {
            const float* xp = (const float*)Xv + (size_t)(m0 + ar) * DX + kb * 64 + ac;
            *(bf16x8*)&As[ar * LP + ac]     = cvt8(xp);
            *(bf16x8*)&As[ar * LP + ac + 8] = cvt8(xp + 8);
        } else {
            const bf16* xp = (const bf16*)Xv + ((size_t)kb * SEQ + (m0 + ar)) * DH + ac;
            *(bf16x8*)&As[ar * LP + ac]     = *(const bf16x8*)xp;
            *(bf16x8*)&As[ar * LP + ac + 8] = *(const bf16x8*)(xp + 8);
        }
        {
            const float* wp = W + (size_t)(n0 + br) * DX + kb * 64 + bc;
            #pragma unroll
            for (int g = 0; g < 4; ++g)
                *(bf16x8*)&Bs[br * LP + bc + g * 8] = cvt8(wp + g * 8);
        }
        __syncthreads();
        #pragma unroll
        for (int ks = 0; ks < 2; ++ks) {
            bf16x8 a0 = *(const bf16x8*)&As[(m_w + l16)      * LP + ks * 32 + quad * 8];
            bf16x8 a1 = *(const bf16x8*)&As[(m_w + 16 + l16) * LP + ks * 32 + quad * 8];
            #pragma unroll
            for (int nf = 0; nf < 4; ++nf) {
                bf16x8 b = *(const bf16x8*)&Bs[(n_w + nf * 16 + l16) * LP + ks * 32 + quad * 8];
                acc[0][nf] = mfma16(a0, b, acc[0][nf]);
                acc[1][nf] = mfma16(a1, b, acc[1][nf]);
            }
        }
    }
    #pragma unroll
    for (int mf = 0; mf < 2; ++mf)
        #pragma unroll
        for (int nf = 0; nf < 4; ++nf) {
            const int col = n0 + n_w + nf * 16 + l16;
            const float bvv = bias[col];
            #pragma unroll
            for (int r = 0; r < 4; ++r) {
                const int row = m0 + m_w + mf * 16 + quad * 4 + r;
                float v = acc[mf][nf][r] + bvv;
                if (out_mode == 0) {
                    int h = col >> 6, d = col & 63;
                    ((bf16*)Yv)[((size_t)h * SEQ + row) * DH + d] = (bf16)v;
                } else {
                    ((float*)Yv)[(size_t)row * DX + col] = v;
                }
            }
        }
}

__global__ __launch_bounds__(256) void attn_dual(
    bf16* __restrict__ Q, const bf16* __restrict__ K,
    const bf16* __restrict__ V, const bf16* __restrict__ xV,
    bf16* __restrict__ vb)
{
    __shared__ __align__(16) bf16 Ks [64 * LP];
    __shared__ __align__(16) bf16 Vt [64 * LP];
    __shared__ __align__(16) bf16 xVt[64 * LP];
    __shared__ __align__(16) bf16 Pl[4][32 * LP];
    const int tid  = threadIdx.x;
    const int h    = blockIdx.y;
    const int qt   = blockIdx.x;
    const int wave = tid >> 6;
    const int lane = tid & 63;
    const int l16  = lane & 15;
    const int quad = lane >> 4;
    const size_t hb = (size_t)h * SEQ * DH;
    const int q0 = qt * 128 + wave * 32;

    bf16x8 qf[2][2];
    #pragma unroll
    for (int mf = 0; mf < 2; ++mf)
        #pragma unroll
        for (int ks = 0; ks < 2; ++ks)
            qf[mf][ks] = *(const bf16x8*)(Q + hb + (size_t)(q0 + mf*16 + l16) * DH + ks*32 + quad*8);

    float mr[2][4], lr[2][4];
    f32x4 ov[2][4], oxv[2][4];
    #pragma unroll
    for (int mf = 0; mf < 2; ++mf)
        #pragma unroll
        for (int r = 0; r < 4; ++r) { mr[mf][r] = -1e30f; lr[mf][r] = 0.f; }
    #pragma unroll
    for (int mf = 0; mf < 2; ++mf)
        #pragma unroll
        for (int c = 0; c < 4; ++c) {
            ov[mf][c]  = (f32x4){0.f,0.f,0.f,0.f};
            oxv[mf][c] = (f32x4){0.f,0.f,0.f,0.f};
        }
    const int sr = tid >> 2, sc = (tid & 3) * 16;
    const int vkp = (tid & 31) * 2;
    const int vd0 = (tid >> 5) * 8;
    const float SCL = 0.125f * 1.4426950408889634f;

    for (int kt = 0; kt < SEQ; kt += 64) {
        __syncthreads();
        {
            const bf16* kpt = K + hb + (size_t)(kt + sr) * DH + sc;
            *(bf16x8*)&Ks[sr * LP + sc]     = *(const bf16x8*)kpt;
            *(bf16x8*)&Ks[sr * LP + sc + 8] = *(const bf16x8*)(kpt + 8);
            const size_t g0 = hb + (size_t)(kt + vkp) * DH + vd0;
            bf16x8 v0 = *(const bf16x8*)(V + g0);
            bf16x8 v1 = *(const bf16x8*)(V + g0 + DH);
            bf16x8 x0 = *(const bf16x8*)(xV + g0);
            bf16x8 x1 = *(const bf16x8*)(xV + g0 + DH);
            #pragma unroll
            for (int j = 0; j < 8; ++j) {
                *(bf16x2*)&Vt [(vd0 + j) * LP + vkp] = (bf16x2){v0[j], v1[j]};
                *(bf16x2*)&xVt[(vd0 + j) * LP + vkp] = (bf16x2){x0[j], x1[j]};
            }
        }
        __syncthreads();
        f32x4 sf[2][4];
        #pragma unroll
        for (int mf = 0; mf < 2; ++mf)
            #pragma unroll
            for (int nf = 0; nf < 4; ++nf) sf[mf][nf] = (f32x4){0.f,0.f,0.f,0.f};
        #pragma unroll
        for (int ks = 0; ks < 2; ++ks)
            #pragma unroll
            for (int nf = 0; nf < 4; ++nf) {
                bf16x8 bk = *(const bf16x8*)&Ks[(nf * 16 + l16) * LP + ks * 32 + quad * 8];
                sf[0][nf] = mfma16(qf[0][ks], bk, sf[0][nf]);
                sf[1][nf] = mfma16(qf[1][ks], bk, sf[1][nf]);
            }
        float mx[2][4], rs[2][4], alpha[2][4];
        #pragma unroll
        for (int mf = 0; mf < 2; ++mf)
            #pragma unroll
            for (int r = 0; r < 4; ++r) {
                float aa = fmaxf(sf[mf][0][r], sf[mf][1][r]);
                float bb = fmaxf(sf[mf][2][r], sf[mf][3][r]);
                mx[mf][r] = fmaxf(aa, bb) * SCL;
            }
        #pragma unroll
        for (int off = 1; off < 16; off <<= 1)
            #pragma unroll
            for (int mf = 0; mf < 2; ++mf)
                #pragma unroll
                for (int r = 0; r < 4; ++r)
                    mx[mf][r] = fmaxf(mx[mf][r], __shfl_xor(mx[mf][r], off, 64));
        #pragma unroll
        for (int mf = 0; mf < 2; ++mf)
            #pragma unroll
            for (int r = 0; r < 4; ++r) {
                float mnew = fmaxf(mr[mf][r], mx[mf][r]);
                alpha[mf][r] = exp2f(mr[mf][r] - mnew);
                mr[mf][r] = mnew;
            }
        bf16* pw = &Pl[wave][0];
        #pragma unroll
        for (int mf = 0; mf < 2; ++mf)
            #pragma unroll
            for (int r = 0; r < 4; ++r) rs[mf][r] = 0.f;
        #pragma unroll
        for (int mf = 0; mf < 2; ++mf)
            #pragma unroll
            for (int nf = 0; nf < 4; ++nf)
                #pragma unroll
                for (int r = 0; r < 4; ++r) {
                    float p = exp2f(sf[mf][nf][r] * SCL - mr[mf][r]);
                    rs[mf][r] += p;
                    pw[(mf * 16 + quad * 4 + r) * LP + nf * 16 + l16] = (bf16)p;
                }
        #pragma unroll
        for (int off = 1; off < 16; off <<= 1)
            #pragma unroll
            for (int mf = 0; mf < 2; ++mf)
                #pragma unroll
                for (int r = 0; r < 4; ++r)
                    rs[mf][r] += __shfl_xor(rs[mf][r], off, 64);
        #pragma unroll
        for (int mf = 0; mf < 2; ++mf)
            #pragma unroll
            for (int r = 0; r < 4; ++r)
                lr[mf][r] = lr[mf][r] * alpha[mf][r] + rs[mf][r];
        #pragma unroll
        for (int mf = 0; mf < 2; ++mf)
            #pragma unroll
            for (int c = 0; c < 4; ++c)
                #pragma unroll
                for (int r = 0; r < 4; ++r) {
                    ov[mf][c][r]  *= alpha[mf][r];
                    oxv[mf][c][r] *= alpha[mf][r];
                }
        __asm__ volatile("s_waitcnt lgkmcnt(0)" ::: "memory");
        #pragma unroll
        for (int ks = 0; ks < 2; ++ks) {
            bf16x8 pa0 = *(const bf16x8*)&Pl[wave][(l16)      * LP + ks * 32 + quad * 8];
            bf16x8 pa1 = *(const bf16x8*)&Pl[wave][(16 + l16) * LP + ks * 32 + quad * 8];
            #pragma unroll
            for (int c = 0; c < 4; ++c) {
                bf16x8 bv = *(const bf16x8*)&Vt [(c * 16 + l16) * LP + ks * 32 + quad * 8];
                ov[0][c]  = mfma16(pa0, bv, ov[0][c]);
                ov[1][c]  = mfma16(pa1, bv, ov[1][c]);
                bf16x8 bx = *(const bf16x8*)&xVt[(c * 16 + l16) * LP + ks * 32 + quad * 8];
                oxv[0][c] = mfma16(pa0, bx, oxv[0][c]);
                oxv[1][c] = mfma16(pa1, bx, oxv[1][c]);
            }
        }
    }
    #pragma unroll
    for (int mf = 0; mf < 2; ++mf)
        #pragma unroll
        for (int r = 0; r < 4; ++r) {
            const int s = q0 + mf * 16 + quad * 4 + r;
            const float inv = 1.0f / lr[mf][r];
            #pragma unroll
            for (int c = 0; c < 4; ++c) {
                const int d = c * 16 + l16;
                Q [hb + (size_t)s * DH + d] = (bf16)(oxv[mf][c][r] * inv);
                vb[hb + (size_t)s * DH + d] = (bf16)(ov[mf][c][r]  * inv);
            }
        }
}

// ================================ launch ====================================

extern "C" void kernel_launch(void* const* d_in, const int* in_sizes, int n_in,
                              void* d_out, int out_size, void* d_ws, size_t ws_size,
                              hipStream_t stream) {
    const float* query = (const float*)d_in[0];
    const float* key   = (const float*)d_in[1];
    const float* value = (const float*)d_in[2];
    const float* Wq  = (const float*)d_in[3];  const float* bq  = (const float*)d_in[4];
    const float* Wk  = (const float*)d_in[5];  const float* bk  = (const float*)d_in[6];
    const float* Wv  = (const float*)d_in[7];  const float* bv  = (const float*)d_in[8];
    const float* Wxv = (const float*)d_in[9];  const float* bxv = (const float*)d_in[10];
    const float* Wxo = (const float*)d_in[11]; const float* bxo = (const float*)d_in[12];
    const float* Wmo = (const float*)d_in[13]; const float* bmo = (const float*)d_in[14];

    float* out = (float*)d_out;
    const size_t SB = (size_t)SEQ * DX;          // 2,097,152 el
    const size_t M1 = 1ull << 20;

    dim3 blk(256);

    if (ws_size >= (76ull << 20)) {
        // ---------------- Plan A: merged batches, bf16 everywhere -----------
        bf16* ws = (bf16*)d_ws;
        bf16* qb  = ws;                 // 4M el
        bf16* kb  = ws + 4 * M1;
        bf16* vb  = ws + 8 * M1;
        bf16* Wqb = ws + 12 * M1;       // 6 x 1M el
        bf16* Wkb = Wqb + M1;
        bf16* Wvb = Wkb + M1;
        bf16* Wxvb= Wvb + M1;
        bf16* Wxob= Wxvb + M1;
        bf16* Wmob= Wxob + M1;
        bf16* Qs  = ws + 18 * M1;       // bhsd [2][16][2048][64], 4M el each
        bf16* Kss = ws + 22 * M1;
        bf16* Vs  = ws + 26 * M1;
        bf16* xVs = ws + 30 * M1;
        bf16* VBs = ws + 34 * M1;

        cvt_all<<<9216, blk, 0, stream>>>(query, key, value,
                                          Wq, Wk, Wv, Wxv, Wxo, Wmo, ws + 0);

        G4 g1;
        g1.X[0]=qb;  g1.W[0]=Wqb;  g1.B[0]=bq;  g1.Yb[0]=Qs;  g1.Yf[0]=nullptr; g1.xmode[0]=0; g1.ymode[0]=0;
        g1.X[1]=kb;  g1.W[1]=Wkb;  g1.B[1]=bk;  g1.Yb[1]=Kss; g1.Yf[1]=nullptr; g1.xmode[1]=0; g1.ymode[1]=0;
        g1.X[2]=vb;  g1.W[2]=Wvb;  g1.B[2]=bv;  g1.Yb[2]=Vs;  g1.Yf[2]=nullptr; g1.xmode[2]=0; g1.ymode[2]=0;
        g1.X[3]=kb;  g1.W[3]=Wxvb; g1.B[3]=bxv; g1.Yb[3]=xVs; g1.Yf[3]=nullptr; g1.xmode[3]=0; g1.ymode[3]=0;
        gemm256<256><<<dim3(4, 16, 4), dim3(512), 0, stream>>>(g1);

        attn_pair<<<dim3(16, NH, 2), dim3(512), 0, stream>>>(Qs, Kss, Vs, xVs, VBs);

        G4 g2;
        g2.X[0]=Qs;  g2.W[0]=Wxob; g2.B[0]=bxo; g2.Yb[0]=nullptr; g2.Yf[0]=out;          g2.xmode[0]=1; g2.ymode[0]=1;
        g2.X[1]=VBs; g2.W[1]=Wmob; g2.B[1]=bmo; g2.Yb[1]=nullptr; g2.Yf[1]=out + 2*SB;   g2.xmode[1]=1; g2.ymode[1]=1;
        g2.X[2]=Qs;  g2.W[2]=Wxob; g2.B[2]=bxo; g2.Yb[2]=nullptr; g2.Yf[2]=out;          g2.xmode[2]=1; g2.ymode[2]=1;
        g2.X[3]=Qs;  g2.W[3]=Wxob; g2.B[3]=bxo; g2.Yb[3]=nullptr; g2.Yf[3]=out;          g2.xmode[3]=1; g2.ymode[3]=1;
        gemm256<128><<<dim3(4, 32, 2), dim3(512), 0, stream>>>(g2);
    } else {
        // ---------------- fallback: proven R6 path (20 MB ws) ---------------
        bf16* Qs  = (bf16*)d_ws;
        bf16* Ksb = Qs  + SB;
        bf16* Vs  = Ksb + SB;
        bf16* xVs = Vs  + SB;
        bf16* vbs = xVs + SB;
        dim3 pg(8, 32);
        dim3 ag(16, NH);
        for (int b = 0; b < 2; ++b) {
            const float* q_b = query + (size_t)b * SB;
            const float* k_b = key   + (size_t)b * SB;
            const float* v_b = value + (size_t)b * SB;
            float* x_b = out + (size_t)b * SB;
            float* m_b = out + 2 * SB + (size_t)b * SB;
            proj_gemm<<<pg, blk, 0, stream>>>(q_b, Wq,  bq,  Qs,  0, 0);
            proj_gemm<<<pg, blk, 0, stream>>>(k_b, Wk,  bk,  Ksb, 0, 0);
            proj_gemm<<<pg, blk, 0, stream>>>(v_b, Wv,  bv,  Vs,  0, 0);
            proj_gemm<<<pg, blk, 0, stream>>>(k_b, Wxv, bxv, xVs, 0, 0);
            attn_dual<<<ag, blk, 0, stream>>>(Qs, Ksb, Vs, xVs, vbs);
            proj_gemm<<<pg, blk, 0, stream>>>(Qs,  Wxo, bxo, x_b, 1, 1);
            proj_gemm<<<pg, blk, 0, stream>>>(vbs, Wmo, bmo, m_b, 1, 1);
        }
    }
}

// Round 7
// 257.268 us; speedup vs baseline: 1.2592x; 1.0321x over previous
//
#include <hip/hip_runtime.h>
#include <math.h>

typedef __bf16 bf16;
typedef __bf16 bf16x2 __attribute__((ext_vector_type(2)));
typedef __bf16 bf16x4 __attribute__((ext_vector_type(4)));
typedef __bf16 bf16x8 __attribute__((ext_vector_type(8)));
typedef float f32x4 __attribute__((ext_vector_type(4)));

#define SEQ 2048
#define DH 64
#define DX 1024
#define NH 16
#define LP 72   // padded LDS row stride (64+8)

static __device__ __forceinline__ f32x4 mfma16(bf16x8 a, bf16x8 b, f32x4 c) {
    return __builtin_amdgcn_mfma_f32_16x16x32_bf16(a, b, c, 0, 0, 0);
}
static __device__ __forceinline__ bf16x8 cvt8(const float* __restrict__ p) {
    f32x4 a = *(const f32x4*)p;
    f32x4 b = *(const f32x4*)(p + 4);
    bf16x8 r;
    #pragma unroll
    for (int j = 0; j < 4; ++j) { r[j] = (bf16)a[j]; r[4 + j] = (bf16)b[j]; }
    return r;
}

// async global->LDS, 16 B per lane (lands at ldsbase + lane*16)
#define GL16(gp, lp) __builtin_amdgcn_global_load_lds( \
    (const __attribute__((address_space(1))) void*)(gp), \
    (__attribute__((address_space(3))) void*)(lp), 16, 0, 0)

// ============================ PLAN A kernels ================================

// f32 -> bf16 bulk convert: 3 inputs (4M el each) + 6 weights (1M el each)
// into ws at fixed offsets. 18M elements, 8 per thread.
__global__ __launch_bounds__(256) void cvt_all(
    const float* __restrict__ q, const float* __restrict__ k,
    const float* __restrict__ v,
    const float* __restrict__ w0, const float* __restrict__ w1,
    const float* __restrict__ w2, const float* __restrict__ w3,
    const float* __restrict__ w4, const float* __restrict__ w5,
    bf16* __restrict__ out)
{
    const size_t i = (size_t)blockIdx.x * 2048 + threadIdx.x * 8;
    const int seg = (int)(i >> 20);
    const float* s;
    size_t off;
    if (seg < 4)       { s = q; off = i; }
    else if (seg < 8)  { s = k; off = i - (4ull << 20); }
    else if (seg < 12) { s = v; off = i - (8ull << 20); }
    else {
        const float* ww[6] = {w0, w1, w2, w3, w4, w5};
        s = ww[seg - 12]; off = i - ((size_t)seg << 20);
    }
    *(bf16x8*)(out + i) = cvt8(s + off);
}

// fused multi-GEMM: Y_z = X_z @ W_z^T + bias_z, M=4096, N=K=1024, all bf16 in.
// xmode: 0 = X row-major [4096][1024]; 1 = X bhsd [2][16][2048][64]
// ymode: 0 = Y bf16 bhsd;              1 = Y f32 row-major
struct G4 {
    const bf16* X[4]; const bf16* W[4]; const float* B[4];
    bf16* Yb[4]; float* Yf[4]; int xmode[4]; int ymode[4];
};

// R3: 256-wide-N tile, BK=64, 8 waves (2M x 4N), double-buffered LDS.
// R4: XCD-bijective block swizzle (T1).
// R6: counted-vmcnt pipeline (T4) + bhsd epilogue repack via LDS.
template<int BM>
__global__ __launch_bounds__(512) void gemm256(G4 a)
{
    constexpr int MREP = BM / 32;           // M fragments per wave (8 or 4)
    constexpr int NT   = DX / 64;           // 16 K-steps
    constexpr int AEL  = BM * 64;
    constexpr int BEL  = 256 * 64;
    constexpr int SN   = BM / 64 + 4;       // GL16 per wave per stage (8 / 6)
    __shared__ __align__(16) bf16 smem[2 * AEL + 2 * BEL];

    const int z = blockIdx.z;
    const bf16* __restrict__ X = a.X[z];
    const bf16* __restrict__ W = a.W[z];
    const int xmode = a.xmode[z], ymode = a.ymode[z];

    const int tid  = threadIdx.x;
    const int wid  = tid >> 6;
    const int lane = tid & 63;
    const int l16  = lane & 15;
    const int quad = lane >> 4;
    const int wm   = wid >> 2;              // 0..1
    const int wn   = wid & 3;               // 0..3

    // XCD swizzle: t = linear 2D id; XCD k gets contiguous chunk of tiles
    // (x-major) -> all 4 x-blocks of a given y run on one XCD.
    const int nx = gridDim.x;               // 4
    const int nt = nx * gridDim.y;          // 64 (g1) / 128 (g2), %8 == 0
    int t = blockIdx.x + nx * blockIdx.y;
    t = (t & 7) * (nt >> 3) + (t >> 3);
    const int n0 = (t % nx) * 256;
    const int m0 = (t / nx) * BM;

    // staging geometry: per GL16 call a wave covers 8 rows x 64 cols.
    // LDS[row][c] = global[row][c ^ (row&7)]  (linear dest, swizzled src)
    const int srow8 = lane >> 3;            // row within 8-row group
    const int sch   = (lane & 7) ^ srow8;   // pre-swizzled source chunk

    f32x4 acc[MREP][4];
    #pragma unroll
    for (int i = 0; i < MREP; ++i)
        #pragma unroll
        for (int j = 0; j < 4; ++j) acc[i][j] = (f32x4){0.f,0.f,0.f,0.f};

    auto stage = [&](int buf, int kb) {
        bf16* Ab = smem + buf * AEL;
        bf16* Bb = smem + 2 * AEL + buf * BEL;
        #pragma unroll
        for (int g = 0; g < BM / 64; ++g) {
            const int row = g * 64 + wid * 8 + srow8;   // row in A tile
            const bf16* src;
            if (xmode == 0) {
                src = X + (size_t)(m0 + row) * DX + kb * 64 + sch * 8;
            } else {
                const int m = m0 + row;
                const int b = m >> 11, s = m & 2047;
                src = X + ((size_t)(b * NH + kb) * SEQ + s) * DH + sch * 8;
            }
            GL16(src, Ab + (g * 64 + wid * 8) * 64);
        }
        #pragma unroll
        for (int g = 0; g < 4; ++g) {
            const int row = g * 64 + wid * 8 + srow8;   // row in B tile
            const bf16* src = W + (size_t)(n0 + row) * DX + kb * 64 + sch * 8;
            GL16(src, Bb + (g * 64 + wid * 8) * 64);
        }
    };

    stage(0, 0);

    int cur = 0;
    for (int kb = 0; kb < NT; ++kb) {
        if (kb + 1 < NT) {
            stage(cur ^ 1, kb + 1);        // SN newer vmem ops in flight
            if constexpr (SN == 8) {
                __asm__ volatile("s_waitcnt vmcnt(8)" ::: "memory");
            } else {
                __asm__ volatile("s_waitcnt vmcnt(6)" ::: "memory");
            }
        } else {
            __asm__ volatile("s_waitcnt vmcnt(0)" ::: "memory");
        }
        __builtin_amdgcn_s_barrier();      // all waves' cur-buffer loads landed
        __builtin_amdgcn_sched_barrier(0);

        const bf16* Ab = smem + cur * AEL;
        const bf16* Bb = smem + 2 * AEL + cur * BEL;
        #pragma unroll
        for (int ks = 0; ks < 2; ++ks) {
            bf16x8 af[MREP], bfr[4];
            const int cc = (ks * 4 + quad) ^ (l16 & 7); // swizzled chunk
            #pragma unroll
            for (int mf = 0; mf < MREP; ++mf)
                af[mf] = *(const bf16x8*)&Ab[(wm * (BM/2) + mf * 16 + l16) * 64 + cc * 8];
            #pragma unroll
            for (int nf = 0; nf < 4; ++nf)
                bfr[nf] = *(const bf16x8*)&Bb[(wn * 64 + nf * 16 + l16) * 64 + cc * 8];
            #pragma unroll
            for (int mf = 0; mf < MREP; ++mf)
                #pragma unroll
                for (int nf = 0; nf < 4; ++nf)
                    acc[mf][nf] = mfma16(af[mf], bfr[nf], acc[mf][nf]);
        }
        __builtin_amdgcn_sched_barrier(0);
        __builtin_amdgcn_s_barrier();      // all reads of cur done before
        cur ^= 1;                          // it is re-staged next iter
    }

    if (ymode == 0) {
        // bhsd bf16 out: repack through LDS (reuse staging buffers),
        // 128-row passes, row stride 264 el (bank stagger).
        constexpr int EPS = 264;
        constexpr int PR  = 128;
        constexpr int NP  = BM / PR;        // 2 (BM=256) / 1 (BM=128)
        bf16* Ep = smem;
        #pragma unroll
        for (int p = 0; p < NP; ++p) {
            __builtin_amdgcn_s_barrier();
            if (NP == 1 || wm == p) {
                #pragma unroll
                for (int nf = 0; nf < 4; ++nf) {
                    const int col = wn * 64 + nf * 16 + l16;
                    const float bvv = a.B[z][n0 + col];
                    #pragma unroll
                    for (int mf = 0; mf < MREP; ++mf) {
                        const int rb = wm * (BM/2) + mf * 16 + quad * 4 - p * PR;
                        #pragma unroll
                        for (int r = 0; r < 4; ++r)
                            Ep[(rb + r) * EPS + col] = (bf16)(acc[mf][nf][r] + bvv);
                    }
                }
            }
            __asm__ volatile("s_waitcnt lgkmcnt(0)" ::: "memory");
            __builtin_amdgcn_s_barrier();
            #pragma unroll
            for (int j = 0; j < 8; ++j) {          // 128*256/8/512 = 8
                const int g    = j * 512 + tid;
                const int lrow = g >> 5;
                const int cg   = g & 31;
                bf16x8 vv = *(const bf16x8*)&Ep[lrow * EPS + cg * 8];
                const int row = m0 + p * PR + lrow;
                const int b = row >> 11, s = row & 2047;
                const int col = n0 + cg * 8;
                const int h = col >> 6, d = col & 63;
                *(bf16x8*)&a.Yb[z][((size_t)(b * NH + h) * SEQ + s) * DH + d] = vv;
            }
        }
    } else {
        // f32 row-major out: direct stores (64-B contiguous per quad-row,
        // full lines -> no amplification).
        #pragma unroll
        for (int nf = 0; nf < 4; ++nf) {
            const int col = n0 + wn * 64 + nf * 16 + l16;
            const float bvv = a.B[z][col];
            #pragma unroll
            for (int mf = 0; mf < MREP; ++mf) {
                #pragma unroll
                for (int r = 0; r < 4; ++r) {
                    const int row = m0 + wm * (BM/2) + mf * 16 + quad * 4 + r;
                    a.Yf[z][(size_t)row * DX + col] = acc[mf][nf][r] + bvv;
                }
            }
        }
    }
}

// R7 dual flash attention: grid (qt 16, h 16, b 2), block 512, 2 blocks/CU.
// Pair structure: 4 pairs x 32 q; wave A (half=0) -> P@V -> VB, wave B
// (half=1) -> P@xV -> Q; each wave computes QK^T + exp for its 16-q half;
// P shared through LDS.
// R7: cross-iteration phase pipeline (T15 structure). Iter i:
//   vmcnt(0) -> TOP barrier -> D1: QK^T(i) -> issue prefetch(i+1)
//   -> D2: exp(i) into REGS -> D3: PV(i-1) from Pl/Vt (prev tile)
//   -> MID barrier -> commit Pl<-p(i), Vt/xVt<-V(i) -> lgkmcnt(0).
// The D2->D3 lgkm+barrier of R6 is gone: the P write->read gap now spans
// a barrier + full QK^T+exp phase. exp(i) and PV(i-1) are independent and
// barrier-free -> scheduler interleaves TRANS with MFMA. Barriers 3 -> 2.
// Pl/Vt stay single-buffered: commit happens after the barrier proving all
// readers of the old tile are done; visibility via per-wave lgkmcnt(0) +
// next TOP barrier (m201 discipline). V prefetch regs use named cv/nv
// rotation (no runtime-indexed arrays, rule #20). One peeled PV at end.
__global__ __launch_bounds__(512) void attn_pair(
    bf16* __restrict__ Q, const bf16* __restrict__ K,
    const bf16* __restrict__ V, const bf16* __restrict__ xV,
    bf16* __restrict__ VB)
{
    __shared__ __align__(16) bf16 Ks[2][64 * 64];   // XOR-swizzled (GL16)
    __shared__ __align__(16) bf16 Vt [64 * LP];     // [d][k] transposed
    __shared__ __align__(16) bf16 xVt[64 * LP];
    __shared__ __align__(16) bf16 Pl[4][32 * LP];   // per-pair [q 32][k 64]

    const int tid  = threadIdx.x;
    const int wid  = tid >> 6;
    const int lane = tid & 63;
    const int l16  = lane & 15;
    const int quad = lane >> 4;
    const int pair = wid >> 1;
    const int half = wid & 1;                // 0: V->VB, 1: xV->Q
    const size_t hb = ((size_t)blockIdx.z * NH + blockIdx.y) * SEQ * DH;
    const int qp = blockIdx.x * 128 + pair * 32;   // pair base (32 q)
    const int q0 = qp + half * 16;                 // this wave's 16-q half

    bf16x8 qf[2];
    #pragma unroll
    for (int ks = 0; ks < 2; ++ks)
        qf[ks] = *(const bf16x8*)(Q + hb + (size_t)(q0 + l16) * DH + ks*32 + quad*8);

    bf16x8 one8;
    #pragma unroll
    for (int j = 0; j < 8; ++j) one8[j] = (bf16)1.0f;

    f32x4 ov[2][4];          // 32 q x 64 d (one value array)
    f32x4 rsa[2];            // row-sums for 32 q
    #pragma unroll
    for (int mf = 0; mf < 2; ++mf) {
        rsa[mf] = (f32x4){0.f,0.f,0.f,0.f};
        #pragma unroll
        for (int c2 = 0; c2 < 4; ++c2) ov[mf][c2] = (f32x4){0.f,0.f,0.f,0.f};
    }

    // K staging: wave w stages rows w*8..w*8+7 (1 GL16), XOR pre-swizzled
    const int krow = lane >> 3;
    const int kch  = (lane & 7) ^ krow;
    // V/xV staging: threads 0-255 stage V, 256-511 stage xV
    const bf16* __restrict__ vsrc = (tid & 256) ? xV : V;
    bf16* __restrict__ vdst = (tid & 256) ? xVt : Vt;
    const int t8  = tid & 255;
    const int vkp = (t8 & 31) * 2;
    const int vd0 = (t8 >> 5) * 8;
    const float SCL = 0.125f * 1.4426950408889634f;

    // ---- prologue: issue K(0) GL16 + load V(0) regs ----
    bf16x8 cv0, cv1;
    {
        const bf16* kg = K + hb + (size_t)(wid*8 + krow) * DH + kch*8;
        GL16(kg, &Ks[0][(wid*8) * 64]);
        const size_t g0 = hb + (size_t)vkp * DH + vd0;
        cv0 = *(const bf16x8*)(vsrc + g0);
        cv1 = *(const bf16x8*)(vsrc + g0 + DH);
    }

    int c = 0;
    for (int i = 0; i < SEQ / 64; ++i) {
        const int kt = i * 64;
        // TOP: own GL16 drained before barrier -> Ks[c] valid chip-wide
        __asm__ volatile("s_waitcnt vmcnt(0)" ::: "memory");
        __builtin_amdgcn_s_barrier();
        __builtin_amdgcn_sched_barrier(0);

        // D1: S^T(i) = K Q^T for this wave's 16 q (swizzled Ks read)
        f32x4 sf[4];
        #pragma unroll
        for (int mf = 0; mf < 4; ++mf) sf[mf] = (f32x4){0.f,0.f,0.f,0.f};
        __builtin_amdgcn_s_setprio(1);
        #pragma unroll
        for (int ks = 0; ks < 2; ++ks)
            #pragma unroll
            for (int mf = 0; mf < 4; ++mf) {
                bf16x8 kf = *(const bf16x8*)&Ks[c][(mf*16 + l16) * 64 +
                                                   (((ks*4 + quad) ^ (l16 & 7)) * 8)];
                sf[mf] = mfma16(kf, qf[ks], sf[mf]);
            }
        __builtin_amdgcn_s_setprio(0);

        // prefetch tile i+1 (GL16 K + V/xV reg loads)
        bf16x8 nv0, nv1;
        const bool more = (i + 1 < SEQ / 64);
        if (more) {
            const bf16* kg = K + hb + (size_t)(kt + 64 + wid*8 + krow) * DH + kch*8;
            GL16(kg, &Ks[c ^ 1][(wid*8) * 64]);
            const size_t g0 = hb + (size_t)(kt + 64 + vkp) * DH + vd0;
            nv0 = *(const bf16x8*)(vsrc + g0);
            nv1 = *(const bf16x8*)(vsrc + g0 + DH);
        }

        // D2: p(i) = exp2(S*scl) -> REGISTERS (no LDS, no barrier)
        bf16x4 pk[4];
        #pragma unroll
        for (int mf = 0; mf < 4; ++mf) {
            float p0 = __builtin_amdgcn_exp2f(sf[mf][0] * SCL);
            float p1 = __builtin_amdgcn_exp2f(sf[mf][1] * SCL);
            float p2 = __builtin_amdgcn_exp2f(sf[mf][2] * SCL);
            float p3 = __builtin_amdgcn_exp2f(sf[mf][3] * SCL);
            pk[mf] = (bf16x4){(bf16)p0, (bf16)p1, (bf16)p2, (bf16)p3};
        }

        // D3: PV(i-1) -- previous tile's P/V from LDS; interleaves with D2
        if (i > 0) {
            __builtin_amdgcn_s_setprio(1);
            #pragma unroll
            for (int ks = 0; ks < 2; ++ks) {
                bf16x8 pa[2];
                #pragma unroll
                for (int mf = 0; mf < 2; ++mf)
                    pa[mf] = *(const bf16x8*)&Pl[pair][(mf*16 + l16) * LP + ks*32 + quad*8];
                #pragma unroll
                for (int mf = 0; mf < 2; ++mf)
                    rsa[mf] = mfma16(pa[mf], one8, rsa[mf]);
                const bf16* __restrict__ tile = half ? xVt : Vt;
                #pragma unroll
                for (int cc = 0; cc < 4; ++cc) {
                    bf16x8 bv = *(const bf16x8*)&tile[(cc*16 + l16) * LP + ks*32 + quad*8];
                    #pragma unroll
                    for (int mf = 0; mf < 2; ++mf)
                        ov[mf][cc] = mfma16(pa[mf], bv, ov[mf][cc]);
                }
            }
            __builtin_amdgcn_s_setprio(0);
        }

        // MID barrier: every wave done reading Pl/Vt of tile i-1
        __builtin_amdgcn_sched_barrier(0);
        __builtin_amdgcn_s_barrier();
        __builtin_amdgcn_sched_barrier(0);

        // commit p(i) -> Pl, V(i) -> Vt/xVt (read next iter after TOP barrier)
        #pragma unroll
        for (int mf = 0; mf < 4; ++mf)
            *(bf16x4*)&Pl[pair][(half*16 + l16) * LP + mf*16 + quad*4] = pk[mf];
        #pragma unroll
        for (int j = 0; j < 8; ++j)
            *(bf16x2*)&vdst[(vd0 + j) * LP + vkp] = (bf16x2){cv0[j], cv1[j]};
        __asm__ volatile("s_waitcnt lgkmcnt(0)" ::: "memory");
        if (more) { cv0 = nv0; cv1 = nv1; }
        c ^= 1;
    }

    // peeled PV for the last tile
    __builtin_amdgcn_s_barrier();
    __builtin_amdgcn_sched_barrier(0);
    {
        __builtin_amdgcn_s_setprio(1);
        #pragma unroll
        for (int ks = 0; ks < 2; ++ks) {
            bf16x8 pa[2];
            #pragma unroll
            for (int mf = 0; mf < 2; ++mf)
                pa[mf] = *(const bf16x8*)&Pl[pair][(mf*16 + l16) * LP + ks*32 + quad*8];
            #pragma unroll
            for (int mf = 0; mf < 2; ++mf)
                rsa[mf] = mfma16(pa[mf], one8, rsa[mf]);
            const bf16* __restrict__ tile = half ? xVt : Vt;
            #pragma unroll
            for (int cc = 0; cc < 4; ++cc) {
                bf16x8 bv = *(const bf16x8*)&tile[(cc*16 + l16) * LP + ks*32 + quad*8];
                #pragma unroll
                for (int mf = 0; mf < 2; ++mf)
                    ov[mf][cc] = mfma16(pa[mf], bv, ov[mf][cc]);
            }
        }
        __builtin_amdgcn_s_setprio(0);
    }

    // epilogue: rsa[mf][r] = row-sum for pair q-row mf*16+quad*4+r
    // (broadcast over l16). Wave A -> VB (vbar), wave B -> Q (kbar).
    bf16* __restrict__ outp = half ? Q : VB;
    #pragma unroll
    for (int mf = 0; mf < 2; ++mf)
        #pragma unroll
        for (int r = 0; r < 4; ++r) {
            const int qrow = mf * 16 + quad * 4 + r;
            const float inv = 1.0f / rsa[mf][r];
            const size_t base = hb + (size_t)(qp + qrow) * DH;
            #pragma unroll
            for (int cc = 0; cc < 4; ++cc)
                outp[base + cc*16 + l16] = (bf16)(ov[mf][cc][r] * inv);
        }
}

// ======================= legacy (R6, proven) fallback =======================

__global__ __launch_bounds__(256) void proj_gemm(
    const void* __restrict__ Xv, const float* __restrict__ W,
    const float* __restrict__ bias, void* __restrict__ Yv,
    int in_kind, int out_mode)
{
    __shared__ __align__(16) bf16 As[64 * LP];
    __shared__ __align__(16) bf16 Bs[128 * LP];
    const int tid  = threadIdx.x;
    const int wave = tid >> 6;
    const int lane = tid & 63;
    const int l16  = lane & 15;
    const int quad = lane >> 4;
    const int m0 = blockIdx.y * 64;
    const int n0 = blockIdx.x * 128;
    const int m_w = (wave >> 1) * 32;
    const int n_w = (wave & 1) * 64;
    const int ar = tid >> 2, ac = (tid & 3) * 16;
    const int br = tid >> 1, bc = (tid & 1) * 32;

    f32x4 acc[2][4];
    #pragma unroll
    for (int i = 0; i < 2; ++i)
        #pragma unroll
        for (int j = 0; j < 4; ++j) acc[i][j] = (f32x4){0.f,0.f,0.f,0.f};

    for (int kb = 0; kb < DX / 64; ++kb) {
        __syncthreads();
        if (in_kind == 0) {
            const float* xp = (const float*)Xv + (size_t)(m0 + ar) * DX + kb * 64 + ac;
            *(bf16x8*)&As[ar * LP + ac]     = cvt8(xp);
            *(bf16x8*)&As[ar * LP + ac + 8] = cvt8(xp + 8);
        } else {
            const bf16* xp = (const bf16*)Xv + ((size_t)kb * SEQ + (m0 + ar)) * DH + ac;
            *(bf16x8*)&As[ar * LP + ac]     = *(const bf16x8*)xp;
            *(bf16x8*)&As[ar * LP + ac + 8] = *(const bf16x8*)(xp + 8);
        }
        {
            const float* wp = W + (size_t)(n0 + br) * DX + kb * 64 + bc;
            #pragma unroll
            for (int g = 0; g < 4; ++g)
                *(bf16x8*)&Bs[br * LP + bc + g * 8] = cvt8(wp + g * 8);
        }
        __syncthreads();
        #pragma unroll
        for (int ks = 0; ks < 2; ++ks) {
            bf16x8 a0 = *(const bf16x8*)&As[(m_w + l16)      * LP + ks * 32 + quad * 8];
            bf16x8 a1 = *(const bf16x8*)&As[(m_w + 16 + l16) * LP + ks * 32 + quad * 8];
            #pragma unroll
            for (int nf = 0; nf < 4; ++nf) {
                bf16x8 b = *(const bf16x8*)&Bs[(n_w + nf * 16 + l16) * LP + ks * 32 + quad * 8];
                acc[0][nf] = mfma16(a0, b, acc[0][nf]);
                acc[1][nf] = mfma16(a1, b, acc[1][nf]);
            }
        }
    }
    #pragma unroll
    for (int mf = 0; mf < 2; ++mf)
        #pragma unroll
        for (int nf = 0; nf < 4; ++nf) {
            const int col = n0 + n_w + nf * 16 + l16;
            const float bvv = bias[col];
            #pragma unroll
            for (int r = 0; r < 4; ++r) {
                const int row = m0 + m_w + mf * 16 + quad * 4 + r;
                float v = acc[mf][nf][r] + bvv;
                if (out_mode == 0) {
                    int h = col >> 6, d = col & 63;
                    ((bf16*)Yv)[((size_t)h * SEQ + row) * DH + d] = (bf16)v;
                } else {
                    ((float*)Yv)[(size_t)row * DX + col] = v;
                }
            }
        }
}

__global__ __launch_bounds__(256) void attn_dual(
    bf16* __restrict__ Q, const bf16* __restrict__ K,
    const bf16* __restrict__ V, const bf16* __restrict__ xV,
    bf16* __restrict__ vb)
{
    __shared__ __align__(16) bf16 Ks [64 * LP];
    __shared__ __align__(16) bf16 Vt [64 * LP];
    __shared__ __align__(16) bf16 xVt[64 * LP];
    __shared__ __align__(16) bf16 Pl[4][32 * LP];
    const int tid  = threadIdx.x;
    const int h    = blockIdx.y;
    const int qt   = blockIdx.x;
    const int wave = tid >> 6;
    const int lane = tid & 63;
    const int l16  = lane & 15;
    const int quad = lane >> 4;
    const size_t hb = (size_t)h * SEQ * DH;
    const int q0 = qt * 128 + wave * 32;

    bf16x8 qf[2][2];
    #pragma unroll
    for (int mf = 0; mf < 2; ++mf)
        #pragma unroll
        for (int ks = 0; ks < 2; ++ks)
            qf[mf][ks] = *(const bf16x8*)(Q + hb + (size_t)(q0 + mf*16 + l16) * DH + ks*32 + quad*8);

    float mr[2][4], lr[2][4];
    f32x4 ov[2][4], oxv[2][4];
    #pragma unroll
    for (int mf = 0; mf < 2; ++mf)
        #pragma unroll
        for (int r = 0; r < 4; ++r) { mr[mf][r] = -1e30f; lr[mf][r] = 0.f; }
    #pragma unroll
    for (int mf = 0; mf < 2; ++mf)
        #pragma unroll
        for (int c = 0; c < 4; ++c) {
            ov[mf][c]  = (f32x4){0.f,0.f,0.f,0.f};
            oxv[mf][c] = (f32x4){0.f,0.f,0.f,0.f};
        }
    const int sr = tid >> 2, sc = (tid & 3) * 16;
    const int vkp = (tid & 31) * 2;
    const int vd0 = (tid >> 5) * 8;
    const float SCL = 0.125f * 1.4426950408889634f;

    for (int kt = 0; kt < SEQ; kt += 64) {
        __syncthreads();
        {
            const bf16* kpt = K + hb + (size_t)(kt + sr) * DH + sc;
            *(bf16x8*)&Ks[sr * LP + sc]     = *(const bf16x8*)kpt;
            *(bf16x8*)&Ks[sr * LP + sc + 8] = *(const bf16x8*)(kpt + 8);
            const size_t g0 = hb + (size_t)(kt + vkp) * DH + vd0;
            bf16x8 v0 = *(const bf16x8*)(V + g0);
            bf16x8 v1 = *(const bf16x8*)(V + g0 + DH);
            bf16x8 x0 = *(const bf16x8*)(xV + g0);
            bf16x8 x1 = *(const bf16x8*)(xV + g0 + DH);
            #pragma unroll
            for (int j = 0; j < 8; ++j) {
                *(bf16x2*)&Vt [(vd0 + j) * LP + vkp] = (bf16x2){v0[j], v1[j]};
                *(bf16x2*)&xVt[(vd0 + j) * LP + vkp] = (bf16x2){x0[j], x1[j]};
            }
        }
        __syncthreads();
        f32x4 sf[2][4];
        #pragma unroll
        for (int mf = 0; mf < 2; ++mf)
            #pragma unroll
            for (int nf = 0; nf < 4; ++nf) sf[mf][nf] = (f32x4){0.f,0.f,0.f,0.f};
        #pragma unroll
        for (int ks = 0; ks < 2; ++ks)
            #pragma unroll
            for (int nf = 0; nf < 4; ++nf) {
                bf16x8 bk = *(const bf16x8*)&Ks[(nf * 16 + l16) * LP + ks * 32 + quad * 8];
                sf[0][nf] = mfma16(qf[0][ks], bk, sf[0][nf]);
                sf[1][nf] = mfma16(qf[1][ks], bk, sf[1][nf]);
            }
        float mx[2][4], rs[2][4], alpha[2][4];
        #pragma unroll
        for (int mf = 0; mf < 2; ++mf)
            #pragma unroll
            for (int r = 0; r < 4; ++r) {
                float aa = fmaxf(sf[mf][0][r], sf[mf][1][r]);
                float bb = fmaxf(sf[mf][2][r], sf[mf][3][r]);
                mx[mf][r] = fmaxf(aa, bb) * SCL;
            }
        #pragma unroll
        for (int off = 1; off < 16; off <<= 1)
            #pragma unroll
            for (int mf = 0; mf < 2; ++mf)
                #pragma unroll
                for (int r = 0; r < 4; ++r)
                    mx[mf][r] = fmaxf(mx[mf][r], __shfl_xor(mx[mf][r], off, 64));
        #pragma unroll
        for (int mf = 0; mf < 2; ++mf)
            #pragma unroll
            for (int r = 0; r < 4; ++r) {
                float mnew = fmaxf(mr[mf][r], mx[mf][r]);
                alpha[mf][r] = exp2f(mr[mf][r] - mnew);
                mr[mf][r] = mnew;
            }
        bf16* pw = &Pl[wave][0];
        #pragma unroll
        for (int mf = 0; mf < 2; ++mf)
            #pragma unroll
            for (int r = 0; r < 4; ++r) rs[mf][r] = 0.f;
        #pragma unroll
        for (int mf = 0; mf < 2; ++mf)
            #pragma unroll
            for (int nf = 0; nf < 4; ++nf)
                #pragma unroll
                for (int r = 0; r < 4; ++r) {
                    float p = exp2f(sf[mf][nf][r] * SCL - mr[mf][r]);
                    rs[mf][r] += p;
                    pw[(mf * 16 + quad * 4 + r) * LP + nf * 16 + l16] = (bf16)p;
                }
        #pragma unroll
        for (int off = 1; off < 16; off <<= 1)
            #pragma unroll
            for (int mf = 0; mf < 2; ++mf)
                #pragma unroll
                for (int r = 0; r < 4; ++r)
                    rs[mf][r] += __shfl_xor(rs[mf][r], off, 64);
        #pragma unroll
        for (int mf = 0; mf < 2; ++mf)
            #pragma unroll
            for (int r = 0; r < 4; ++r)
                lr[mf][r] = lr[mf][r] * alpha[mf][r] + rs[mf][r];
        #pragma unroll
        for (int mf = 0; mf < 2; ++mf)
            #pragma unroll
            for (int c = 0; c < 4; ++c)
                #pragma unroll
                for (int r = 0; r < 4; ++r) {
                    ov[mf][c][r]  *= alpha[mf][r];
                    oxv[mf][c][r] *= alpha[mf][r];
                }
        __asm__ volatile("s_waitcnt lgkmcnt(0)" ::: "memory");
        #pragma unroll
        for (int ks = 0; ks < 2; ++ks) {
            bf16x8 pa0 = *(const bf16x8*)&Pl[wave][(l16)      * LP + ks * 32 + quad * 8];
            bf16x8 pa1 = *(const bf16x8*)&Pl[wave][(16 + l16) * LP + ks * 32 + quad * 8];
            #pragma unroll
            for (int c = 0; c < 4; ++c) {
                bf16x8 bv = *(const bf16x8*)&Vt [(c * 16 + l16) * LP + ks * 32 + quad * 8];
                ov[0][c]  = mfma16(pa0, bv, ov[0][c]);
                ov[1][c]  = mfma16(pa1, bv, ov[1][c]);
                bf16x8 bx = *(const bf16x8*)&xVt[(c * 16 + l16) * LP + ks * 32 + quad * 8];
                oxv[0][c] = mfma16(pa0, bx, oxv[0][c]);
                oxv[1][c] = mfma16(pa1, bx, oxv[1][c]);
            }
        }
    }
    #pragma unroll
    for (int mf = 0; mf < 2; ++mf)
        #pragma unroll
        for (int r = 0; r < 4; ++r) {
            const int s = q0 + mf * 16 + quad * 4 + r;
            const float inv = 1.0f / lr[mf][r];
            #pragma unroll
            for (int c = 0; c < 4; ++c) {
                const int d = c * 16 + l16;
                Q [hb + (size_t)s * DH + d] = (bf16)(oxv[mf][c][r] * inv);
                vb[hb + (size_t)s * DH + d] = (bf16)(ov[mf][c][r]  * inv);
            }
        }
}

// ================================ launch ====================================

extern "C" void kernel_launch(void* const* d_in, const int* in_sizes, int n_in,
                              void* d_out, int out_size, void* d_ws, size_t ws_size,
                              hipStream_t stream) {
    const float* query = (const float*)d_in[0];
    const float* key   = (const float*)d_in[1];
    const float* value = (const float*)d_in[2];
    const float* Wq  = (const float*)d_in[3];  const float* bq  = (const float*)d_in[4];
    const float* Wk  = (const float*)d_in[5];  const float* bk  = (const float*)d_in[6];
    const float* Wv  = (const float*)d_in[7];  const float* bv  = (const float*)d_in[8];
    const float* Wxv = (const float*)d_in[9];  const float* bxv = (const float*)d_in[10];
    const float* Wxo = (const float*)d_in[11]; const float* bxo = (const float*)d_in[12];
    const float* Wmo = (const float*)d_in[13]; const float* bmo = (const float*)d_in[14];

    float* out = (float*)d_out;
    const size_t SB = (size_t)SEQ * DX;          // 2,097,152 el
    const size_t M1 = 1ull << 20;

    dim3 blk(256);

    if (ws_size >= (76ull << 20)) {
        // ---------------- Plan A: merged batches, bf16 everywhere -----------
        bf16* ws = (bf16*)d_ws;
        bf16* qb  = ws;                 // 4M el
        bf16* kb  = ws + 4 * M1;
        bf16* vb  = ws + 8 * M1;
        bf16* Wqb = ws + 12 * M1;       // 6 x 1M el
        bf16* Wkb = Wqb + M1;
        bf16* Wvb = Wkb + M1;
        bf16* Wxvb= Wvb + M1;
        bf16* Wxob= Wxvb + M1;
        bf16* Wmob= Wxob + M1;
        bf16* Qs  = ws + 18 * M1;       // bhsd [2][16][2048][64], 4M el each
        bf16* Kss = ws + 22 * M1;
        bf16* Vs  = ws + 26 * M1;
        bf16* xVs = ws + 30 * M1;
        bf16* VBs = ws + 34 * M1;

        cvt_all<<<9216, blk, 0, stream>>>(query, key, value,
                                          Wq, Wk, Wv, Wxv, Wxo, Wmo, ws + 0);

        G4 g1;
        g1.X[0]=qb;  g1.W[0]=Wqb;  g1.B[0]=bq;  g1.Yb[0]=Qs;  g1.Yf[0]=nullptr; g1.xmode[0]=0; g1.ymode[0]=0;
        g1.X[1]=kb;  g1.W[1]=Wkb;  g1.B[1]=bk;  g1.Yb[1]=Kss; g1.Yf[1]=nullptr; g1.xmode[1]=0; g1.ymode[1]=0;
        g1.X[2]=vb;  g1.W[2]=Wvb;  g1.B[2]=bv;  g1.Yb[2]=Vs;  g1.Yf[2]=nullptr; g1.xmode[2]=0; g1.ymode[2]=0;
        g1.X[3]=kb;  g1.W[3]=Wxvb; g1.B[3]=bxv; g1.Yb[3]=xVs; g1.Yf[3]=nullptr; g1.xmode[3]=0; g1.ymode[3]=0;
        gemm256<256><<<dim3(4, 16, 4), dim3(512), 0, stream>>>(g1);

        attn_pair<<<dim3(16, NH, 2), dim3(512), 0, stream>>>(Qs, Kss, Vs, xVs, VBs);

        G4 g2;
        g2.X[0]=Qs;  g2.W[0]=Wxob; g2.B[0]=bxo; g2.Yb[0]=nullptr; g2.Yf[0]=out;          g2.xmode[0]=1; g2.ymode[0]=1;
        g2.X[1]=VBs; g2.W[1]=Wmob; g2.B[1]=bmo; g2.Yb[1]=nullptr; g2.Yf[1]=out + 2*SB;   g2.xmode[1]=1; g2.ymode[1]=1;
        g2.X[2]=Qs;  g2.W[2]=Wxob; g2.B[2]=bxo; g2.Yb[2]=nullptr; g2.Yf[2]=out;          g2.xmode[2]=1; g2.ymode[2]=1;
        g2.X[3]=Qs;  g2.W[3]=Wxob; g2.B[3]=bxo; g2.Yb[3]=nullptr; g2.Yf[3]=out;          g2.xmode[3]=1; g2.ymode[3]=1;
        gemm256<128><<<dim3(4, 32, 2), dim3(512), 0, stream>>>(g2);
    } else {
        // ---------------- fallback: proven R6 path (20 MB ws) ---------------
        bf16* Qs  = (bf16*)d_ws;
        bf16* Ksb = Qs  + SB;
        bf16* Vs  = Ksb + SB;
        bf16* xVs = Vs  + SB;
        bf16* vbs = xVs + SB;
        dim3 pg(8, 32);
        dim3 ag(16, NH);
        for (int b = 0; b < 2; ++b) {
            const float* q_b = query + (size_t)b * SB;
            const float* k_b = key   + (size_t)b * SB;
            const float* v_b = value + (size_t)b * SB;
            float* x_b = out + (size_t)b * SB;
            float* m_b = out + 2 * SB + (size_t)b * SB;
            proj_gemm<<<pg, blk, 0, stream>>>(q_b, Wq,  bq,  Qs,  0, 0);
            proj_gemm<<<pg, blk, 0, stream>>>(k_b, Wk,  bk,  Ksb, 0, 0);
            proj_gemm<<<pg, blk, 0, stream>>>(v_b, Wv,  bv,  Vs,  0, 0);
            proj_gemm<<<pg, blk, 0, stream>>>(k_b, Wxv, bxv, xVs, 0, 0);
            attn_dual<<<ag, blk, 0, stream>>>(Qs, Ksb, Vs, xVs, vbs);
            proj_gemm<<<pg, blk, 0, stream>>>(Qs,  Wxo, bxo, x_b, 1, 1);
            proj_gemm<<<pg, blk, 0, stream>>>(vbs, Wmo, bmo, m_b, 1, 1);
        }
    }
}